// Round 1
// baseline (1638.838 us; speedup 1.0000x reference)
//
#include <hip/hip_runtime.h>
#include <hip/hip_bf16.h>
#include <math.h>

#define BGR 64
#define EMAX 1024000

// ---------------- small init ----------------
__global__ void init_ecnt_kernel(int* ecnt) {
    if (threadIdx.x == 0) { ecnt[0] = EMAX; ecnt[1] = 0; ecnt[2] = 0; }
}

__global__ void pnorm_kernel(const float* __restrict__ p, float* __restrict__ out) {
    __shared__ float buf[128];
    int t = threadIdx.x;
    float v = p[t];
    buf[t] = v * v;
    __syncthreads();
    for (int off = 64; off; off >>= 1) {
        if (t < off) buf[t] += buf[t + off];
        __syncthreads();
    }
    if (t == 0) out[0] = sqrtf(buf[0]);
}

// ---------------- degree / CSR build ----------------
__global__ void count_kernel(const int* __restrict__ dst, const int* __restrict__ ecnt,
                             int* __restrict__ deg) {
    int e = blockIdx.x * 256 + threadIdx.x;
    if (e >= ecnt[0]) return;
    atomicAdd(&deg[dst[e]], 1);
}

__global__ void dinv_kernel(const int* __restrict__ deg, float* __restrict__ dinv) {
    int i = blockIdx.x * 256 + threadIdx.x;
    dinv[i] = rsqrtf((float)deg[i] + 1.0f);
}

__global__ void scan1_kernel(const int* __restrict__ deg, int* __restrict__ rowptr,
                             int* __restrict__ part) {
    __shared__ int buf[256];
    int t = threadIdx.x;
    int i = blockIdx.x * 256 + t;
    int v = deg[i];
    buf[t] = v;
    __syncthreads();
    for (int off = 1; off < 256; off <<= 1) {
        int tmp = (t >= off) ? buf[t - off] : 0;
        __syncthreads();
        buf[t] += tmp;
        __syncthreads();
    }
    rowptr[i] = buf[t] - v;
    if (t == 255) part[blockIdx.x] = buf[255];
}

__global__ void scan2_kernel(int* __restrict__ part, int* __restrict__ rowptr, int nb, int n) {
    __shared__ int buf[256];
    int t = threadIdx.x;
    int v = (t < nb) ? part[t] : 0;
    buf[t] = v;
    __syncthreads();
    for (int off = 1; off < 256; off <<= 1) {
        int tmp = (t >= off) ? buf[t - off] : 0;
        __syncthreads();
        buf[t] += tmp;
        __syncthreads();
    }
    if (t < nb) part[t] = buf[t] - v;
    if (t == 255) rowptr[n] = buf[255];
}

__global__ void scan3_kernel(int* __restrict__ rowptr, int* __restrict__ cursor,
                             const int* __restrict__ part) {
    int i = blockIdx.x * 256 + threadIdx.x;
    int v = rowptr[i] + part[blockIdx.x];
    rowptr[i] = v;
    cursor[i] = v;
}

__global__ void scatter_kernel(const int* __restrict__ src, const int* __restrict__ dst,
                               const int* __restrict__ ecnt, int* __restrict__ cursor,
                               const float* __restrict__ dinv, int* __restrict__ colidx,
                               float* __restrict__ wcoef) {
    int e = blockIdx.x * 256 + threadIdx.x;
    if (e >= ecnt[0]) return;
    int s = src[e], d = dst[e];
    int pos = atomicAdd(&cursor[d], 1);
    colidx[pos] = s;
    wcoef[pos] = dinv[s] * dinv[d];
}

// ---------------- fused 3-branch GEMM + bias + relu + sum ----------------
// H = relu(x@wa+ba) + relu(x@wb+bb) + relu(x@wc+bc), x:[n,128], w:[128,128]
// block: 256 thr, 64-node tile; thread = 8 nodes x 4 feats micro-tile
__global__ __launch_bounds__(256) void gemm3_kernel(
    const float* __restrict__ x,
    const float* __restrict__ w0, const float* __restrict__ b0,
    const float* __restrict__ w1, const float* __restrict__ b1,
    const float* __restrict__ w2, const float* __restrict__ b2,
    float* __restrict__ out) {
    __shared__ float4 xs[2048];   // 64 rows x 32 float4 (full K)
    __shared__ float4 ws[2048];   // 64 kk x 32 float4 (half K at a time)
    const int tid = threadIdx.x;
    const int ty = tid >> 5;      // 0..7  node group (8 nodes each)
    const int tx = tid & 31;      // 0..31 feature group (4 feats)
    const long base = (long)blockIdx.x * 64;

    const float4* xg = (const float4*)(x + base * 128);
    for (int i = tid; i < 2048; i += 256) xs[i] = xg[i];

    float tot[8][4];
#pragma unroll
    for (int m = 0; m < 8; m++) { tot[m][0] = 0.f; tot[m][1] = 0.f; tot[m][2] = 0.f; tot[m][3] = 0.f; }

    const float* wj[3] = {w0, w1, w2};
    const float* bj[3] = {b0, b1, b2};

    for (int j = 0; j < 3; j++) {
        float acc[8][4];
#pragma unroll
        for (int m = 0; m < 8; m++) { acc[m][0] = 0.f; acc[m][1] = 0.f; acc[m][2] = 0.f; acc[m][3] = 0.f; }
        for (int kc = 0; kc < 128; kc += 64) {
            __syncthreads();
            const float4* wh = (const float4*)(wj[j] + kc * 128);
            for (int i = tid; i < 2048; i += 256) ws[i] = wh[i];
            __syncthreads();
            for (int c4 = 0; c4 < 16; c4++) {
                float4 xr[8];
#pragma unroll
                for (int m = 0; m < 8; m++) xr[m] = xs[(ty * 8 + m) * 32 + (kc >> 2) + c4];
#pragma unroll
                for (int r = 0; r < 4; r++) {
                    float4 wv = ws[(c4 * 4 + r) * 32 + tx];
#pragma unroll
                    for (int m = 0; m < 8; m++) {
                        float xv = (r == 0) ? xr[m].x : (r == 1) ? xr[m].y : (r == 2) ? xr[m].z : xr[m].w;
                        acc[m][0] += xv * wv.x;
                        acc[m][1] += xv * wv.y;
                        acc[m][2] += xv * wv.z;
                        acc[m][3] += xv * wv.w;
                    }
                }
            }
        }
        float4 bv = ((const float4*)bj[j])[tx];
#pragma unroll
        for (int m = 0; m < 8; m++) {
            tot[m][0] += fmaxf(acc[m][0] + bv.x, 0.f);
            tot[m][1] += fmaxf(acc[m][1] + bv.y, 0.f);
            tot[m][2] += fmaxf(acc[m][2] + bv.z, 0.f);
            tot[m][3] += fmaxf(acc[m][3] + bv.w, 0.f);
        }
    }
    float4* og = (float4*)(out + base * 128);
#pragma unroll
    for (int m = 0; m < 8; m++)
        og[(ty * 8 + m) * 32 + tx] = make_float4(tot[m][0], tot[m][1], tot[m][2], tot[m][3]);
}

// ---------------- propagation: hout = hin*(1+dinv^2) + sum_e w[e]*hin[col[e]] ----------------
__global__ __launch_bounds__(256) void prop_kernel(
    const float* __restrict__ hin, float* __restrict__ hout,
    const int* __restrict__ rowptr, const int* __restrict__ colidx,
    const float* __restrict__ wcoef, const float* __restrict__ dinv, int n) {
    int node = blockIdx.x * 4 + (threadIdx.x >> 6);
    int lane = threadIdx.x & 63;
    const float2* h2 = (const float2*)hin;
    float di = dinv[node];
    float selfc = 1.0f + di * di;
    float2 hv = h2[node * 64 + lane];
    float ax = hv.x * selfc, ay = hv.y * selfc;
    int e0 = rowptr[node], e1 = rowptr[node + 1];
    for (int e = e0; e < e1; ++e) {
        int c = colidx[e];
        float w = wcoef[e];
        float2 g = h2[c * 64 + lane];
        ax += w * g.x;
        ay += w * g.y;
    }
    ((float2*)hout)[node * 64 + lane] = make_float2(ax, ay);
}

// ---------------- score = h @ p / ||p|| ----------------
__global__ void score_kernel(const float* __restrict__ h, const float* __restrict__ p,
                             const float* __restrict__ pn, float* __restrict__ score) {
    int node = blockIdx.x * 4 + (threadIdx.x >> 6);
    int lane = threadIdx.x & 63;
    float2 a = ((const float2*)h)[node * 64 + lane];
    float2 b = ((const float2*)p)[lane];
    float v = a.x * b.x + a.y * b.y;
    v += __shfl_xor(v, 32, 64);
    v += __shfl_xor(v, 16, 64);
    v += __shfl_xor(v, 8, 64);
    v += __shfl_xor(v, 4, 64);
    v += __shfl_xor(v, 2, 64);
    v += __shfl_xor(v, 1, 64);
    if (lane == 0) score[node] = v / pn[0];
}

// ---------------- top-k pool: bitonic sort 1024 per graph ----------------
__global__ __launch_bounds__(256) void pool_kernel(const float* __restrict__ score, int npg, int k,
                            int* __restrict__ perm, float* __restrict__ gate,
                            int* __restrict__ remap) {
    __shared__ float sval[1024];
    __shared__ int sidx[1024];
    int b = blockIdx.x, t = threadIdx.x;
    for (int i = t; i < 1024; i += 256) {
        sval[i] = (i < npg) ? score[b * npg + i] : -INFINITY;
        sidx[i] = i;
    }
    __syncthreads();
    for (int ksz = 2; ksz <= 1024; ksz <<= 1) {
        for (int j = ksz >> 1; j > 0; j >>= 1) {
            for (int i = t; i < 1024; i += 256) {
                int l = i ^ j;
                if (l > i) {
                    float vi = sval[i], vl = sval[l];
                    bool up = ((i & ksz) == 0);
                    bool sw = up ? (vi < vl) : (vi > vl);   // descending sort
                    if (sw) {
                        sval[i] = vl; sval[l] = vi;
                        int tmp = sidx[i]; sidx[i] = sidx[l]; sidx[l] = tmp;
                    }
                }
            }
            __syncthreads();
        }
    }
    for (int i = t; i < k; i += 256) {
        int oldg = b * npg + sidx[i];
        int newg = b * k + i;
        perm[newg] = oldg;
        gate[newg] = tanhf(sval[i]);
        remap[oldg] = newg;
    }
}

// ---------------- gather new_x = h[perm] * gate ----------------
__global__ void newx_kernel(const float* __restrict__ h, const int* __restrict__ perm,
                            const float* __restrict__ gate, float* __restrict__ xo) {
    int m = blockIdx.x * 4 + (threadIdx.x >> 6);
    int lane = threadIdx.x & 63;
    int old = perm[m];
    float g = gate[m];
    float2 v = ((const float2*)h)[old * 64 + lane];
    ((float2*)xo)[m * 64 + lane] = make_float2(v.x * g, v.y * g);
}

// ---------------- readout: rsum[b] += [max over k ; mean over k] ----------------
__global__ void readout_kernel(const float* __restrict__ x, float* __restrict__ rsum, int k) {
    int b = blockIdx.x, f = threadIdx.x;   // 128 threads
    const float* base = x + (size_t)b * k * 128;
    float mx = -INFINITY, sm = 0.f;
#pragma unroll 4
    for (int j = 0; j < k; j++) {
        float v = base[j * 128 + f];
        mx = fmaxf(mx, v);
        sm += v;
    }
    rsum[b * 256 + f] += mx;
    rsum[b * 256 + 128 + f] += sm / (float)k;
}

// ---------------- edge remap + compact ----------------
__global__ void compact_kernel(const int* __restrict__ src, const int* __restrict__ dst,
                               const int* __restrict__ ecnt, const int* __restrict__ remap,
                               int* __restrict__ so, int* __restrict__ dd,
                               int* __restrict__ ecout) {
    int e = blockIdx.x * 256 + threadIdx.x;
    if (e >= ecnt[0]) return;
    int ns = remap[src[e]], nd = remap[dst[e]];
    if ((ns | nd) >= 0) {
        int pos = atomicAdd(ecout, 1);
        so[pos] = ns;
        dd[pos] = nd;
    }
}

// ---------------- final MLP ----------------
__global__ void mlp1_kernel(const float* __restrict__ z, const float* __restrict__ w,
                            const float* __restrict__ bias, float* __restrict__ o) {
    int b = blockIdx.x, f = threadIdx.x;   // 128
    float acc = bias[f];
    for (int kk = 0; kk < 256; kk++) acc += z[b * 256 + kk] * w[kk * 128 + f];
    o[b * 128 + f] = fmaxf(acc, 0.f);
}

__global__ void mlp2_kernel(const float* __restrict__ z, const float* __restrict__ w,
                            const float* __restrict__ bias, float* __restrict__ o) {
    int b = blockIdx.x, f = threadIdx.x;   // 64
    float acc = bias[f];
    for (int kk = 0; kk < 128; kk++) acc += z[b * 128 + kk] * w[kk * 64 + f];
    o[b * 64 + f] = fmaxf(acc, 0.f);
}

__global__ void mlp3_kernel(const float* __restrict__ z2, const float* __restrict__ w3,
                            const float* __restrict__ b3, float* __restrict__ out) {
    __shared__ float lg[10];
    __shared__ float ls;
    int b = blockIdx.x, t = threadIdx.x;   // 64
    if (t < 10) {
        float acc = b3[t];
        for (int kk = 0; kk < 64; kk++) acc += z2[b * 64 + kk] * w3[kk * 10 + t];
        lg[t] = acc;
    }
    __syncthreads();
    if (t == 0) {
        float m = lg[0];
        for (int c = 1; c < 10; c++) m = fmaxf(m, lg[c]);
        float s = 0.f;
        for (int c = 0; c < 10; c++) s += expf(lg[c] - m);
        ls = m + logf(s);
    }
    __syncthreads();
    if (t < 10) out[b * 10 + t] = lg[t] - ls;
}

// =====================================================================
extern "C" void kernel_launch(void* const* d_in, const int* in_sizes, int n_in,
                              void* d_out, int out_size, void* d_ws, size_t ws_size,
                              hipStream_t stream) {
    char* ws = (char*)d_ws;
    size_t off = 0;
    auto alloc = [&](size_t bytes) -> void* {
        void* p = ws + off;
        off += (bytes + 255) & ~(size_t)255;
        return p;
    };
    float* hA = (float*)alloc(64000UL * 128 * 4);
    float* hB = (float*)alloc(64000UL * 128 * 4);
    float* score = (float*)alloc(64000UL * 4);
    float* dinvb = (float*)alloc(64000UL * 4);
    int* deg = (int*)alloc(64000UL * 4);
    int* rowptr = (int*)alloc(64001UL * 4);
    int* cursor = (int*)alloc(64000UL * 4);
    int* part = (int*)alloc(1024);
    int* colidx = (int*)alloc((size_t)EMAX * 4);
    float* wcoef = (float*)alloc((size_t)EMAX * 4);
    int* srcA = (int*)alloc((size_t)EMAX * 4);
    int* dstA = (int*)alloc((size_t)EMAX * 4);
    int* srcB = (int*)alloc((size_t)EMAX * 4);
    int* dstB = (int*)alloc((size_t)EMAX * 4);
    int* perm = (int*)alloc(51200UL * 4);
    float* gate = (float*)alloc(51200UL * 4);
    int* remap = (int*)alloc(64000UL * 4);
    float* rsum = (float*)alloc(64UL * 256 * 4);
    float* z1 = (float*)alloc(64UL * 128 * 4);
    float* z2 = (float*)alloc(64UL * 64 * 4);
    float* pnorm = (float*)alloc(256);
    int* ecnt = (int*)alloc(256);
    (void)ws_size;  // requires ~92.5 MB

    const float* x0 = (const float*)d_in[0];
    const int* src0 = (const int*)d_in[1];
    const int* dst0 = (const int*)d_in[2];

    hipMemsetAsync(rsum, 0, 64 * 256 * 4, stream);
    init_ecnt_kernel<<<1, 64, 0, stream>>>(ecnt);
    pnorm_kernel<<<1, 128, 0, stream>>>((const float*)d_in[27], pnorm + 0);
    pnorm_kernel<<<1, 128, 0, stream>>>((const float*)d_in[28], pnorm + 1);
    pnorm_kernel<<<1, 128, 0, stream>>>((const float*)d_in[29], pnorm + 2);

    auto run_layer = [&](int n, int npg, int k, const float* x,
                         const int* esrc, const int* edst, const int* ecin,
                         const float* wa, const float* ba, const float* wb, const float* bb,
                         const float* wc, const float* bc, const float* p, const float* pn,
                         int* so, int* ddst, int* ecout) {
        hipMemsetAsync(deg, 0, (size_t)n * 4, stream);
        count_kernel<<<EMAX / 256, 256, 0, stream>>>(edst, ecin, deg);
        dinv_kernel<<<n / 256, 256, 0, stream>>>(deg, dinvb);
        scan1_kernel<<<n / 256, 256, 0, stream>>>(deg, rowptr, part);
        scan2_kernel<<<1, 256, 0, stream>>>(part, rowptr, n / 256, n);
        scan3_kernel<<<n / 256, 256, 0, stream>>>(rowptr, cursor, part);
        scatter_kernel<<<EMAX / 256, 256, 0, stream>>>(esrc, edst, ecin, cursor, dinvb,
                                                       colidx, wcoef);
        gemm3_kernel<<<n / 64, 256, 0, stream>>>(x, wa, ba, wb, bb, wc, bc, hA);
        prop_kernel<<<n / 4, 256, 0, stream>>>(hA, hB, rowptr, colidx, wcoef, dinvb, n);
        prop_kernel<<<n / 4, 256, 0, stream>>>(hB, hA, rowptr, colidx, wcoef, dinvb, n);
        score_kernel<<<n / 4, 256, 0, stream>>>(hA, p, pn, score);
        hipMemsetAsync(remap, 0xFF, (size_t)n * 4, stream);
        pool_kernel<<<BGR, 256, 0, stream>>>(score, npg, k, perm, gate, remap);
        newx_kernel<<<(BGR * k) / 4, 256, 0, stream>>>(hA, perm, gate, hB);
        readout_kernel<<<BGR, 128, 0, stream>>>(hB, rsum, k);
        if (ecout)
            compact_kernel<<<EMAX / 256, 256, 0, stream>>>(esrc, edst, ecin, remap, so, ddst,
                                                           ecout);
    };

    run_layer(64000, 1000, 800, x0, src0, dst0, ecnt + 0,
              (const float*)d_in[3], (const float*)d_in[4], (const float*)d_in[5],
              (const float*)d_in[6], (const float*)d_in[7], (const float*)d_in[8],
              (const float*)d_in[27], pnorm + 0, srcA, dstA, ecnt + 1);

    run_layer(51200, 800, 640, hB, srcA, dstA, ecnt + 1,
              (const float*)d_in[9], (const float*)d_in[10], (const float*)d_in[11],
              (const float*)d_in[12], (const float*)d_in[13], (const float*)d_in[14],
              (const float*)d_in[28], pnorm + 1, srcB, dstB, ecnt + 2);

    run_layer(40960, 640, 512, hB, srcB, dstB, ecnt + 2,
              (const float*)d_in[15], (const float*)d_in[16], (const float*)d_in[17],
              (const float*)d_in[18], (const float*)d_in[19], (const float*)d_in[20],
              (const float*)d_in[29], pnorm + 2, nullptr, nullptr, nullptr);

    mlp1_kernel<<<64, 128, 0, stream>>>(rsum, (const float*)d_in[21], (const float*)d_in[22], z1);
    mlp2_kernel<<<64, 64, 0, stream>>>(z1, (const float*)d_in[23], (const float*)d_in[24], z2);
    mlp3_kernel<<<64, 64, 0, stream>>>(z2, (const float*)d_in[25], (const float*)d_in[26],
                                       (float*)d_out);
}

// Round 2
// 1339.353 us; speedup vs baseline: 1.2236x; 1.2236x over previous
//
#include <hip/hip_runtime.h>
#include <hip/hip_bf16.h>
#include <math.h>

#define BGR 64
#define EMAX 1024000

// ---------------- small init ----------------
__global__ void init_ecnt_kernel(int* ecnt) {
    if (threadIdx.x == 0) { ecnt[0] = EMAX; ecnt[1] = 0; ecnt[2] = 0; }
}

__global__ void pnorm_kernel(const float* __restrict__ p, float* __restrict__ out) {
    __shared__ float buf[128];
    int t = threadIdx.x;
    float v = p[t];
    buf[t] = v * v;
    __syncthreads();
    for (int off = 64; off; off >>= 1) {
        if (t < off) buf[t] += buf[t + off];
        __syncthreads();
    }
    if (t == 0) out[0] = sqrtf(buf[0]);
}

// ---------------- degree / CSR build ----------------
__global__ void count_kernel(const int* __restrict__ dst, const int* __restrict__ ecnt,
                             int* __restrict__ deg) {
    int e = blockIdx.x * 256 + threadIdx.x;
    if (e >= ecnt[0]) return;
    atomicAdd(&deg[dst[e]], 1);
}

__global__ void dinv_kernel(const int* __restrict__ deg, float* __restrict__ dinv) {
    int i = blockIdx.x * 256 + threadIdx.x;
    dinv[i] = rsqrtf((float)deg[i] + 1.0f);
}

__global__ void scan1_kernel(const int* __restrict__ deg, int* __restrict__ rowptr,
                             int* __restrict__ part) {
    __shared__ int buf[256];
    int t = threadIdx.x;
    int i = blockIdx.x * 256 + t;
    int v = deg[i];
    buf[t] = v;
    __syncthreads();
    for (int off = 1; off < 256; off <<= 1) {
        int tmp = (t >= off) ? buf[t - off] : 0;
        __syncthreads();
        buf[t] += tmp;
        __syncthreads();
    }
    rowptr[i] = buf[t] - v;
    if (t == 255) part[blockIdx.x] = buf[255];
}

__global__ void scan2_kernel(int* __restrict__ part, int* __restrict__ rowptr, int nb, int n) {
    __shared__ int buf[256];
    int t = threadIdx.x;
    int v = (t < nb) ? part[t] : 0;
    buf[t] = v;
    __syncthreads();
    for (int off = 1; off < 256; off <<= 1) {
        int tmp = (t >= off) ? buf[t - off] : 0;
        __syncthreads();
        buf[t] += tmp;
        __syncthreads();
    }
    if (t < nb) part[t] = buf[t] - v;
    if (t == 255) rowptr[n] = buf[255];
}

__global__ void scan3_kernel(int* __restrict__ rowptr, int* __restrict__ cursor,
                             const int* __restrict__ part) {
    int i = blockIdx.x * 256 + threadIdx.x;
    int v = rowptr[i] + part[blockIdx.x];
    rowptr[i] = v;
    cursor[i] = v;
}

__global__ void scatter_kernel(const int* __restrict__ src, const int* __restrict__ dst,
                               const int* __restrict__ ecnt, int* __restrict__ cursor,
                               const float* __restrict__ dinv, int* __restrict__ colidx,
                               float* __restrict__ wcoef) {
    int e = blockIdx.x * 256 + threadIdx.x;
    if (e >= ecnt[0]) return;
    int s = src[e], d = dst[e];
    int pos = atomicAdd(&cursor[d], 1);
    colidx[pos] = s;
    wcoef[pos] = dinv[s] * dinv[d];
}

// ---------------- fused 3-branch GEMM + bias + relu + sum ----------------
__global__ __launch_bounds__(256) void gemm3_kernel(
    const float* __restrict__ x,
    const float* __restrict__ w0, const float* __restrict__ b0,
    const float* __restrict__ w1, const float* __restrict__ b1,
    const float* __restrict__ w2, const float* __restrict__ b2,
    float* __restrict__ out) {
    __shared__ float4 xs[2048];   // 64 rows x 32 float4 (full K)
    __shared__ float4 ws[2048];   // 64 kk x 32 float4 (half K at a time)
    const int tid = threadIdx.x;
    const int ty = tid >> 5;      // 0..7  node group (8 nodes each)
    const int tx = tid & 31;      // 0..31 feature group (4 feats)
    const long base = (long)blockIdx.x * 64;

    const float4* xg = (const float4*)(x + base * 128);
    for (int i = tid; i < 2048; i += 256) xs[i] = xg[i];

    float tot[8][4];
#pragma unroll
    for (int m = 0; m < 8; m++) { tot[m][0] = 0.f; tot[m][1] = 0.f; tot[m][2] = 0.f; tot[m][3] = 0.f; }

    const float* wj[3] = {w0, w1, w2};
    const float* bj[3] = {b0, b1, b2};

    for (int j = 0; j < 3; j++) {
        float acc[8][4];
#pragma unroll
        for (int m = 0; m < 8; m++) { acc[m][0] = 0.f; acc[m][1] = 0.f; acc[m][2] = 0.f; acc[m][3] = 0.f; }
        for (int kc = 0; kc < 128; kc += 64) {
            __syncthreads();
            const float4* wh = (const float4*)(wj[j] + kc * 128);
            for (int i = tid; i < 2048; i += 256) ws[i] = wh[i];
            __syncthreads();
            for (int c4 = 0; c4 < 16; c4++) {
                float4 xr[8];
#pragma unroll
                for (int m = 0; m < 8; m++) xr[m] = xs[(ty * 8 + m) * 32 + (kc >> 2) + c4];
#pragma unroll
                for (int r = 0; r < 4; r++) {
                    float4 wv = ws[(c4 * 4 + r) * 32 + tx];
#pragma unroll
                    for (int m = 0; m < 8; m++) {
                        float xv = (r == 0) ? xr[m].x : (r == 1) ? xr[m].y : (r == 2) ? xr[m].z : xr[m].w;
                        acc[m][0] += xv * wv.x;
                        acc[m][1] += xv * wv.y;
                        acc[m][2] += xv * wv.z;
                        acc[m][3] += xv * wv.w;
                    }
                }
            }
        }
        float4 bv = ((const float4*)bj[j])[tx];
#pragma unroll
        for (int m = 0; m < 8; m++) {
            tot[m][0] += fmaxf(acc[m][0] + bv.x, 0.f);
            tot[m][1] += fmaxf(acc[m][1] + bv.y, 0.f);
            tot[m][2] += fmaxf(acc[m][2] + bv.z, 0.f);
            tot[m][3] += fmaxf(acc[m][3] + bv.w, 0.f);
        }
    }
    float4* og = (float4*)(out + base * 128);
#pragma unroll
    for (int m = 0; m < 8; m++)
        og[(ty * 8 + m) * 32 + tx] = make_float4(tot[m][0], tot[m][1], tot[m][2], tot[m][3]);
}

// ---------------- propagation: hout = hin*(1+dinv^2) + sum_e w[e]*hin[col[e]] ----------------
__global__ __launch_bounds__(256) void prop_kernel(
    const float* __restrict__ hin, float* __restrict__ hout,
    const int* __restrict__ rowptr, const int* __restrict__ colidx,
    const float* __restrict__ wcoef, const float* __restrict__ dinv, int n) {
    int node = blockIdx.x * 4 + (threadIdx.x >> 6);
    int lane = threadIdx.x & 63;
    const float2* h2 = (const float2*)hin;
    float di = dinv[node];
    float selfc = 1.0f + di * di;
    float2 hv = h2[node * 64 + lane];
    float ax = hv.x * selfc, ay = hv.y * selfc;
    int e0 = rowptr[node], e1 = rowptr[node + 1];
    for (int e = e0; e < e1; ++e) {
        int c = colidx[e];
        float w = wcoef[e];
        float2 g = h2[c * 64 + lane];
        ax += w * g.x;
        ay += w * g.y;
    }
    ((float2*)hout)[node * 64 + lane] = make_float2(ax, ay);
}

// ---------------- score = h @ p / ||p|| ----------------
__global__ void score_kernel(const float* __restrict__ h, const float* __restrict__ p,
                             const float* __restrict__ pn, float* __restrict__ score) {
    int node = blockIdx.x * 4 + (threadIdx.x >> 6);
    int lane = threadIdx.x & 63;
    float2 a = ((const float2*)h)[node * 64 + lane];
    float2 b = ((const float2*)p)[lane];
    float v = a.x * b.x + a.y * b.y;
    v += __shfl_xor(v, 32, 64);
    v += __shfl_xor(v, 16, 64);
    v += __shfl_xor(v, 8, 64);
    v += __shfl_xor(v, 4, 64);
    v += __shfl_xor(v, 2, 64);
    v += __shfl_xor(v, 1, 64);
    if (lane == 0) score[node] = v / pn[0];
}

// ---------------- top-k pool: bitonic sort 1024 per graph ----------------
__global__ __launch_bounds__(256) void pool_kernel(const float* __restrict__ score, int npg, int k,
                            int* __restrict__ perm, float* __restrict__ gate,
                            int* __restrict__ remap) {
    __shared__ float sval[1024];
    __shared__ int sidx[1024];
    int b = blockIdx.x, t = threadIdx.x;
    for (int i = t; i < 1024; i += 256) {
        sval[i] = (i < npg) ? score[b * npg + i] : -INFINITY;
        sidx[i] = i;
    }
    __syncthreads();
    for (int ksz = 2; ksz <= 1024; ksz <<= 1) {
        for (int j = ksz >> 1; j > 0; j >>= 1) {
            for (int i = t; i < 1024; i += 256) {
                int l = i ^ j;
                if (l > i) {
                    float vi = sval[i], vl = sval[l];
                    bool up = ((i & ksz) == 0);
                    bool sw = up ? (vi < vl) : (vi > vl);   // descending sort
                    if (sw) {
                        sval[i] = vl; sval[l] = vi;
                        int tmp = sidx[i]; sidx[i] = sidx[l]; sidx[l] = tmp;
                    }
                }
            }
            __syncthreads();
        }
    }
    for (int i = t; i < k; i += 256) {
        int oldg = b * npg + sidx[i];
        int newg = b * k + i;
        perm[newg] = oldg;
        gate[newg] = tanhf(sval[i]);
        remap[oldg] = newg;
    }
}

// ---------------- gather new_x = h[perm] * gate ----------------
__global__ void newx_kernel(const float* __restrict__ h, const int* __restrict__ perm,
                            const float* __restrict__ gate, float* __restrict__ xo) {
    int m = blockIdx.x * 4 + (threadIdx.x >> 6);
    int lane = threadIdx.x & 63;
    int old = perm[m];
    float g = gate[m];
    float2 v = ((const float2*)h)[old * 64 + lane];
    ((float2*)xo)[m * 64 + lane] = make_float2(v.x * g, v.y * g);
}

// ---------------- readout: rsum[b] += [max over k ; mean over k] ----------------
__global__ void readout_kernel(const float* __restrict__ x, float* __restrict__ rsum, int k) {
    int b = blockIdx.x, f = threadIdx.x;   // 128 threads
    const float* base = x + (size_t)b * k * 128;
    float mx = -INFINITY, sm = 0.f;
#pragma unroll 4
    for (int j = 0; j < k; j++) {
        float v = base[j * 128 + f];
        mx = fmaxf(mx, v);
        sm += v;
    }
    rsum[b * 256 + f] += mx;
    rsum[b * 256 + 128 + f] += sm / (float)k;
}

// ---------------- edge remap + compact (hierarchical: 1 atomic per block) ----------------
__global__ __launch_bounds__(1024) void compact_kernel(
    const int* __restrict__ src, const int* __restrict__ dst,
    const int* __restrict__ ecnt, const int* __restrict__ remap,
    int* __restrict__ so, int* __restrict__ dd, int* __restrict__ ecout) {
    __shared__ int wcnt[16];
    __shared__ int bbase;
    int n = ecnt[0];
    int e = blockIdx.x * 1024 + threadIdx.x;
    int wave = threadIdx.x >> 6;
    int lane = threadIdx.x & 63;
    bool v = false;
    int s = 0, d = 0;
    if (e < n) {
        s = remap[src[e]];
        d = remap[dst[e]];
        v = ((s | d) >= 0);
    }
    unsigned long long m = __ballot(v);
    int before = __popcll(m & ((1ULL << lane) - 1ULL));
    if (lane == 0) wcnt[wave] = __popcll(m);
    __syncthreads();
    if (threadIdx.x == 0) {
        int tot = 0;
#pragma unroll
        for (int i = 0; i < 16; i++) { int c = wcnt[i]; wcnt[i] = tot; tot += c; }
        bbase = atomicAdd(ecout, tot);
    }
    __syncthreads();
    if (v) {
        int pos = bbase + wcnt[wave] + before;
        so[pos] = s;
        dd[pos] = d;
    }
}

// ---------------- final MLP ----------------
__global__ void mlp1_kernel(const float* __restrict__ z, const float* __restrict__ w,
                            const float* __restrict__ bias, float* __restrict__ o) {
    int b = blockIdx.x, f = threadIdx.x;   // 128
    float acc = bias[f];
    for (int kk = 0; kk < 256; kk++) acc += z[b * 256 + kk] * w[kk * 128 + f];
    o[b * 128 + f] = fmaxf(acc, 0.f);
}

__global__ void mlp2_kernel(const float* __restrict__ z, const float* __restrict__ w,
                            const float* __restrict__ bias, float* __restrict__ o) {
    int b = blockIdx.x, f = threadIdx.x;   // 64
    float acc = bias[f];
    for (int kk = 0; kk < 128; kk++) acc += z[b * 128 + kk] * w[kk * 64 + f];
    o[b * 64 + f] = fmaxf(acc, 0.f);
}

__global__ void mlp3_kernel(const float* __restrict__ z2, const float* __restrict__ w3,
                            const float* __restrict__ b3, float* __restrict__ out) {
    __shared__ float lg[10];
    __shared__ float ls;
    int b = blockIdx.x, t = threadIdx.x;   // 64
    if (t < 10) {
        float acc = b3[t];
        for (int kk = 0; kk < 64; kk++) acc += z2[b * 64 + kk] * w3[kk * 10 + t];
        lg[t] = acc;
    }
    __syncthreads();
    if (t == 0) {
        float m = lg[0];
        for (int c = 1; c < 10; c++) m = fmaxf(m, lg[c]);
        float s = 0.f;
        for (int c = 0; c < 10; c++) s += expf(lg[c] - m);
        ls = m + logf(s);
    }
    __syncthreads();
    if (t < 10) out[b * 10 + t] = lg[t] - ls;
}

// =====================================================================
extern "C" void kernel_launch(void* const* d_in, const int* in_sizes, int n_in,
                              void* d_out, int out_size, void* d_ws, size_t ws_size,
                              hipStream_t stream) {
    char* ws = (char*)d_ws;
    size_t off = 0;
    auto alloc = [&](size_t bytes) -> void* {
        void* p = ws + off;
        off += (bytes + 255) & ~(size_t)255;
        return p;
    };
    float* hA = (float*)alloc(64000UL * 128 * 4);
    float* hB = (float*)alloc(64000UL * 128 * 4);
    float* score = (float*)alloc(64000UL * 4);
    float* dinvb = (float*)alloc(64000UL * 4);
    int* deg = (int*)alloc(64000UL * 4);
    int* rowptr = (int*)alloc(64001UL * 4);
    int* cursor = (int*)alloc(64000UL * 4);
    int* part = (int*)alloc(1024);
    int* colidx = (int*)alloc((size_t)EMAX * 4);
    float* wcoef = (float*)alloc((size_t)EMAX * 4);
    int* srcA = (int*)alloc((size_t)EMAX * 4);
    int* dstA = (int*)alloc((size_t)EMAX * 4);
    int* srcB = (int*)alloc((size_t)EMAX * 4);
    int* dstB = (int*)alloc((size_t)EMAX * 4);
    int* perm = (int*)alloc(51200UL * 4);
    float* gate = (float*)alloc(51200UL * 4);
    int* remap = (int*)alloc(64000UL * 4);
    float* rsum = (float*)alloc(64UL * 256 * 4);
    float* z1 = (float*)alloc(64UL * 128 * 4);
    float* z2 = (float*)alloc(64UL * 64 * 4);
    float* pnorm = (float*)alloc(256);
    int* ecnt = (int*)alloc(256);
    (void)ws_size;  // requires ~92.5 MB

    const float* x0 = (const float*)d_in[0];
    const int* src0 = (const int*)d_in[1];
    const int* dst0 = (const int*)d_in[2];

    hipMemsetAsync(rsum, 0, 64 * 256 * 4, stream);
    init_ecnt_kernel<<<1, 64, 0, stream>>>(ecnt);
    pnorm_kernel<<<1, 128, 0, stream>>>((const float*)d_in[27], pnorm + 0);
    pnorm_kernel<<<1, 128, 0, stream>>>((const float*)d_in[28], pnorm + 1);
    pnorm_kernel<<<1, 128, 0, stream>>>((const float*)d_in[29], pnorm + 2);

    auto run_layer = [&](int n, int npg, int k, const float* x,
                         const int* esrc, const int* edst, const int* ecin,
                         const float* wa, const float* ba, const float* wb, const float* bb,
                         const float* wc, const float* bc, const float* p, const float* pn,
                         int* so, int* ddst, int* ecout) {
        hipMemsetAsync(deg, 0, (size_t)n * 4, stream);
        count_kernel<<<EMAX / 256, 256, 0, stream>>>(edst, ecin, deg);
        dinv_kernel<<<n / 256, 256, 0, stream>>>(deg, dinvb);
        scan1_kernel<<<n / 256, 256, 0, stream>>>(deg, rowptr, part);
        scan2_kernel<<<1, 256, 0, stream>>>(part, rowptr, n / 256, n);
        scan3_kernel<<<n / 256, 256, 0, stream>>>(rowptr, cursor, part);
        scatter_kernel<<<EMAX / 256, 256, 0, stream>>>(esrc, edst, ecin, cursor, dinvb,
                                                       colidx, wcoef);
        gemm3_kernel<<<n / 64, 256, 0, stream>>>(x, wa, ba, wb, bb, wc, bc, hA);
        prop_kernel<<<n / 4, 256, 0, stream>>>(hA, hB, rowptr, colidx, wcoef, dinvb, n);
        prop_kernel<<<n / 4, 256, 0, stream>>>(hB, hA, rowptr, colidx, wcoef, dinvb, n);
        score_kernel<<<n / 4, 256, 0, stream>>>(hA, p, pn, score);
        hipMemsetAsync(remap, 0xFF, (size_t)n * 4, stream);
        pool_kernel<<<BGR, 256, 0, stream>>>(score, npg, k, perm, gate, remap);
        newx_kernel<<<(BGR * k) / 4, 256, 0, stream>>>(hA, perm, gate, hB);
        readout_kernel<<<BGR, 128, 0, stream>>>(hB, rsum, k);
        if (ecout)
            compact_kernel<<<EMAX / 1024, 1024, 0, stream>>>(esrc, edst, ecin, remap, so, ddst,
                                                             ecout);
    };

    run_layer(64000, 1000, 800, x0, src0, dst0, ecnt + 0,
              (const float*)d_in[3], (const float*)d_in[4], (const float*)d_in[5],
              (const float*)d_in[6], (const float*)d_in[7], (const float*)d_in[8],
              (const float*)d_in[27], pnorm + 0, srcA, dstA, ecnt + 1);

    run_layer(51200, 800, 640, hB, srcA, dstA, ecnt + 1,
              (const float*)d_in[9], (const float*)d_in[10], (const float*)d_in[11],
              (const float*)d_in[12], (const float*)d_in[13], (const float*)d_in[14],
              (const float*)d_in[28], pnorm + 1, srcB, dstB, ecnt + 2);

    run_layer(40960, 640, 512, hB, srcB, dstB, ecnt + 2,
              (const float*)d_in[15], (const float*)d_in[16], (const float*)d_in[17],
              (const float*)d_in[18], (const float*)d_in[19], (const float*)d_in[20],
              (const float*)d_in[29], pnorm + 2, nullptr, nullptr, nullptr);

    mlp1_kernel<<<64, 128, 0, stream>>>(rsum, (const float*)d_in[21], (const float*)d_in[22], z1);
    mlp2_kernel<<<64, 64, 0, stream>>>(z1, (const float*)d_in[23], (const float*)d_in[24], z2);
    mlp3_kernel<<<64, 64, 0, stream>>>(z2, (const float*)d_in[25], (const float*)d_in[26],
                                       (float*)d_out);
}

// Round 3
// 1023.638 us; speedup vs baseline: 1.6010x; 1.3084x over previous
//
#include <hip/hip_runtime.h>
#include <hip/hip_bf16.h>
#include <math.h>

#define BGR 64
#define EMAX 1024000

// ---------------- small init ----------------
__global__ void init_ecnt_kernel(int* ecnt) {
    if (threadIdx.x == 0) { ecnt[0] = EMAX; ecnt[1] = 0; ecnt[2] = 0; }
}

__global__ void pnorm_kernel(const float* __restrict__ p, float* __restrict__ out) {
    __shared__ float buf[128];
    int t = threadIdx.x;
    float v = p[t];
    buf[t] = v * v;
    __syncthreads();
    for (int off = 64; off; off >>= 1) {
        if (t < off) buf[t] += buf[t + off];
        __syncthreads();
    }
    if (t == 0) out[0] = sqrtf(buf[0]);
}

// ---------------- degree / CSR build ----------------
__global__ void count_kernel(const int* __restrict__ dst, const int* __restrict__ ecnt,
                             int* __restrict__ deg) {
    int e = blockIdx.x * 256 + threadIdx.x;
    if (e >= ecnt[0]) return;
    atomicAdd(&deg[dst[e]], 1);
}

__global__ void dinv_kernel(const int* __restrict__ deg, float* __restrict__ dinv) {
    int i = blockIdx.x * 256 + threadIdx.x;
    dinv[i] = rsqrtf((float)deg[i] + 1.0f);
}

__global__ void scan1_kernel(const int* __restrict__ deg, int* __restrict__ rowptr,
                             int* __restrict__ part) {
    __shared__ int buf[256];
    int t = threadIdx.x;
    int i = blockIdx.x * 256 + t;
    int v = deg[i];
    buf[t] = v;
    __syncthreads();
    for (int off = 1; off < 256; off <<= 1) {
        int tmp = (t >= off) ? buf[t - off] : 0;
        __syncthreads();
        buf[t] += tmp;
        __syncthreads();
    }
    rowptr[i] = buf[t] - v;
    if (t == 255) part[blockIdx.x] = buf[255];
}

__global__ void scan2_kernel(int* __restrict__ part, int* __restrict__ rowptr, int nb, int n) {
    __shared__ int buf[256];
    int t = threadIdx.x;
    int v = (t < nb) ? part[t] : 0;
    buf[t] = v;
    __syncthreads();
    for (int off = 1; off < 256; off <<= 1) {
        int tmp = (t >= off) ? buf[t - off] : 0;
        __syncthreads();
        buf[t] += tmp;
        __syncthreads();
    }
    if (t < nb) part[t] = buf[t] - v;
    if (t == 255) rowptr[n] = buf[255];
}

__global__ void scan3_kernel(int* __restrict__ rowptr, int* __restrict__ cursor,
                             const int* __restrict__ part) {
    int i = blockIdx.x * 256 + threadIdx.x;
    int v = rowptr[i] + part[blockIdx.x];
    rowptr[i] = v;
    cursor[i] = v;
}

__global__ void scatter_kernel(const int* __restrict__ src, const int* __restrict__ dst,
                               const int* __restrict__ ecnt, int* __restrict__ cursor,
                               const float* __restrict__ dinv, int* __restrict__ colidx,
                               float* __restrict__ wcoef) {
    int e = blockIdx.x * 256 + threadIdx.x;
    if (e >= ecnt[0]) return;
    int s = src[e], d = dst[e];
    int pos = atomicAdd(&cursor[d], 1);
    colidx[pos] = s;
    wcoef[pos] = dinv[s] * dinv[d];
}

// ---------------- fused 3-branch GEMM + bias + relu + sum ----------------
// LDS = 32KB x-tile + 16KB w-chunk = 48KB -> 3 blocks/CU (was 64KB -> 2)
__global__ __launch_bounds__(256) void gemm3_kernel(
    const float* __restrict__ x,
    const float* __restrict__ w0, const float* __restrict__ b0,
    const float* __restrict__ w1, const float* __restrict__ b1,
    const float* __restrict__ w2, const float* __restrict__ b2,
    float* __restrict__ out) {
    __shared__ float4 xs[2048];   // 64 rows x 32 float4 (full K)      32KB
    __shared__ float4 ws[1024];   // 32 kk  x 32 float4 (quarter K)    16KB
    const int tid = threadIdx.x;
    const int ty = tid >> 5;      // 0..7  node group (8 nodes each)
    const int tx = tid & 31;      // 0..31 feature group (4 feats)
    const long base = (long)blockIdx.x * 64;

    const float4* xg = (const float4*)(x + base * 128);
    for (int i = tid; i < 2048; i += 256) xs[i] = xg[i];

    float tot[8][4];
#pragma unroll
    for (int m = 0; m < 8; m++) { tot[m][0] = 0.f; tot[m][1] = 0.f; tot[m][2] = 0.f; tot[m][3] = 0.f; }

    const float* wj[3] = {w0, w1, w2};
    const float* bj[3] = {b0, b1, b2};

    for (int j = 0; j < 3; j++) {
        float acc[8][4];
#pragma unroll
        for (int m = 0; m < 8; m++) { acc[m][0] = 0.f; acc[m][1] = 0.f; acc[m][2] = 0.f; acc[m][3] = 0.f; }
        for (int kc = 0; kc < 128; kc += 32) {
            __syncthreads();
            const float4* wh = (const float4*)(wj[j] + kc * 128);
            for (int i = tid; i < 1024; i += 256) ws[i] = wh[i];
            __syncthreads();
            for (int c4 = 0; c4 < 8; c4++) {
                float4 xr[8];
#pragma unroll
                for (int m = 0; m < 8; m++) xr[m] = xs[(ty * 8 + m) * 32 + (kc >> 2) + c4];
#pragma unroll
                for (int r = 0; r < 4; r++) {
                    float4 wv = ws[(c4 * 4 + r) * 32 + tx];
#pragma unroll
                    for (int m = 0; m < 8; m++) {
                        float xv = (r == 0) ? xr[m].x : (r == 1) ? xr[m].y : (r == 2) ? xr[m].z : xr[m].w;
                        acc[m][0] += xv * wv.x;
                        acc[m][1] += xv * wv.y;
                        acc[m][2] += xv * wv.z;
                        acc[m][3] += xv * wv.w;
                    }
                }
            }
        }
        float4 bv = ((const float4*)bj[j])[tx];
#pragma unroll
        for (int m = 0; m < 8; m++) {
            tot[m][0] += fmaxf(acc[m][0] + bv.x, 0.f);
            tot[m][1] += fmaxf(acc[m][1] + bv.y, 0.f);
            tot[m][2] += fmaxf(acc[m][2] + bv.z, 0.f);
            tot[m][3] += fmaxf(acc[m][3] + bv.w, 0.f);
        }
    }
    float4* og = (float4*)(out + base * 128);
#pragma unroll
    for (int m = 0; m < 8; m++)
        og[(ty * 8 + m) * 32 + tx] = make_float4(tot[m][0], tot[m][1], tot[m][2], tot[m][3]);
}

// ---------------- propagation: hout = hin*(1+dinv^2) + sum_e w[e]*hin[col[e]] ----------------
// XCD-swizzled blocks: each XCD owns a contiguous n/8 node slice (8 graphs, 4MB -> L2-resident)
// 4x edge unroll: 4 independent gathers in flight per wave
__global__ __launch_bounds__(256) void prop_kernel(
    const float* __restrict__ hin, float* __restrict__ hout,
    const int* __restrict__ rowptr, const int* __restrict__ colidx,
    const float* __restrict__ wcoef, const float* __restrict__ dinv, int n) {
    int per = gridDim.x >> 3;                       // gridDim divisible by 8
    int b = blockIdx.x;
    int sb = (b & 7) * per + (b >> 3);              // XCD = blockIdx%8 round-robin
    int node = sb * 4 + (threadIdx.x >> 6);
    int lane = threadIdx.x & 63;
    const float2* h2 = (const float2*)hin;
    float di = dinv[node];
    float selfc = 1.0f + di * di;
    float2 hv = h2[node * 64 + lane];
    float ax = hv.x * selfc, ay = hv.y * selfc;
    int e0 = rowptr[node], e1 = rowptr[node + 1];
    int e = e0;
    for (; e + 4 <= e1; e += 4) {
        int c0 = colidx[e], c1 = colidx[e + 1], c2 = colidx[e + 2], c3 = colidx[e + 3];
        float w0 = wcoef[e], w1 = wcoef[e + 1], w2 = wcoef[e + 2], w3 = wcoef[e + 3];
        float2 g0 = h2[c0 * 64 + lane];
        float2 g1 = h2[c1 * 64 + lane];
        float2 g2 = h2[c2 * 64 + lane];
        float2 g3 = h2[c3 * 64 + lane];
        ax += w0 * g0.x; ay += w0 * g0.y;
        ax += w1 * g1.x; ay += w1 * g1.y;
        ax += w2 * g2.x; ay += w2 * g2.y;
        ax += w3 * g3.x; ay += w3 * g3.y;
    }
    for (; e < e1; ++e) {
        int c = colidx[e];
        float w = wcoef[e];
        float2 g = h2[c * 64 + lane];
        ax += w * g.x; ay += w * g.y;
    }
    ((float2*)hout)[node * 64 + lane] = make_float2(ax, ay);
}

// ---------------- score = h @ p / ||p|| ----------------
__global__ void score_kernel(const float* __restrict__ h, const float* __restrict__ p,
                             const float* __restrict__ pn, float* __restrict__ score) {
    int node = blockIdx.x * 4 + (threadIdx.x >> 6);
    int lane = threadIdx.x & 63;
    float2 a = ((const float2*)h)[node * 64 + lane];
    float2 b = ((const float2*)p)[lane];
    float v = a.x * b.x + a.y * b.y;
    v += __shfl_xor(v, 32, 64);
    v += __shfl_xor(v, 16, 64);
    v += __shfl_xor(v, 8, 64);
    v += __shfl_xor(v, 4, 64);
    v += __shfl_xor(v, 2, 64);
    v += __shfl_xor(v, 1, 64);
    if (lane == 0) score[node] = v / pn[0];
}

// ---------------- top-k pool: bitonic sort 1024 per graph ----------------
__global__ __launch_bounds__(256) void pool_kernel(const float* __restrict__ score, int npg, int k,
                            int* __restrict__ perm, float* __restrict__ gate,
                            int* __restrict__ remap) {
    __shared__ float sval[1024];
    __shared__ int sidx[1024];
    int b = blockIdx.x, t = threadIdx.x;
    for (int i = t; i < 1024; i += 256) {
        sval[i] = (i < npg) ? score[b * npg + i] : -INFINITY;
        sidx[i] = i;
    }
    __syncthreads();
    for (int ksz = 2; ksz <= 1024; ksz <<= 1) {
        for (int j = ksz >> 1; j > 0; j >>= 1) {
            for (int i = t; i < 1024; i += 256) {
                int l = i ^ j;
                if (l > i) {
                    float vi = sval[i], vl = sval[l];
                    bool up = ((i & ksz) == 0);
                    bool sw = up ? (vi < vl) : (vi > vl);   // descending sort
                    if (sw) {
                        sval[i] = vl; sval[l] = vi;
                        int tmp = sidx[i]; sidx[i] = sidx[l]; sidx[l] = tmp;
                    }
                }
            }
            __syncthreads();
        }
    }
    for (int i = t; i < k; i += 256) {
        int oldg = b * npg + sidx[i];
        int newg = b * k + i;
        perm[newg] = oldg;
        gate[newg] = tanhf(sval[i]);
        remap[oldg] = newg;
    }
}

// ---------------- gather new_x = h[perm] * gate ----------------
__global__ void newx_kernel(const float* __restrict__ h, const int* __restrict__ perm,
                            const float* __restrict__ gate, float* __restrict__ xo) {
    int m = blockIdx.x * 4 + (threadIdx.x >> 6);
    int lane = threadIdx.x & 63;
    int old = perm[m];
    float g = gate[m];
    float2 v = ((const float2*)h)[old * 64 + lane];
    ((float2*)xo)[m * 64 + lane] = make_float2(v.x * g, v.y * g);
}

// ---------------- readout: rsum[b] += [max over k ; mean over k] ----------------
__global__ void readout_kernel(const float* __restrict__ x, float* __restrict__ rsum, int k) {
    int b = blockIdx.x, f = threadIdx.x;   // 128 threads
    const float* base = x + (size_t)b * k * 128;
    float mx = -INFINITY, sm = 0.f;
#pragma unroll 4
    for (int j = 0; j < k; j++) {
        float v = base[j * 128 + f];
        mx = fmaxf(mx, v);
        sm += v;
    }
    rsum[b * 256 + f] += mx;
    rsum[b * 256 + 128 + f] += sm / (float)k;
}

// ---------------- edge remap + compact (hierarchical: 1 atomic per block) ----------------
__global__ __launch_bounds__(1024) void compact_kernel(
    const int* __restrict__ src, const int* __restrict__ dst,
    const int* __restrict__ ecnt, const int* __restrict__ remap,
    int* __restrict__ so, int* __restrict__ dd, int* __restrict__ ecout) {
    __shared__ int wcnt[16];
    __shared__ int bbase;
    int n = ecnt[0];
    int e = blockIdx.x * 1024 + threadIdx.x;
    int wave = threadIdx.x >> 6;
    int lane = threadIdx.x & 63;
    bool v = false;
    int s = 0, d = 0;
    if (e < n) {
        s = remap[src[e]];
        d = remap[dst[e]];
        v = ((s | d) >= 0);
    }
    unsigned long long m = __ballot(v);
    int before = __popcll(m & ((1ULL << lane) - 1ULL));
    if (lane == 0) wcnt[wave] = __popcll(m);
    __syncthreads();
    if (threadIdx.x == 0) {
        int tot = 0;
#pragma unroll
        for (int i = 0; i < 16; i++) { int c = wcnt[i]; wcnt[i] = tot; tot += c; }
        bbase = atomicAdd(ecout, tot);
    }
    __syncthreads();
    if (v) {
        int pos = bbase + wcnt[wave] + before;
        so[pos] = s;
        dd[pos] = d;
    }
}

// ---------------- final MLP ----------------
__global__ void mlp1_kernel(const float* __restrict__ z, const float* __restrict__ w,
                            const float* __restrict__ bias, float* __restrict__ o) {
    int b = blockIdx.x, f = threadIdx.x;   // 128
    float acc = bias[f];
    for (int kk = 0; kk < 256; kk++) acc += z[b * 256 + kk] * w[kk * 128 + f];
    o[b * 128 + f] = fmaxf(acc, 0.f);
}

__global__ void mlp2_kernel(const float* __restrict__ z, const float* __restrict__ w,
                            const float* __restrict__ bias, float* __restrict__ o) {
    int b = blockIdx.x, f = threadIdx.x;   // 64
    float acc = bias[f];
    for (int kk = 0; kk < 128; kk++) acc += z[b * 128 + kk] * w[kk * 64 + f];
    o[b * 64 + f] = fmaxf(acc, 0.f);
}

__global__ void mlp3_kernel(const float* __restrict__ z2, const float* __restrict__ w3,
                            const float* __restrict__ b3, float* __restrict__ out) {
    __shared__ float lg[10];
    __shared__ float ls;
    int b = blockIdx.x, t = threadIdx.x;   // 64
    if (t < 10) {
        float acc = b3[t];
        for (int kk = 0; kk < 64; kk++) acc += z2[b * 64 + kk] * w3[kk * 10 + t];
        lg[t] = acc;
    }
    __syncthreads();
    if (t == 0) {
        float m = lg[0];
        for (int c = 1; c < 10; c++) m = fmaxf(m, lg[c]);
        float s = 0.f;
        for (int c = 0; c < 10; c++) s += expf(lg[c] - m);
        ls = m + logf(s);
    }
    __syncthreads();
    if (t < 10) out[b * 10 + t] = lg[t] - ls;
}

// =====================================================================
extern "C" void kernel_launch(void* const* d_in, const int* in_sizes, int n_in,
                              void* d_out, int out_size, void* d_ws, size_t ws_size,
                              hipStream_t stream) {
    char* ws = (char*)d_ws;
    size_t off = 0;
    auto alloc = [&](size_t bytes) -> void* {
        void* p = ws + off;
        off += (bytes + 255) & ~(size_t)255;
        return p;
    };
    float* hA = (float*)alloc(64000UL * 128 * 4);
    float* hB = (float*)alloc(64000UL * 128 * 4);
    float* score = (float*)alloc(64000UL * 4);
    float* dinvb = (float*)alloc(64000UL * 4);
    int* deg = (int*)alloc(64000UL * 4);
    int* rowptr = (int*)alloc(64001UL * 4);
    int* cursor = (int*)alloc(64000UL * 4);
    int* part = (int*)alloc(1024);
    int* colidx = (int*)alloc((size_t)EMAX * 4);
    float* wcoef = (float*)alloc((size_t)EMAX * 4);
    int* srcA = (int*)alloc((size_t)EMAX * 4);
    int* dstA = (int*)alloc((size_t)EMAX * 4);
    int* srcB = (int*)alloc((size_t)EMAX * 4);
    int* dstB = (int*)alloc((size_t)EMAX * 4);
    int* perm = (int*)alloc(51200UL * 4);
    float* gate = (float*)alloc(51200UL * 4);
    int* remap = (int*)alloc(64000UL * 4);
    float* rsum = (float*)alloc(64UL * 256 * 4);
    float* z1 = (float*)alloc(64UL * 128 * 4);
    float* z2 = (float*)alloc(64UL * 64 * 4);
    float* pnorm = (float*)alloc(256);
    int* ecnt = (int*)alloc(256);
    (void)ws_size;  // requires ~92.5 MB

    const float* x0 = (const float*)d_in[0];
    const int* src0 = (const int*)d_in[1];
    const int* dst0 = (const int*)d_in[2];

    hipMemsetAsync(rsum, 0, 64 * 256 * 4, stream);
    init_ecnt_kernel<<<1, 64, 0, stream>>>(ecnt);
    pnorm_kernel<<<1, 128, 0, stream>>>((const float*)d_in[27], pnorm + 0);
    pnorm_kernel<<<1, 128, 0, stream>>>((const float*)d_in[28], pnorm + 1);
    pnorm_kernel<<<1, 128, 0, stream>>>((const float*)d_in[29], pnorm + 2);

    auto run_layer = [&](int n, int npg, int k, const float* x,
                         const int* esrc, const int* edst, const int* ecin,
                         const float* wa, const float* ba, const float* wb, const float* bb,
                         const float* wc, const float* bc, const float* p, const float* pn,
                         int* so, int* ddst, int* ecout) {
        hipMemsetAsync(deg, 0, (size_t)n * 4, stream);
        count_kernel<<<EMAX / 256, 256, 0, stream>>>(edst, ecin, deg);
        dinv_kernel<<<n / 256, 256, 0, stream>>>(deg, dinvb);
        scan1_kernel<<<n / 256, 256, 0, stream>>>(deg, rowptr, part);
        scan2_kernel<<<1, 256, 0, stream>>>(part, rowptr, n / 256, n);
        scan3_kernel<<<n / 256, 256, 0, stream>>>(rowptr, cursor, part);
        scatter_kernel<<<EMAX / 256, 256, 0, stream>>>(esrc, edst, ecin, cursor, dinvb,
                                                       colidx, wcoef);
        gemm3_kernel<<<n / 64, 256, 0, stream>>>(x, wa, ba, wb, bb, wc, bc, hA);
        prop_kernel<<<n / 4, 256, 0, stream>>>(hA, hB, rowptr, colidx, wcoef, dinvb, n);
        prop_kernel<<<n / 4, 256, 0, stream>>>(hB, hA, rowptr, colidx, wcoef, dinvb, n);
        score_kernel<<<n / 4, 256, 0, stream>>>(hA, p, pn, score);
        hipMemsetAsync(remap, 0xFF, (size_t)n * 4, stream);
        pool_kernel<<<BGR, 256, 0, stream>>>(score, npg, k, perm, gate, remap);
        newx_kernel<<<(BGR * k) / 4, 256, 0, stream>>>(hA, perm, gate, hB);
        readout_kernel<<<BGR, 128, 0, stream>>>(hB, rsum, k);
        if (ecout)
            compact_kernel<<<EMAX / 1024, 1024, 0, stream>>>(esrc, edst, ecin, remap, so, ddst,
                                                             ecout);
    };

    run_layer(64000, 1000, 800, x0, src0, dst0, ecnt + 0,
              (const float*)d_in[3], (const float*)d_in[4], (const float*)d_in[5],
              (const float*)d_in[6], (const float*)d_in[7], (const float*)d_in[8],
              (const float*)d_in[27], pnorm + 0, srcA, dstA, ecnt + 1);

    run_layer(51200, 800, 640, hB, srcA, dstA, ecnt + 1,
              (const float*)d_in[9], (const float*)d_in[10], (const float*)d_in[11],
              (const float*)d_in[12], (const float*)d_in[13], (const float*)d_in[14],
              (const float*)d_in[28], pnorm + 1, srcB, dstB, ecnt + 2);

    run_layer(40960, 640, 512, hB, srcB, dstB, ecnt + 2,
              (const float*)d_in[15], (const float*)d_in[16], (const float*)d_in[17],
              (const float*)d_in[18], (const float*)d_in[19], (const float*)d_in[20],
              (const float*)d_in[29], pnorm + 2, nullptr, nullptr, nullptr);

    mlp1_kernel<<<64, 128, 0, stream>>>(rsum, (const float*)d_in[21], (const float*)d_in[22], z1);
    mlp2_kernel<<<64, 64, 0, stream>>>(z1, (const float*)d_in[23], (const float*)d_in[24], z2);
    mlp3_kernel<<<64, 64, 0, stream>>>(z2, (const float*)d_in[25], (const float*)d_in[26],
                                       (float*)d_out);
}

// Round 4
// 866.682 us; speedup vs baseline: 1.8909x; 1.1811x over previous
//
#include <hip/hip_runtime.h>
#include <hip/hip_bf16.h>
#include <math.h>

#define BGR 64
#define EMAX 1024000

typedef _Float16 f16x8 __attribute__((ext_vector_type(8)));
typedef float f32x4 __attribute__((ext_vector_type(4)));

// ---------------- small init ----------------
__global__ void init_ecnt_kernel(int* ecnt) {
    if (threadIdx.x == 0) { ecnt[0] = EMAX; ecnt[1] = 0; ecnt[2] = 0; }
}

__global__ void pnorm_kernel(const float* __restrict__ p, float* __restrict__ out) {
    __shared__ float buf[128];
    int t = threadIdx.x;
    float v = p[t];
    buf[t] = v * v;
    __syncthreads();
    for (int off = 64; off; off >>= 1) {
        if (t < off) buf[t] += buf[t + off];
        __syncthreads();
    }
    if (t == 0) out[0] = sqrtf(buf[0]);
}

// ---------------- weight split: f32 [k][n] -> f16 hi/lo chunk-major ----------------
// per matrix layout: [ks(4)][half(2)][kg(4)][n(128)][8]  (chunk (br,ks) = 16KB contiguous)
struct WP { const float* w[9]; };

__global__ void wsplit_kernel(WP wp, _Float16* __restrict__ out) {
    int mat = blockIdx.x;
    const float* __restrict__ w = wp.w[mat];
    _Float16* __restrict__ dst = out + (size_t)mat * 32768;
    for (int e = threadIdx.x; e < 2048; e += 256) {
        int n = e >> 4;
        int kb = (e & 15) * 8;
        f16x8 hi, lo;
#pragma unroll
        for (int j = 0; j < 8; j++) {
            float v = w[(kb + j) * 128 + n];
            _Float16 h = (_Float16)v;
            hi[j] = h;
            lo[j] = (_Float16)((v - (float)h) * 2048.0f);
        }
        int ks = kb >> 5, kg = (kb >> 3) & 3;
        *(f16x8*)(dst + ((((ks * 2 + 0) * 4 + kg) * 128 + n) * 8)) = hi;
        *(f16x8*)(dst + ((((ks * 2 + 1) * 4 + kg) * 128 + n) * 8)) = lo;
    }
}

// ---------------- degree / CSR build ----------------
__global__ void count_kernel(const int* __restrict__ dst, const int* __restrict__ ecnt,
                             int* __restrict__ deg) {
    int e = blockIdx.x * 256 + threadIdx.x;
    if (e >= ecnt[0]) return;
    atomicAdd(&deg[dst[e]], 1);
}

__global__ void scan1_kernel(const int* __restrict__ deg, int* __restrict__ rowptr,
                             int* __restrict__ part, float* __restrict__ dinv) {
    __shared__ int buf[256];
    int t = threadIdx.x;
    int i = blockIdx.x * 256 + t;
    int v = deg[i];
    dinv[i] = rsqrtf((float)v + 1.0f);
    buf[t] = v;
    __syncthreads();
    for (int off = 1; off < 256; off <<= 1) {
        int tmp = (t >= off) ? buf[t - off] : 0;
        __syncthreads();
        buf[t] += tmp;
        __syncthreads();
    }
    rowptr[i] = buf[t] - v;
    if (t == 255) part[blockIdx.x] = buf[255];
}

__global__ void scan2_kernel(int* __restrict__ part, int* __restrict__ rowptr, int nb, int n) {
    __shared__ int buf[256];
    int t = threadIdx.x;
    int v = (t < nb) ? part[t] : 0;
    buf[t] = v;
    __syncthreads();
    for (int off = 1; off < 256; off <<= 1) {
        int tmp = (t >= off) ? buf[t - off] : 0;
        __syncthreads();
        buf[t] += tmp;
        __syncthreads();
    }
    if (t < nb) part[t] = buf[t] - v;
    if (t == 255) rowptr[n] = buf[255];
}

__global__ void scan3_kernel(int* __restrict__ rowptr, int* __restrict__ cursor,
                             const int* __restrict__ part) {
    int i = blockIdx.x * 256 + threadIdx.x;
    int v = rowptr[i] + part[blockIdx.x];
    rowptr[i] = v;
    cursor[i] = v;
}

__global__ void scatter_kernel(const int* __restrict__ src, const int* __restrict__ dst,
                               const int* __restrict__ ecnt, int* __restrict__ cursor,
                               const float* __restrict__ dinv, int* __restrict__ colidx,
                               float* __restrict__ wcoef) {
    int e = blockIdx.x * 256 + threadIdx.x;
    if (e >= ecnt[0]) return;
    int s = src[e], d = dst[e];
    int pos = atomicAdd(&cursor[d], 1);
    colidx[pos] = s;
    wcoef[pos] = dinv[s] * dinv[d];
}

// ---------------- fused 3-branch MFMA GEMM (f16 split, f32-equivalent accuracy) ----------
// H = relu(x@wa+ba)+relu(x@wb+bb)+relu(x@wc+bc); x:[n,128] f32, out f32
// block 256 thr / 4 waves; wave = 16 rows; 16x16x32 f16 MFMA; W double-buffered in LDS.
__global__ __launch_bounds__(256) void gemm3m_kernel(
    const float* __restrict__ x, const _Float16* __restrict__ wsp,
    const float* __restrict__ b0, const float* __restrict__ b1, const float* __restrict__ b2,
    float* __restrict__ out) {
    __shared__ _Float16 ws[2][8192] __attribute__((aligned(16)));
    const int tid = threadIdx.x;
    const int wave = tid >> 6;
    const int lane = tid & 63;
    const int l15 = lane & 15;
    const int kg = lane >> 4;          // 0..3
    const long base = (long)blockIdx.x * 64;
    const int m = wave * 16 + l15;     // row within block tile

    // ---- load this lane's x row pieces (8 consecutive f32 per ks) ----
    float4 xrow[8];
    const float4* xg = (const float4*)(x + (base + m) * 128);
#pragma unroll
    for (int q = 0; q < 8; q++) xrow[q] = xg[(q >> 1) * 8 + kg * 2 + (q & 1)];

    // ---- staging helper ----
    auto stage = [&](int c, int buf) {
#pragma unroll
        for (int t = 0; t < 4; t++) {
            int u = tid + t * 256;
            __builtin_amdgcn_global_load_lds(
                (const __attribute__((address_space(1))) unsigned int*)(wsp + (size_t)c * 8192 + u * 8),
                (__attribute__((address_space(3))) unsigned int*)(&ws[buf][u * 8]),
                16, 0, 0);
        }
    };

    float tot[8][4];
#pragma unroll
    for (int nt = 0; nt < 8; nt++)
#pragma unroll
        for (int r = 0; r < 4; r++) tot[nt][r] = 0.f;

    f32x4 acc_h[8], acc_m[8];
    stage(0, 0);

#pragma unroll
    for (int c = 0; c < 12; c++) {
        const int br = c >> 2, ks = c & 3, buf = c & 1;
        if (ks == 0) {
#pragma unroll
            for (int nt = 0; nt < 8; nt++) {
                acc_h[nt] = (f32x4){0.f, 0.f, 0.f, 0.f};
                acc_m[nt] = (f32x4){0.f, 0.f, 0.f, 0.f};
            }
        }
        __syncthreads();                       // chunk c ready; prev buf free
        if (c < 11) stage(c + 1, buf ^ 1);

        // A fragments (hi / scaled-lo) from registers
        float ev[8] = {xrow[ks * 2].x, xrow[ks * 2].y, xrow[ks * 2].z, xrow[ks * 2].w,
                       xrow[ks * 2 + 1].x, xrow[ks * 2 + 1].y, xrow[ks * 2 + 1].z, xrow[ks * 2 + 1].w};
        f16x8 ah, al;
#pragma unroll
        for (int i = 0; i < 8; i++) {
            _Float16 h = (_Float16)ev[i];
            ah[i] = h;
            al[i] = (_Float16)((ev[i] - (float)h) * 2048.0f);
        }

        const _Float16* wb = &ws[buf][0];
        const int nb = kg * 1024 + l15 * 8;
        f16x8 bh[8], bl[8];
#pragma unroll
        for (int nt = 0; nt < 8; nt++) {
            bh[nt] = *(const f16x8*)(wb + nb + nt * 128);
            bl[nt] = *(const f16x8*)(wb + 4096 + nb + nt * 128);
        }
#pragma unroll
        for (int nt = 0; nt < 8; nt++)
            acc_h[nt] = __builtin_amdgcn_mfma_f32_16x16x32_f16(ah, bh[nt], acc_h[nt], 0, 0, 0);
#pragma unroll
        for (int nt = 0; nt < 8; nt++)
            acc_m[nt] = __builtin_amdgcn_mfma_f32_16x16x32_f16(ah, bl[nt], acc_m[nt], 0, 0, 0);
#pragma unroll
        for (int nt = 0; nt < 8; nt++)
            acc_m[nt] = __builtin_amdgcn_mfma_f32_16x16x32_f16(al, bh[nt], acc_m[nt], 0, 0, 0);

        if (ks == 3) {
            const float* bb = (br == 0) ? b0 : (br == 1) ? b1 : b2;
#pragma unroll
            for (int nt = 0; nt < 8; nt++) {
                float bv = bb[nt * 16 + l15];
#pragma unroll
                for (int r = 0; r < 4; r++)
                    tot[nt][r] += fmaxf(acc_h[nt][r] + acc_m[nt][r] * (1.0f / 2048.0f) + bv, 0.f);
            }
        }
    }

    // D layout: col = lane&15, row = kg*4 + r
    float* op = out + (base + wave * 16 + kg * 4) * 128 + l15;
#pragma unroll
    for (int nt = 0; nt < 8; nt++)
#pragma unroll
        for (int r = 0; r < 4; r++) op[r * 128 + nt * 16] = tot[nt][r];
}

// ---------------- propagation (+optional fused score) ----------------
// hout = hin*(1+dinv^2) + sum_e w[e]*hin[col[e]]; 8-deep gather pipeline; XCD swizzle
template <int SC>
__global__ __launch_bounds__(256) void prop_t(
    const float* __restrict__ hin, float* __restrict__ hout,
    const int* __restrict__ rowptr, const int* __restrict__ colidx,
    const float* __restrict__ wcoef, const float* __restrict__ dinv,
    const float* __restrict__ p, const float* __restrict__ pn, float* __restrict__ score) {
    int per = gridDim.x >> 3;
    int b = blockIdx.x;
    int sb = (b & 7) * per + (b >> 3);
    int node = sb * 4 + (threadIdx.x >> 6);
    int lane = threadIdx.x & 63;
    const float2* h2 = (const float2*)hin;
    float di = dinv[node];
    float selfc = 1.0f + di * di;
    float2 hv = h2[node * 64 + lane];
    float ax = hv.x * selfc, ay = hv.y * selfc;
    int e0 = rowptr[node], e1 = rowptr[node + 1];
    int e = e0;
    for (; e + 8 <= e1; e += 8) {
        int cc[8];
        float ww[8];
        float2 gg[8];
#pragma unroll
        for (int j = 0; j < 8; j++) { cc[j] = colidx[e + j]; ww[j] = wcoef[e + j]; }
#pragma unroll
        for (int j = 0; j < 8; j++) gg[j] = h2[(long)cc[j] * 64 + lane];
#pragma unroll
        for (int j = 0; j < 8; j++) { ax += ww[j] * gg[j].x; ay += ww[j] * gg[j].y; }
    }
    for (; e + 2 <= e1; e += 2) {
        int c0 = colidx[e], c1 = colidx[e + 1];
        float w0 = wcoef[e], w1 = wcoef[e + 1];
        float2 g0 = h2[(long)c0 * 64 + lane];
        float2 g1 = h2[(long)c1 * 64 + lane];
        ax += w0 * g0.x; ay += w0 * g0.y;
        ax += w1 * g1.x; ay += w1 * g1.y;
    }
    if (e < e1) {
        int c = colidx[e];
        float w = wcoef[e];
        float2 g = h2[(long)c * 64 + lane];
        ax += w * g.x; ay += w * g.y;
    }
    ((float2*)hout)[node * 64 + lane] = make_float2(ax, ay);
    if (SC) {
        float2 pv = ((const float2*)p)[lane];
        float v = ax * pv.x + ay * pv.y;
        v += __shfl_xor(v, 32);
        v += __shfl_xor(v, 16);
        v += __shfl_xor(v, 8);
        v += __shfl_xor(v, 4);
        v += __shfl_xor(v, 2);
        v += __shfl_xor(v, 1);
        if (lane == 0) score[node] = v / pn[0];
    }
}

// ---------------- top-k pool: bitonic sort 1024 per graph ----------------
__global__ __launch_bounds__(256) void pool_kernel(const float* __restrict__ score, int npg, int k,
                            int* __restrict__ perm, float* __restrict__ gate,
                            int* __restrict__ remap) {
    __shared__ float sval[1024];
    __shared__ int sidx[1024];
    int b = blockIdx.x, t = threadIdx.x;
    for (int i = t; i < 1024; i += 256) {
        sval[i] = (i < npg) ? score[b * npg + i] : -INFINITY;
        sidx[i] = i;
    }
    __syncthreads();
    for (int ksz = 2; ksz <= 1024; ksz <<= 1) {
        for (int j = ksz >> 1; j > 0; j >>= 1) {
            for (int i = t; i < 1024; i += 256) {
                int l = i ^ j;
                if (l > i) {
                    float vi = sval[i], vl = sval[l];
                    bool up = ((i & ksz) == 0);
                    bool sw = up ? (vi < vl) : (vi > vl);   // descending sort
                    if (sw) {
                        sval[i] = vl; sval[l] = vi;
                        int tmp = sidx[i]; sidx[i] = sidx[l]; sidx[l] = tmp;
                    }
                }
            }
            __syncthreads();
        }
    }
    for (int i = t; i < k; i += 256) {
        int oldg = b * npg + sidx[i];
        int newg = b * k + i;
        perm[newg] = oldg;
        gate[newg] = tanhf(sval[i]);
        remap[oldg] = newg;
    }
}

// ---------------- gather new_x = h[perm] * gate ----------------
__global__ void newx_kernel(const float* __restrict__ h, const int* __restrict__ perm,
                            const float* __restrict__ gate, float* __restrict__ xo) {
    int m = blockIdx.x * 4 + (threadIdx.x >> 6);
    int lane = threadIdx.x & 63;
    int old = perm[m];
    float g = gate[m];
    float2 v = ((const float2*)h)[old * 64 + lane];
    ((float2*)xo)[m * 64 + lane] = make_float2(v.x * g, v.y * g);
}

// ---------------- readout: rsum[b] += [max over k ; mean over k] ----------------
__global__ void readout_kernel(const float* __restrict__ x, float* __restrict__ rsum, int k) {
    int b = blockIdx.x, f = threadIdx.x;   // 128 threads
    const float* base = x + (size_t)b * k * 128;
    float mx = -INFINITY, sm = 0.f;
#pragma unroll 4
    for (int j = 0; j < k; j++) {
        float v = base[j * 128 + f];
        mx = fmaxf(mx, v);
        sm += v;
    }
    rsum[b * 256 + f] += mx;
    rsum[b * 256 + 128 + f] += sm / (float)k;
}

// ---------------- edge remap + compact (hierarchical: 1 atomic per block) ----------------
__global__ __launch_bounds__(1024) void compact_kernel(
    const int* __restrict__ src, const int* __restrict__ dst,
    const int* __restrict__ ecnt, const int* __restrict__ remap,
    int* __restrict__ so, int* __restrict__ dd, int* __restrict__ ecout) {
    __shared__ int wcnt[16];
    __shared__ int bbase;
    int n = ecnt[0];
    int e = blockIdx.x * 1024 + threadIdx.x;
    int wave = threadIdx.x >> 6;
    int lane = threadIdx.x & 63;
    bool v = false;
    int s = 0, d = 0;
    if (e < n) {
        s = remap[src[e]];
        d = remap[dst[e]];
        v = ((s | d) >= 0);
    }
    unsigned long long m = __ballot(v);
    int before = __popcll(m & ((1ULL << lane) - 1ULL));
    if (lane == 0) wcnt[wave] = __popcll(m);
    __syncthreads();
    if (threadIdx.x == 0) {
        int tot = 0;
#pragma unroll
        for (int i = 0; i < 16; i++) { int c = wcnt[i]; wcnt[i] = tot; tot += c; }
        bbase = atomicAdd(ecout, tot);
    }
    __syncthreads();
    if (v) {
        int pos = bbase + wcnt[wave] + before;
        so[pos] = s;
        dd[pos] = d;
    }
}

// ---------------- fused final MLP + log_softmax ----------------
__global__ void mlp_kernel(const float* __restrict__ rsum,
                           const float* __restrict__ w1, const float* __restrict__ b1,
                           const float* __restrict__ w2, const float* __restrict__ b2,
                           const float* __restrict__ w3, const float* __restrict__ b3,
                           float* __restrict__ out) {
    __shared__ float z0[256], z1l[128], z2l[64], lg[10], ls;
    int b = blockIdx.x, t = threadIdx.x;   // 128 threads
    z0[t] = rsum[b * 256 + t];
    z0[t + 128] = rsum[b * 256 + 128 + t];
    __syncthreads();
    float acc = b1[t];
    for (int k = 0; k < 256; k++) acc += z0[k] * w1[k * 128 + t];
    z1l[t] = fmaxf(acc, 0.f);
    __syncthreads();
    if (t < 64) {
        acc = b2[t];
        for (int k = 0; k < 128; k++) acc += z1l[k] * w2[k * 64 + t];
        z2l[t] = fmaxf(acc, 0.f);
    }
    __syncthreads();
    if (t < 10) {
        acc = b3[t];
        for (int k = 0; k < 64; k++) acc += z2l[k] * w3[k * 10 + t];
        lg[t] = acc;
    }
    __syncthreads();
    if (t == 0) {
        float mx = lg[0];
        for (int c = 1; c < 10; c++) mx = fmaxf(mx, lg[c]);
        float s = 0.f;
        for (int c = 0; c < 10; c++) s += expf(lg[c] - mx);
        ls = mx + logf(s);
    }
    __syncthreads();
    if (t < 10) out[b * 10 + t] = lg[t] - ls;
}

// =====================================================================
extern "C" void kernel_launch(void* const* d_in, const int* in_sizes, int n_in,
                              void* d_out, int out_size, void* d_ws, size_t ws_size,
                              hipStream_t stream) {
    char* ws = (char*)d_ws;
    size_t off = 0;
    auto alloc = [&](size_t bytes) -> void* {
        void* p = ws + off;
        off += (bytes + 255) & ~(size_t)255;
        return p;
    };
    float* hA = (float*)alloc(64000UL * 128 * 4);
    float* hB = (float*)alloc(64000UL * 128 * 4);
    float* score = (float*)alloc(64000UL * 4);
    float* dinvb = (float*)alloc(64000UL * 4);
    int* deg = (int*)alloc(64000UL * 4);
    int* rowptr = (int*)alloc(64001UL * 4);
    int* cursor = (int*)alloc(64000UL * 4);
    int* part = (int*)alloc(1024);
    int* colidx = (int*)alloc((size_t)EMAX * 4);
    float* wcoef = (float*)alloc((size_t)EMAX * 4);
    int* srcA = (int*)alloc((size_t)EMAX * 4);
    int* dstA = (int*)alloc((size_t)EMAX * 4);
    int* srcB = (int*)alloc((size_t)EMAX * 4);
    int* dstB = (int*)alloc((size_t)EMAX * 4);
    int* perm = (int*)alloc(51200UL * 4);
    float* gate = (float*)alloc(51200UL * 4);
    int* remap = (int*)alloc(64000UL * 4);
    float* rsum = (float*)alloc(64UL * 256 * 4);
    _Float16* wsall = (_Float16*)alloc(9UL * 32768 * 2);
    float* pnorm = (float*)alloc(256);
    int* ecnt = (int*)alloc(256);
    (void)ws_size;  // requires ~94 MB

    const float* x0 = (const float*)d_in[0];
    const int* src0 = (const int*)d_in[1];
    const int* dst0 = (const int*)d_in[2];

    hipMemsetAsync(rsum, 0, 64 * 256 * 4, stream);
    init_ecnt_kernel<<<1, 64, 0, stream>>>(ecnt);
    pnorm_kernel<<<1, 128, 0, stream>>>((const float*)d_in[27], pnorm + 0);
    pnorm_kernel<<<1, 128, 0, stream>>>((const float*)d_in[28], pnorm + 1);
    pnorm_kernel<<<1, 128, 0, stream>>>((const float*)d_in[29], pnorm + 2);

    WP wp;
    wp.w[0] = (const float*)d_in[3];  wp.w[1] = (const float*)d_in[5];  wp.w[2] = (const float*)d_in[7];
    wp.w[3] = (const float*)d_in[9];  wp.w[4] = (const float*)d_in[11]; wp.w[5] = (const float*)d_in[13];
    wp.w[6] = (const float*)d_in[15]; wp.w[7] = (const float*)d_in[17]; wp.w[8] = (const float*)d_in[19];
    wsplit_kernel<<<9, 256, 0, stream>>>(wp, wsall);

    auto run_layer = [&](int n, int npg, int k, const float* x, int layer,
                         const int* esrc, const int* edst, const int* ecin,
                         const float* ba, const float* bb, const float* bc,
                         const float* p, const float* pn,
                         int* so, int* ddst, int* ecout) {
        hipMemsetAsync(deg, 0, (size_t)n * 4, stream);
        count_kernel<<<EMAX / 256, 256, 0, stream>>>(edst, ecin, deg);
        scan1_kernel<<<n / 256, 256, 0, stream>>>(deg, rowptr, part, dinvb);
        scan2_kernel<<<1, 256, 0, stream>>>(part, rowptr, n / 256, n);
        scan3_kernel<<<n / 256, 256, 0, stream>>>(rowptr, cursor, part);
        scatter_kernel<<<EMAX / 256, 256, 0, stream>>>(esrc, edst, ecin, cursor, dinvb,
                                                       colidx, wcoef);
        gemm3m_kernel<<<n / 64, 256, 0, stream>>>(x, wsall + (size_t)layer * 3 * 32768,
                                                  ba, bb, bc, hA);
        prop_t<0><<<n / 4, 256, 0, stream>>>(hA, hB, rowptr, colidx, wcoef, dinvb,
                                             nullptr, nullptr, nullptr);
        prop_t<1><<<n / 4, 256, 0, stream>>>(hB, hA, rowptr, colidx, wcoef, dinvb,
                                             p, pn, score);
        hipMemsetAsync(remap, 0xFF, (size_t)n * 4, stream);
        pool_kernel<<<BGR, 256, 0, stream>>>(score, npg, k, perm, gate, remap);
        newx_kernel<<<(BGR * k) / 4, 256, 0, stream>>>(hA, perm, gate, hB);
        readout_kernel<<<BGR, 128, 0, stream>>>(hB, rsum, k);
        if (ecout)
            compact_kernel<<<EMAX / 1024, 1024, 0, stream>>>(esrc, edst, ecin, remap, so, ddst,
                                                             ecout);
    };

    run_layer(64000, 1000, 800, x0, 0, src0, dst0, ecnt + 0,
              (const float*)d_in[4], (const float*)d_in[6], (const float*)d_in[8],
              (const float*)d_in[27], pnorm + 0, srcA, dstA, ecnt + 1);

    run_layer(51200, 800, 640, hB, 1, srcA, dstA, ecnt + 1,
              (const float*)d_in[10], (const float*)d_in[12], (const float*)d_in[14],
              (const float*)d_in[28], pnorm + 1, srcB, dstB, ecnt + 2);

    run_layer(40960, 640, 512, hB, 2, srcB, dstB, ecnt + 2,
              (const float*)d_in[16], (const float*)d_in[18], (const float*)d_in[20],
              (const float*)d_in[29], pnorm + 2, nullptr, nullptr, nullptr);

    mlp_kernel<<<64, 128, 0, stream>>>(rsum, (const float*)d_in[21], (const float*)d_in[22],
                                       (const float*)d_in[23], (const float*)d_in[24],
                                       (const float*)d_in[25], (const float*)d_in[26],
                                       (float*)d_out);
}

// Round 5
// 862.156 us; speedup vs baseline: 1.9009x; 1.0053x over previous
//
#include <hip/hip_runtime.h>
#include <hip/hip_bf16.h>
#include <math.h>

#define BGR 64
#define EMAX 1024000

typedef _Float16 f16x8 __attribute__((ext_vector_type(8)));
typedef float f32x4 __attribute__((ext_vector_type(4)));

// ---------------- fused pnorm x3 + ecnt init ----------------
__global__ void pnorm3_kernel(const float* __restrict__ p1, const float* __restrict__ p2,
                              const float* __restrict__ p3, float* __restrict__ out,
                              int* __restrict__ ecnt) {
    __shared__ float buf[128];
    int t = threadIdx.x;
    const float* p = (blockIdx.x == 0) ? p1 : (blockIdx.x == 1) ? p2 : p3;
    float v = p[t];
    buf[t] = v * v;
    __syncthreads();
    for (int off = 64; off; off >>= 1) {
        if (t < off) buf[t] += buf[t + off];
        __syncthreads();
    }
    if (t == 0) out[blockIdx.x] = sqrtf(buf[0]);
    if (blockIdx.x == 0 && t == 0) { ecnt[0] = EMAX; ecnt[1] = 0; ecnt[2] = 0; }
}

// ---------------- weight split: f32 [k][n] -> f16 hi/lo chunk-major ----------------
// per matrix layout: [ks(4)][half(2)][kg(4)][n(128)][8]  (chunk (br,ks) = 16KB contiguous)
struct WP { const float* w[9]; };

__global__ void wsplit_kernel(WP wp, _Float16* __restrict__ out) {
    int mat = blockIdx.x;
    const float* __restrict__ w = wp.w[mat];
    _Float16* __restrict__ dst = out + (size_t)mat * 32768;
    for (int e = threadIdx.x; e < 2048; e += 256) {
        int n = e >> 4;
        int kb = (e & 15) * 8;
        f16x8 hi, lo;
#pragma unroll
        for (int j = 0; j < 8; j++) {
            float v = w[(kb + j) * 128 + n];
            _Float16 h = (_Float16)v;
            hi[j] = h;
            lo[j] = (_Float16)((v - (float)h) * 2048.0f);
        }
        int ks = kb >> 5, kg = (kb >> 3) & 3;
        *(f16x8*)(dst + ((((ks * 2 + 0) * 4 + kg) * 128 + n) * 8)) = hi;
        *(f16x8*)(dst + ((((ks * 2 + 1) * 4 + kg) * 128 + n) * 8)) = lo;
    }
}

// ---------------- degree / CSR build ----------------
__global__ void count_kernel(const int* __restrict__ dst, const int* __restrict__ ecnt,
                             int* __restrict__ deg) {
    int e = blockIdx.x * 256 + threadIdx.x;
    if (e >= ecnt[0]) return;
    atomicAdd(&deg[dst[e]], 1);
}

__global__ void scan1_kernel(const int* __restrict__ deg, int* __restrict__ rowptr,
                             int* __restrict__ part, float* __restrict__ dinv) {
    __shared__ int buf[256];
    int t = threadIdx.x;
    int i = blockIdx.x * 256 + t;
    int v = deg[i];
    dinv[i] = rsqrtf((float)v + 1.0f);
    buf[t] = v;
    __syncthreads();
    for (int off = 1; off < 256; off <<= 1) {
        int tmp = (t >= off) ? buf[t - off] : 0;
        __syncthreads();
        buf[t] += tmp;
        __syncthreads();
    }
    rowptr[i] = buf[t] - v;
    if (t == 255) part[blockIdx.x] = buf[255];
}

__global__ void scan2_kernel(int* __restrict__ part, int* __restrict__ rowptr, int nb, int n) {
    __shared__ int buf[256];
    int t = threadIdx.x;
    int v = (t < nb) ? part[t] : 0;
    buf[t] = v;
    __syncthreads();
    for (int off = 1; off < 256; off <<= 1) {
        int tmp = (t >= off) ? buf[t - off] : 0;
        __syncthreads();
        buf[t] += tmp;
        __syncthreads();
    }
    if (t < nb) part[t] = buf[t] - v;
    if (t == 255) rowptr[n] = buf[255];
}

__global__ void scan3_kernel(int* __restrict__ rowptr, int* __restrict__ cursor,
                             const int* __restrict__ part) {
    int i = blockIdx.x * 256 + threadIdx.x;
    int v = rowptr[i] + part[blockIdx.x];
    rowptr[i] = v;
    cursor[i] = v;
}

__global__ void scatter_kernel(const int* __restrict__ src, const int* __restrict__ dst,
                               const int* __restrict__ ecnt, int* __restrict__ cursor,
                               const float* __restrict__ dinv, int* __restrict__ colidx,
                               float* __restrict__ wcoef) {
    int e = blockIdx.x * 256 + threadIdx.x;
    if (e >= ecnt[0]) return;
    int s = src[e], d = dst[e];
    int pos = atomicAdd(&cursor[d], 1);
    colidx[pos] = s;
    wcoef[pos] = dinv[s] * dinv[d];
}

// ---------------- fused 3-branch MFMA GEMM (f16 split, f32-equivalent accuracy) ----------
__global__ __launch_bounds__(256) void gemm3m_kernel(
    const float* __restrict__ x, const _Float16* __restrict__ wsp,
    const float* __restrict__ b0, const float* __restrict__ b1, const float* __restrict__ b2,
    float* __restrict__ out) {
    __shared__ _Float16 ws[2][8192] __attribute__((aligned(16)));
    const int tid = threadIdx.x;
    const int wave = tid >> 6;
    const int lane = tid & 63;
    const int l15 = lane & 15;
    const int kg = lane >> 4;          // 0..3
    const long base = (long)blockIdx.x * 64;
    const int m = wave * 16 + l15;     // row within block tile

    float4 xrow[8];
    const float4* xg = (const float4*)(x + (base + m) * 128);
#pragma unroll
    for (int q = 0; q < 8; q++) xrow[q] = xg[(q >> 1) * 8 + kg * 2 + (q & 1)];

    auto stage = [&](int c, int buf) {
#pragma unroll
        for (int t = 0; t < 4; t++) {
            int u = tid + t * 256;
            __builtin_amdgcn_global_load_lds(
                (const __attribute__((address_space(1))) unsigned int*)(wsp + (size_t)c * 8192 + u * 8),
                (__attribute__((address_space(3))) unsigned int*)(&ws[buf][u * 8]),
                16, 0, 0);
        }
    };

    float tot[8][4];
#pragma unroll
    for (int nt = 0; nt < 8; nt++)
#pragma unroll
        for (int r = 0; r < 4; r++) tot[nt][r] = 0.f;

    f32x4 acc_h[8], acc_m[8];
    stage(0, 0);

#pragma unroll
    for (int c = 0; c < 12; c++) {
        const int br = c >> 2, ks = c & 3, buf = c & 1;
        if (ks == 0) {
#pragma unroll
            for (int nt = 0; nt < 8; nt++) {
                acc_h[nt] = (f32x4){0.f, 0.f, 0.f, 0.f};
                acc_m[nt] = (f32x4){0.f, 0.f, 0.f, 0.f};
            }
        }
        __syncthreads();
        if (c < 11) stage(c + 1, buf ^ 1);

        float ev[8] = {xrow[ks * 2].x, xrow[ks * 2].y, xrow[ks * 2].z, xrow[ks * 2].w,
                       xrow[ks * 2 + 1].x, xrow[ks * 2 + 1].y, xrow[ks * 2 + 1].z, xrow[ks * 2 + 1].w};
        f16x8 ah, al;
#pragma unroll
        for (int i = 0; i < 8; i++) {
            _Float16 h = (_Float16)ev[i];
            ah[i] = h;
            al[i] = (_Float16)((ev[i] - (float)h) * 2048.0f);
        }

        const _Float16* wb = &ws[buf][0];
        const int nb = kg * 1024 + l15 * 8;
        f16x8 bh[8], bl[8];
#pragma unroll
        for (int nt = 0; nt < 8; nt++) {
            bh[nt] = *(const f16x8*)(wb + nb + nt * 128);
            bl[nt] = *(const f16x8*)(wb + 4096 + nb + nt * 128);
        }
#pragma unroll
        for (int nt = 0; nt < 8; nt++)
            acc_h[nt] = __builtin_amdgcn_mfma_f32_16x16x32_f16(ah, bh[nt], acc_h[nt], 0, 0, 0);
#pragma unroll
        for (int nt = 0; nt < 8; nt++)
            acc_m[nt] = __builtin_amdgcn_mfma_f32_16x16x32_f16(ah, bl[nt], acc_m[nt], 0, 0, 0);
#pragma unroll
        for (int nt = 0; nt < 8; nt++)
            acc_m[nt] = __builtin_amdgcn_mfma_f32_16x16x32_f16(al, bh[nt], acc_m[nt], 0, 0, 0);

        if (ks == 3) {
            const float* bb = (br == 0) ? b0 : (br == 1) ? b1 : b2;
#pragma unroll
            for (int nt = 0; nt < 8; nt++) {
                float bv = bb[nt * 16 + l15];
#pragma unroll
                for (int r = 0; r < 4; r++)
                    tot[nt][r] += fmaxf(acc_h[nt][r] + acc_m[nt][r] * (1.0f / 2048.0f) + bv, 0.f);
            }
        }
    }

    float* op = out + (base + wave * 16 + kg * 4) * 128 + l15;
#pragma unroll
    for (int nt = 0; nt < 8; nt++)
#pragma unroll
        for (int r = 0; r < 4; r++) op[r * 128 + nt * 16] = tot[nt][r];
}

// ---------------- propagation (+optional fused score) ----------------
// 2 nodes per wave -> 16 gathers in flight; XCD swizzle for L2 locality
template <int SC>
__global__ __launch_bounds__(256) void prop_t(
    const float* __restrict__ hin, float* __restrict__ hout,
    const int* __restrict__ rowptr, const int* __restrict__ colidx,
    const float* __restrict__ wcoef, const float* __restrict__ dinv,
    const float* __restrict__ p, const float* __restrict__ pn, float* __restrict__ score) {
    int per = gridDim.x >> 3;
    int b = blockIdx.x;
    int sb = (b & 7) * per + (b >> 3);
    int wave = threadIdx.x >> 6;
    int lane = threadIdx.x & 63;
    int nodeA = sb * 8 + wave * 2;
    int nodeB = nodeA + 1;
    const float2* h2 = (const float2*)hin;

    float diA = dinv[nodeA], diB = dinv[nodeB];
    float2 hvA = h2[(long)nodeA * 64 + lane];
    float2 hvB = h2[(long)nodeB * 64 + lane];
    float scA = 1.0f + diA * diA, scB = 1.0f + diB * diB;
    float axA = hvA.x * scA, ayA = hvA.y * scA;
    float axB = hvB.x * scB, ayB = hvB.y * scB;

    int ea = rowptr[nodeA], eaE = rowptr[nodeA + 1];
    int eb = rowptr[nodeB], ebE = rowptr[nodeB + 1];

    // main interleaved loop: 16 gathers in flight
    while (ea + 8 <= eaE && eb + 8 <= ebE) {
        int ca[8], cb[8];
        float wa[8], wb[8];
        float2 ga[8], gb[8];
#pragma unroll
        for (int j = 0; j < 8; j++) { ca[j] = colidx[ea + j]; wa[j] = wcoef[ea + j]; }
#pragma unroll
        for (int j = 0; j < 8; j++) { cb[j] = colidx[eb + j]; wb[j] = wcoef[eb + j]; }
#pragma unroll
        for (int j = 0; j < 8; j++) ga[j] = h2[(long)ca[j] * 64 + lane];
#pragma unroll
        for (int j = 0; j < 8; j++) gb[j] = h2[(long)cb[j] * 64 + lane];
#pragma unroll
        for (int j = 0; j < 8; j++) { axA += wa[j] * ga[j].x; ayA += wa[j] * ga[j].y; }
#pragma unroll
        for (int j = 0; j < 8; j++) { axB += wb[j] * gb[j].x; ayB += wb[j] * gb[j].y; }
        ea += 8; eb += 8;
    }

    auto drain = [&](int e, int eE, float& ax, float& ay) {
        for (; e + 8 <= eE; e += 8) {
            int cc[8];
            float ww[8];
            float2 gg[8];
#pragma unroll
            for (int j = 0; j < 8; j++) { cc[j] = colidx[e + j]; ww[j] = wcoef[e + j]; }
#pragma unroll
            for (int j = 0; j < 8; j++) gg[j] = h2[(long)cc[j] * 64 + lane];
#pragma unroll
            for (int j = 0; j < 8; j++) { ax += ww[j] * gg[j].x; ay += ww[j] * gg[j].y; }
        }
        for (; e + 2 <= eE; e += 2) {
            int c0 = colidx[e], c1 = colidx[e + 1];
            float w0 = wcoef[e], w1 = wcoef[e + 1];
            float2 g0 = h2[(long)c0 * 64 + lane];
            float2 g1 = h2[(long)c1 * 64 + lane];
            ax += w0 * g0.x; ay += w0 * g0.y;
            ax += w1 * g1.x; ay += w1 * g1.y;
        }
        if (e < eE) {
            int c = colidx[e];
            float w = wcoef[e];
            float2 g = h2[(long)c * 64 + lane];
            ax += w * g.x; ay += w * g.y;
        }
    };
    drain(ea, eaE, axA, ayA);
    drain(eb, ebE, axB, ayB);

    ((float2*)hout)[(long)nodeA * 64 + lane] = make_float2(axA, ayA);
    ((float2*)hout)[(long)nodeB * 64 + lane] = make_float2(axB, ayB);

    if (SC) {
        float2 pv = ((const float2*)p)[lane];
        float vA = axA * pv.x + ayA * pv.y;
        float vB = axB * pv.x + ayB * pv.y;
        vA += __shfl_xor(vA, 32); vB += __shfl_xor(vB, 32);
        vA += __shfl_xor(vA, 16); vB += __shfl_xor(vB, 16);
        vA += __shfl_xor(vA, 8);  vB += __shfl_xor(vB, 8);
        vA += __shfl_xor(vA, 4);  vB += __shfl_xor(vB, 4);
        vA += __shfl_xor(vA, 2);  vB += __shfl_xor(vB, 2);
        vA += __shfl_xor(vA, 1);  vB += __shfl_xor(vB, 1);
        if (lane == 0) {
            float inv = 1.0f / pn[0];
            score[nodeA] = vA * inv;
            score[nodeB] = vB * inv;
        }
    }
}

// ---------------- top-k pool: bitonic sort 1024 per graph ----------------
// also writes remap = -1 for evicted nodes (no memset needed)
__global__ __launch_bounds__(256) void pool_kernel(const float* __restrict__ score, int npg, int k,
                            int* __restrict__ perm, float* __restrict__ gate,
                            int* __restrict__ remap) {
    __shared__ float sval[1024];
    __shared__ int sidx[1024];
    int b = blockIdx.x, t = threadIdx.x;
    for (int i = t; i < 1024; i += 256) {
        sval[i] = (i < npg) ? score[b * npg + i] : -INFINITY;
        sidx[i] = i;
    }
    __syncthreads();
    for (int ksz = 2; ksz <= 1024; ksz <<= 1) {
        for (int j = ksz >> 1; j > 0; j >>= 1) {
            for (int i = t; i < 1024; i += 256) {
                int l = i ^ j;
                if (l > i) {
                    float vi = sval[i], vl = sval[l];
                    bool up = ((i & ksz) == 0);
                    bool sw = up ? (vi < vl) : (vi > vl);   // descending sort
                    if (sw) {
                        sval[i] = vl; sval[l] = vi;
                        int tmp = sidx[i]; sidx[i] = sidx[l]; sidx[l] = tmp;
                    }
                }
            }
            __syncthreads();
        }
    }
    for (int i = t; i < k; i += 256) {
        int oldg = b * npg + sidx[i];
        int newg = b * k + i;
        perm[newg] = oldg;
        gate[newg] = tanhf(sval[i]);
        remap[oldg] = newg;
    }
    for (int i = k + t; i < npg; i += 256)
        remap[b * npg + sidx[i]] = -1;
}

// ---------------- gather new_x = h[perm] * gate ----------------
__global__ void newx_kernel(const float* __restrict__ h, const int* __restrict__ perm,
                            const float* __restrict__ gate, float* __restrict__ xo) {
    int m = blockIdx.x * 4 + (threadIdx.x >> 6);
    int lane = threadIdx.x & 63;
    int old = perm[m];
    float g = gate[m];
    float2 v = ((const float2*)h)[old * 64 + lane];
    ((float2*)xo)[m * 64 + lane] = make_float2(v.x * g, v.y * g);
}

// ---------------- readout: rsum[b] += [max over k ; mean over k] ----------------
__global__ void readout_kernel(const float* __restrict__ x, float* __restrict__ rsum, int k) {
    int b = blockIdx.x, f = threadIdx.x;   // 128 threads
    const float* base = x + (size_t)b * k * 128;
    float mx = -INFINITY, sm = 0.f;
#pragma unroll 4
    for (int j = 0; j < k; j++) {
        float v = base[j * 128 + f];
        mx = fmaxf(mx, v);
        sm += v;
    }
    rsum[b * 256 + f] += mx;
    rsum[b * 256 + 128 + f] += sm / (float)k;
}

// ---------------- edge remap + compact (hierarchical: 1 atomic per block) ----------------
__global__ __launch_bounds__(1024) void compact_kernel(
    const int* __restrict__ src, const int* __restrict__ dst,
    const int* __restrict__ ecnt, const int* __restrict__ remap,
    int* __restrict__ so, int* __restrict__ dd, int* __restrict__ ecout) {
    __shared__ int wcnt[16];
    __shared__ int bbase;
    int n = ecnt[0];
    int e = blockIdx.x * 1024 + threadIdx.x;
    int wave = threadIdx.x >> 6;
    int lane = threadIdx.x & 63;
    bool v = false;
    int s = 0, d = 0;
    if (e < n) {
        s = remap[src[e]];
        d = remap[dst[e]];
        v = ((s | d) >= 0);
    }
    unsigned long long m = __ballot(v);
    int before = __popcll(m & ((1ULL << lane) - 1ULL));
    if (lane == 0) wcnt[wave] = __popcll(m);
    __syncthreads();
    if (threadIdx.x == 0) {
        int tot = 0;
#pragma unroll
        for (int i = 0; i < 16; i++) { int c = wcnt[i]; wcnt[i] = tot; tot += c; }
        bbase = atomicAdd(ecout, tot);
    }
    __syncthreads();
    if (v) {
        int pos = bbase + wcnt[wave] + before;
        so[pos] = s;
        dd[pos] = d;
    }
}

// ---------------- fused final MLP + log_softmax ----------------
__global__ void mlp_kernel(const float* __restrict__ rsum,
                           const float* __restrict__ w1, const float* __restrict__ b1,
                           const float* __restrict__ w2, const float* __restrict__ b2,
                           const float* __restrict__ w3, const float* __restrict__ b3,
                           float* __restrict__ out) {
    __shared__ float z0[256], z1l[128], z2l[64], lg[10], ls;
    int b = blockIdx.x, t = threadIdx.x;   // 128 threads
    z0[t] = rsum[b * 256 + t];
    z0[t + 128] = rsum[b * 256 + 128 + t];
    __syncthreads();
    float acc = b1[t];
    for (int k = 0; k < 256; k++) acc += z0[k] * w1[k * 128 + t];
    z1l[t] = fmaxf(acc, 0.f);
    __syncthreads();
    if (t < 64) {
        acc = b2[t];
        for (int k = 0; k < 128; k++) acc += z1l[k] * w2[k * 64 + t];
        z2l[t] = fmaxf(acc, 0.f);
    }
    __syncthreads();
    if (t < 10) {
        acc = b3[t];
        for (int k = 0; k < 64; k++) acc += z2l[k] * w3[k * 10 + t];
        lg[t] = acc;
    }
    __syncthreads();
    if (t == 0) {
        float mx = lg[0];
        for (int c = 1; c < 10; c++) mx = fmaxf(mx, lg[c]);
        float s = 0.f;
        for (int c = 0; c < 10; c++) s += expf(lg[c] - mx);
        ls = mx + logf(s);
    }
    __syncthreads();
    if (t < 10) out[b * 10 + t] = lg[t] - ls;
}

// =====================================================================
extern "C" void kernel_launch(void* const* d_in, const int* in_sizes, int n_in,
                              void* d_out, int out_size, void* d_ws, size_t ws_size,
                              hipStream_t stream) {
    char* ws = (char*)d_ws;
    size_t off = 0;
    auto alloc = [&](size_t bytes) -> void* {
        void* p = ws + off;
        off += (bytes + 255) & ~(size_t)255;
        return p;
    };
    float* hA = (float*)alloc(64000UL * 128 * 4);
    float* hB = (float*)alloc(64000UL * 128 * 4);
    float* score = (float*)alloc(64000UL * 4);
    float* dinvb = (float*)alloc(64000UL * 4);
    int* deg = (int*)alloc(64000UL * 4);
    int* rowptr = (int*)alloc(64001UL * 4);
    int* cursor = (int*)alloc(64000UL * 4);
    int* part = (int*)alloc(1024);
    int* colidx = (int*)alloc((size_t)EMAX * 4);
    float* wcoef = (float*)alloc((size_t)EMAX * 4);
    int* srcA = (int*)alloc((size_t)EMAX * 4);
    int* dstA = (int*)alloc((size_t)EMAX * 4);
    int* srcB = (int*)alloc((size_t)EMAX * 4);
    int* dstB = (int*)alloc((size_t)EMAX * 4);
    int* perm = (int*)alloc(51200UL * 4);
    float* gate = (float*)alloc(51200UL * 4);
    int* remap = (int*)alloc(64000UL * 4);
    float* rsum = (float*)alloc(64UL * 256 * 4);
    _Float16* wsall = (_Float16*)alloc(9UL * 32768 * 2);
    float* pnorm = (float*)alloc(256);
    int* ecnt = (int*)alloc(256);
    (void)ws_size;  // requires ~94 MB

    const float* x0 = (const float*)d_in[0];
    const int* src0 = (const int*)d_in[1];
    const int* dst0 = (const int*)d_in[2];

    hipMemsetAsync(rsum, 0, 64 * 256 * 4, stream);
    pnorm3_kernel<<<3, 128, 0, stream>>>((const float*)d_in[27], (const float*)d_in[28],
                                         (const float*)d_in[29], pnorm, ecnt);

    WP wp;
    wp.w[0] = (const float*)d_in[3];  wp.w[1] = (const float*)d_in[5];  wp.w[2] = (const float*)d_in[7];
    wp.w[3] = (const float*)d_in[9];  wp.w[4] = (const float*)d_in[11]; wp.w[5] = (const float*)d_in[13];
    wp.w[6] = (const float*)d_in[15]; wp.w[7] = (const float*)d_in[17]; wp.w[8] = (const float*)d_in[19];
    wsplit_kernel<<<9, 256, 0, stream>>>(wp, wsall);

    auto run_layer = [&](int n, int npg, int k, const float* x, int layer,
                         const int* esrc, const int* edst, const int* ecin,
                         const float* ba, const float* bb, const float* bc,
                         const float* p, const float* pn,
                         int* so, int* ddst, int* ecout) {
        hipMemsetAsync(deg, 0, (size_t)n * 4, stream);
        count_kernel<<<EMAX / 256, 256, 0, stream>>>(edst, ecin, deg);
        scan1_kernel<<<n / 256, 256, 0, stream>>>(deg, rowptr, part, dinvb);
        scan2_kernel<<<1, 256, 0, stream>>>(part, rowptr, n / 256, n);
        scan3_kernel<<<n / 256, 256, 0, stream>>>(rowptr, cursor, part);
        scatter_kernel<<<EMAX / 256, 256, 0, stream>>>(esrc, edst, ecin, cursor, dinvb,
                                                       colidx, wcoef);
        gemm3m_kernel<<<n / 64, 256, 0, stream>>>(x, wsall + (size_t)layer * 3 * 32768,
                                                  ba, bb, bc, hA);
        prop_t<0><<<n / 8, 256, 0, stream>>>(hA, hB, rowptr, colidx, wcoef, dinvb,
                                             nullptr, nullptr, nullptr);
        prop_t<1><<<n / 8, 256, 0, stream>>>(hB, hA, rowptr, colidx, wcoef, dinvb,
                                             p, pn, score);
        pool_kernel<<<BGR, 256, 0, stream>>>(score, npg, k, perm, gate, remap);
        newx_kernel<<<(BGR * k) / 4, 256, 0, stream>>>(hA, perm, gate, hB);
        readout_kernel<<<BGR, 128, 0, stream>>>(hB, rsum, k);
        if (ecout)
            compact_kernel<<<EMAX / 1024, 1024, 0, stream>>>(esrc, edst, ecin, remap, so, ddst,
                                                             ecout);
    };

    run_layer(64000, 1000, 800, x0, 0, src0, dst0, ecnt + 0,
              (const float*)d_in[4], (const float*)d_in[6], (const float*)d_in[8],
              (const float*)d_in[27], pnorm + 0, srcA, dstA, ecnt + 1);

    run_layer(51200, 800, 640, hB, 1, srcA, dstA, ecnt + 1,
              (const float*)d_in[10], (const float*)d_in[12], (const float*)d_in[14],
              (const float*)d_in[28], pnorm + 1, srcB, dstB, ecnt + 2);

    run_layer(40960, 640, 512, hB, 2, srcB, dstB, ecnt + 2,
              (const float*)d_in[16], (const float*)d_in[18], (const float*)d_in[20],
              (const float*)d_in[29], pnorm + 2, nullptr, nullptr, nullptr);

    mlp_kernel<<<64, 128, 0, stream>>>(rsum, (const float*)d_in[21], (const float*)d_in[22],
                                       (const float*)d_in[23], (const float*)d_in[24],
                                       (const float*)d_in[25], (const float*)d_in[26],
                                       (float*)d_out);
}

// Round 6
// 725.681 us; speedup vs baseline: 2.2583x; 1.1881x over previous
//
#include <hip/hip_runtime.h>
#include <hip/hip_bf16.h>
#include <math.h>

#define BGR 64
#define EMAX 1024000

typedef _Float16 f16x8 __attribute__((ext_vector_type(8)));
typedef float f32x4 __attribute__((ext_vector_type(4)));

// ---------------- fused pnorm x3 + ecnt init ----------------
__global__ void pnorm3_kernel(const float* __restrict__ p1, const float* __restrict__ p2,
                              const float* __restrict__ p3, float* __restrict__ out,
                              int* __restrict__ ecnt) {
    __shared__ float buf[128];
    int t = threadIdx.x;
    const float* p = (blockIdx.x == 0) ? p1 : (blockIdx.x == 1) ? p2 : p3;
    float v = p[t];
    buf[t] = v * v;
    __syncthreads();
    for (int off = 64; off; off >>= 1) {
        if (t < off) buf[t] += buf[t + off];
        __syncthreads();
    }
    if (t == 0) out[blockIdx.x] = sqrtf(buf[0]);
    if (blockIdx.x == 0 && t == 0) { ecnt[0] = EMAX; ecnt[1] = 0; ecnt[2] = 0; }
}

// ---------------- weight split: f32 [k][n] -> f16 hi/lo chunk-major ----------------
struct WP { const float* w[9]; };

__global__ void wsplit_kernel(WP wp, _Float16* __restrict__ out) {
    int mat = blockIdx.x;
    const float* __restrict__ w = wp.w[mat];
    _Float16* __restrict__ dst = out + (size_t)mat * 32768;
    for (int e = threadIdx.x; e < 2048; e += 256) {
        int n = e >> 4;
        int kb = (e & 15) * 8;
        f16x8 hi, lo;
#pragma unroll
        for (int j = 0; j < 8; j++) {
            float v = w[(kb + j) * 128 + n];
            _Float16 h = (_Float16)v;
            hi[j] = h;
            lo[j] = (_Float16)((v - (float)h) * 2048.0f);
        }
        int ks = kb >> 5, kg = (kb >> 3) & 3;
        *(f16x8*)(dst + ((((ks * 2 + 0) * 4 + kg) * 128 + n) * 8)) = hi;
        *(f16x8*)(dst + ((((ks * 2 + 1) * 4 + kg) * 128 + n) * 8)) = lo;
    }
}

// ---------------- degree / CSR build ----------------
__global__ void count_kernel(const int* __restrict__ dst, const int* __restrict__ ecnt,
                             int* __restrict__ deg) {
    int e = blockIdx.x * 256 + threadIdx.x;
    if (e >= ecnt[0]) return;
    atomicAdd(&deg[dst[e]], 1);
}

// reads deg, zeroes it for the next layer's fused counting (in compact)
__global__ void scan1_kernel(int* __restrict__ deg, int* __restrict__ rowptr,
                             int* __restrict__ part, float* __restrict__ dinv) {
    __shared__ int buf[256];
    int t = threadIdx.x;
    int i = blockIdx.x * 256 + t;
    int v = deg[i];
    deg[i] = 0;
    dinv[i] = rsqrtf((float)v + 1.0f);
    buf[t] = v;
    __syncthreads();
    for (int off = 1; off < 256; off <<= 1) {
        int tmp = (t >= off) ? buf[t - off] : 0;
        __syncthreads();
        buf[t] += tmp;
        __syncthreads();
    }
    rowptr[i] = buf[t] - v;
    if (t == 255) part[blockIdx.x] = buf[255];
}

__global__ void scan2_kernel(int* __restrict__ part, int* __restrict__ rowptr, int nb, int n) {
    __shared__ int buf[256];
    int t = threadIdx.x;
    int v = (t < nb) ? part[t] : 0;
    buf[t] = v;
    __syncthreads();
    for (int off = 1; off < 256; off <<= 1) {
        int tmp = (t >= off) ? buf[t - off] : 0;
        __syncthreads();
        buf[t] += tmp;
        __syncthreads();
    }
    if (t < nb) part[t] = buf[t] - v;
    if (t == 255) rowptr[n] = buf[255];
}

__global__ void scan3_kernel(int* __restrict__ rowptr, int* __restrict__ cursor,
                             const int* __restrict__ part) {
    int i = blockIdx.x * 256 + threadIdx.x;
    int v = rowptr[i] + part[blockIdx.x];
    rowptr[i] = v;
    cursor[i] = v;
}

__global__ void scatter_kernel(const int* __restrict__ src, const int* __restrict__ dst,
                               const int* __restrict__ ecnt, int* __restrict__ cursor,
                               const float* __restrict__ dinv, int* __restrict__ colidx,
                               float* __restrict__ wcoef) {
    int e = blockIdx.x * 256 + threadIdx.x;
    if (e >= ecnt[0]) return;
    int s = src[e], d = dst[e];
    int pos = atomicAdd(&cursor[d], 1);
    colidx[pos] = s;
    wcoef[pos] = dinv[s] * dinv[d];
}

// ---------------- fused 3-branch MFMA GEMM (f16 split, f32-equivalent accuracy) ----------
__global__ __launch_bounds__(256) void gemm3m_kernel(
    const float* __restrict__ x, const _Float16* __restrict__ wsp,
    const float* __restrict__ b0, const float* __restrict__ b1, const float* __restrict__ b2,
    float* __restrict__ out) {
    __shared__ _Float16 ws[2][8192] __attribute__((aligned(16)));
    const int tid = threadIdx.x;
    const int wave = tid >> 6;
    const int lane = tid & 63;
    const int l15 = lane & 15;
    const int kg = lane >> 4;          // 0..3
    const long base = (long)blockIdx.x * 64;
    const int m = wave * 16 + l15;     // row within block tile

    float4 xrow[8];
    const float4* xg = (const float4*)(x + (base + m) * 128);
#pragma unroll
    for (int q = 0; q < 8; q++) xrow[q] = xg[(q >> 1) * 8 + kg * 2 + (q & 1)];

    auto stage = [&](int c, int buf) {
#pragma unroll
        for (int t = 0; t < 4; t++) {
            int u = tid + t * 256;
            __builtin_amdgcn_global_load_lds(
                (const __attribute__((address_space(1))) unsigned int*)(wsp + (size_t)c * 8192 + u * 8),
                (__attribute__((address_space(3))) unsigned int*)(&ws[buf][u * 8]),
                16, 0, 0);
        }
    };

    float tot[8][4];
#pragma unroll
    for (int nt = 0; nt < 8; nt++)
#pragma unroll
        for (int r = 0; r < 4; r++) tot[nt][r] = 0.f;

    f32x4 acc_h[8], acc_m[8];
    stage(0, 0);

#pragma unroll
    for (int c = 0; c < 12; c++) {
        const int br = c >> 2, ks = c & 3, buf = c & 1;
        if (ks == 0) {
#pragma unroll
            for (int nt = 0; nt < 8; nt++) {
                acc_h[nt] = (f32x4){0.f, 0.f, 0.f, 0.f};
                acc_m[nt] = (f32x4){0.f, 0.f, 0.f, 0.f};
            }
        }
        __syncthreads();
        if (c < 11) stage(c + 1, buf ^ 1);

        float ev[8] = {xrow[ks * 2].x, xrow[ks * 2].y, xrow[ks * 2].z, xrow[ks * 2].w,
                       xrow[ks * 2 + 1].x, xrow[ks * 2 + 1].y, xrow[ks * 2 + 1].z, xrow[ks * 2 + 1].w};
        f16x8 ah, al;
#pragma unroll
        for (int i = 0; i < 8; i++) {
            _Float16 h = (_Float16)ev[i];
            ah[i] = h;
            al[i] = (_Float16)((ev[i] - (float)h) * 2048.0f);
        }

        const _Float16* wb = &ws[buf][0];
        const int nb = kg * 1024 + l15 * 8;
        f16x8 bh[8], bl[8];
#pragma unroll
        for (int nt = 0; nt < 8; nt++) {
            bh[nt] = *(const f16x8*)(wb + nb + nt * 128);
            bl[nt] = *(const f16x8*)(wb + 4096 + nb + nt * 128);
        }
#pragma unroll
        for (int nt = 0; nt < 8; nt++)
            acc_h[nt] = __builtin_amdgcn_mfma_f32_16x16x32_f16(ah, bh[nt], acc_h[nt], 0, 0, 0);
#pragma unroll
        for (int nt = 0; nt < 8; nt++)
            acc_m[nt] = __builtin_amdgcn_mfma_f32_16x16x32_f16(ah, bl[nt], acc_m[nt], 0, 0, 0);
#pragma unroll
        for (int nt = 0; nt < 8; nt++)
            acc_m[nt] = __builtin_amdgcn_mfma_f32_16x16x32_f16(al, bh[nt], acc_m[nt], 0, 0, 0);

        if (ks == 3) {
            const float* bb = (br == 0) ? b0 : (br == 1) ? b1 : b2;
#pragma unroll
            for (int nt = 0; nt < 8; nt++) {
                float bv = bb[nt * 16 + l15];
#pragma unroll
                for (int r = 0; r < 4; r++)
                    tot[nt][r] += fmaxf(acc_h[nt][r] + acc_m[nt][r] * (1.0f / 2048.0f) + bv, 0.f);
            }
        }
    }

    float* op = out + (base + wave * 16 + kg * 4) * 128 + l15;
#pragma unroll
    for (int nt = 0; nt < 8; nt++)
#pragma unroll
        for (int r = 0; r < 4; r++) op[r * 128 + nt * 16] = tot[nt][r];
}

// ---------------- propagation (+optional fused score) ----------------
// 1 node/wave, 16-deep gather pipeline with 32-bit offsets; VGPR capped at 128.
template <int SC>
__global__ __launch_bounds__(256, 4) void prop_t(
    const float* __restrict__ hin, float* __restrict__ hout,
    const int* __restrict__ rowptr, const int* __restrict__ colidx,
    const float* __restrict__ wcoef, const float* __restrict__ dinv,
    const float* __restrict__ p, const float* __restrict__ pn, float* __restrict__ score) {
    int per = gridDim.x >> 3;
    int b = blockIdx.x;
    int sb = (b & 7) * per + (b >> 3);
    int node = sb * 4 + (threadIdx.x >> 6);
    int lane = threadIdx.x & 63;
    const char* hb = (const char*)hin;
    const unsigned loff = (unsigned)lane * 8u;

    float di = dinv[node];
    float selfc = 1.0f + di * di;
    float2 hv = *(const float2*)(hb + (unsigned)node * 512u + loff);
    float ax = hv.x * selfc, ay = hv.y * selfc;
    int e = rowptr[node], e1 = rowptr[node + 1];

    if (e + 16 <= e1) {
        unsigned off[16];
        float w[16];
        float2 g[16];
#pragma unroll
        for (int j = 0; j < 16; j++) {
            off[j] = (unsigned)colidx[e + j] * 512u + loff;
            w[j] = wcoef[e + j];
        }
#pragma unroll
        for (int j = 0; j < 16; j++) g[j] = *(const float2*)(hb + off[j]);
        e += 16;
        while (e + 16 <= e1) {
            unsigned noff[16];
            float nw[16];
#pragma unroll
            for (int j = 0; j < 16; j++) {
                noff[j] = (unsigned)colidx[e + j] * 512u + loff;
                nw[j] = wcoef[e + j];
            }
#pragma unroll
            for (int j = 0; j < 16; j++) { ax += w[j] * g[j].x; ay += w[j] * g[j].y; }
#pragma unroll
            for (int j = 0; j < 16; j++) g[j] = *(const float2*)(hb + noff[j]);
#pragma unroll
            for (int j = 0; j < 16; j++) w[j] = nw[j];
            e += 16;
        }
#pragma unroll
        for (int j = 0; j < 16; j++) { ax += w[j] * g[j].x; ay += w[j] * g[j].y; }
    }
    if (e + 8 <= e1) {
        unsigned off[8];
        float w[8];
        float2 g[8];
#pragma unroll
        for (int j = 0; j < 8; j++) {
            off[j] = (unsigned)colidx[e + j] * 512u + loff;
            w[j] = wcoef[e + j];
        }
#pragma unroll
        for (int j = 0; j < 8; j++) g[j] = *(const float2*)(hb + off[j]);
#pragma unroll
        for (int j = 0; j < 8; j++) { ax += w[j] * g[j].x; ay += w[j] * g[j].y; }
        e += 8;
    }
    if (e + 4 <= e1) {
        unsigned off[4];
        float w[4];
        float2 g[4];
#pragma unroll
        for (int j = 0; j < 4; j++) {
            off[j] = (unsigned)colidx[e + j] * 512u + loff;
            w[j] = wcoef[e + j];
        }
#pragma unroll
        for (int j = 0; j < 4; j++) g[j] = *(const float2*)(hb + off[j]);
#pragma unroll
        for (int j = 0; j < 4; j++) { ax += w[j] * g[j].x; ay += w[j] * g[j].y; }
        e += 4;
    }
    if (e + 2 <= e1) {
        unsigned o0 = (unsigned)colidx[e] * 512u + loff;
        unsigned o1 = (unsigned)colidx[e + 1] * 512u + loff;
        float w0 = wcoef[e], w1 = wcoef[e + 1];
        float2 g0 = *(const float2*)(hb + o0);
        float2 g1 = *(const float2*)(hb + o1);
        ax += w0 * g0.x; ay += w0 * g0.y;
        ax += w1 * g1.x; ay += w1 * g1.y;
        e += 2;
    }
    if (e < e1) {
        unsigned o0 = (unsigned)colidx[e] * 512u + loff;
        float w0 = wcoef[e];
        float2 g0 = *(const float2*)(hb + o0);
        ax += w0 * g0.x; ay += w0 * g0.y;
    }

    *(float2*)((char*)hout + (unsigned)node * 512u + loff) = make_float2(ax, ay);

    if (SC) {
        float2 pv = ((const float2*)p)[lane];
        float v = ax * pv.x + ay * pv.y;
        v += __shfl_xor(v, 32);
        v += __shfl_xor(v, 16);
        v += __shfl_xor(v, 8);
        v += __shfl_xor(v, 4);
        v += __shfl_xor(v, 2);
        v += __shfl_xor(v, 1);
        if (lane == 0) score[node] = v / pn[0];
    }
}

// ---------------- top-k pool: bitonic sort 1024 per graph ----------------
__global__ __launch_bounds__(256) void pool_kernel(const float* __restrict__ score, int npg, int k,
                            int* __restrict__ perm, float* __restrict__ gate,
                            int* __restrict__ remap) {
    __shared__ float sval[1024];
    __shared__ int sidx[1024];
    int b = blockIdx.x, t = threadIdx.x;
    for (int i = t; i < 1024; i += 256) {
        sval[i] = (i < npg) ? score[b * npg + i] : -INFINITY;
        sidx[i] = i;
    }
    __syncthreads();
    for (int ksz = 2; ksz <= 1024; ksz <<= 1) {
        for (int j = ksz >> 1; j > 0; j >>= 1) {
            for (int i = t; i < 1024; i += 256) {
                int l = i ^ j;
                if (l > i) {
                    float vi = sval[i], vl = sval[l];
                    bool up = ((i & ksz) == 0);
                    bool sw = up ? (vi < vl) : (vi > vl);   // descending sort
                    if (sw) {
                        sval[i] = vl; sval[l] = vi;
                        int tmp = sidx[i]; sidx[i] = sidx[l]; sidx[l] = tmp;
                    }
                }
            }
            __syncthreads();
        }
    }
    for (int i = t; i < k; i += 256) {
        int oldg = b * npg + sidx[i];
        int newg = b * k + i;
        perm[newg] = oldg;
        gate[newg] = tanhf(sval[i]);
        remap[oldg] = newg;
    }
    for (int i = k + t; i < npg; i += 256)
        remap[b * npg + sidx[i]] = -1;
}

// ---------------- gather new_x = h[perm] * gate ----------------
__global__ void newx_kernel(const float* __restrict__ h, const int* __restrict__ perm,
                            const float* __restrict__ gate, float* __restrict__ xo) {
    int m = blockIdx.x * 4 + (threadIdx.x >> 6);
    int lane = threadIdx.x & 63;
    int old = perm[m];
    float g = gate[m];
    float2 v = ((const float2*)h)[old * 64 + lane];
    ((float2*)xo)[m * 64 + lane] = make_float2(v.x * g, v.y * g);
}

// ---------------- readout: rsum[b] += [max over k ; mean over k] ----------------
// 512 threads: 4 row-chunks in parallel per feature, LDS combine
__global__ __launch_bounds__(512) void readout_kernel(const float* __restrict__ x,
                                                      float* __restrict__ rsum, int k) {
    __shared__ float smx[4][128], ssm[4][128];
    int b = blockIdx.x, t = threadIdx.x;
    int f = t & 127, c = t >> 7;
    int rows = k >> 2;
    const float* base = x + (size_t)b * k * 128 + (size_t)c * rows * 128 + f;
    float mx = -INFINITY, sm = 0.f;
#pragma unroll 8
    for (int j = 0; j < rows; j++) {
        float v = base[(size_t)j * 128];
        mx = fmaxf(mx, v);
        sm += v;
    }
    smx[c][f] = mx;
    ssm[c][f] = sm;
    __syncthreads();
    if (c == 0) {
        float m2 = fmaxf(fmaxf(smx[0][f], smx[1][f]), fmaxf(smx[2][f], smx[3][f]));
        float s2 = ssm[0][f] + ssm[1][f] + ssm[2][f] + ssm[3][f];
        rsum[b * 256 + f] += m2;
        rsum[b * 256 + 128 + f] += s2 / (float)k;
    }
}

// ---------------- edge remap + compact + fused next-layer degree count ----------------
__global__ __launch_bounds__(1024) void compact_kernel(
    const int* __restrict__ src, const int* __restrict__ dst,
    const int* __restrict__ ecnt, const int* __restrict__ remap,
    int* __restrict__ so, int* __restrict__ dd, int* __restrict__ ecout,
    int* __restrict__ deg) {
    __shared__ int wcnt[16];
    __shared__ int bbase;
    int n = ecnt[0];
    int e = blockIdx.x * 1024 + threadIdx.x;
    int wave = threadIdx.x >> 6;
    int lane = threadIdx.x & 63;
    bool v = false;
    int s = 0, d = 0;
    if (e < n) {
        s = remap[src[e]];
        d = remap[dst[e]];
        v = ((s | d) >= 0);
    }
    unsigned long long m = __ballot(v);
    int before = __popcll(m & ((1ULL << lane) - 1ULL));
    if (lane == 0) wcnt[wave] = __popcll(m);
    __syncthreads();
    if (threadIdx.x == 0) {
        int tot = 0;
#pragma unroll
        for (int i = 0; i < 16; i++) { int c = wcnt[i]; wcnt[i] = tot; tot += c; }
        bbase = atomicAdd(ecout, tot);
    }
    __syncthreads();
    if (v) {
        int pos = bbase + wcnt[wave] + before;
        so[pos] = s;
        dd[pos] = d;
        atomicAdd(&deg[d], 1);
    }
}

// ---------------- fused final MLP + log_softmax ----------------
__global__ void mlp_kernel(const float* __restrict__ rsum,
                           const float* __restrict__ w1, const float* __restrict__ b1,
                           const float* __restrict__ w2, const float* __restrict__ b2,
                           const float* __restrict__ w3, const float* __restrict__ b3,
                           float* __restrict__ out) {
    __shared__ float z0[256], z1l[128], z2l[64], lg[10], ls;
    int b = blockIdx.x, t = threadIdx.x;   // 128 threads
    z0[t] = rsum[b * 256 + t];
    z0[t + 128] = rsum[b * 256 + 128 + t];
    __syncthreads();
    float acc = b1[t];
    for (int k = 0; k < 256; k++) acc += z0[k] * w1[k * 128 + t];
    z1l[t] = fmaxf(acc, 0.f);
    __syncthreads();
    if (t < 64) {
        acc = b2[t];
        for (int k = 0; k < 128; k++) acc += z1l[k] * w2[k * 64 + t];
        z2l[t] = fmaxf(acc, 0.f);
    }
    __syncthreads();
    if (t < 10) {
        acc = b3[t];
        for (int k = 0; k < 64; k++) acc += z2l[k] * w3[k * 10 + t];
        lg[t] = acc;
    }
    __syncthreads();
    if (t == 0) {
        float mx = lg[0];
        for (int c = 1; c < 10; c++) mx = fmaxf(mx, lg[c]);
        float s = 0.f;
        for (int c = 0; c < 10; c++) s += expf(lg[c] - mx);
        ls = mx + logf(s);
    }
    __syncthreads();
    if (t < 10) out[b * 10 + t] = lg[t] - ls;
}

// =====================================================================
extern "C" void kernel_launch(void* const* d_in, const int* in_sizes, int n_in,
                              void* d_out, int out_size, void* d_ws, size_t ws_size,
                              hipStream_t stream) {
    char* ws = (char*)d_ws;
    size_t off = 0;
    auto alloc = [&](size_t bytes) -> void* {
        void* p = ws + off;
        off += (bytes + 255) & ~(size_t)255;
        return p;
    };
    float* hA = (float*)alloc(64000UL * 128 * 4);
    float* hB = (float*)alloc(64000UL * 128 * 4);
    float* score = (float*)alloc(64000UL * 4);
    float* dinvb = (float*)alloc(64000UL * 4);
    int* deg = (int*)alloc(64000UL * 4);
    int* rowptr = (int*)alloc(64001UL * 4);
    int* cursor = (int*)alloc(64000UL * 4);
    int* part = (int*)alloc(1024);
    int* colidx = (int*)alloc((size_t)EMAX * 4);
    float* wcoef = (float*)alloc((size_t)EMAX * 4);
    int* srcA = (int*)alloc((size_t)EMAX * 4);
    int* dstA = (int*)alloc((size_t)EMAX * 4);
    int* srcB = (int*)alloc((size_t)EMAX * 4);
    int* dstB = (int*)alloc((size_t)EMAX * 4);
    int* perm = (int*)alloc(51200UL * 4);
    float* gate = (float*)alloc(51200UL * 4);
    int* remap = (int*)alloc(64000UL * 4);
    float* rsum = (float*)alloc(64UL * 256 * 4);
    _Float16* wsall = (_Float16*)alloc(9UL * 32768 * 2);
    float* pnorm = (float*)alloc(256);
    int* ecnt = (int*)alloc(256);
    (void)ws_size;  // requires ~94 MB

    const float* x0 = (const float*)d_in[0];
    const int* src0 = (const int*)d_in[1];
    const int* dst0 = (const int*)d_in[2];

    hipMemsetAsync(rsum, 0, 64 * 256 * 4, stream);
    pnorm3_kernel<<<3, 128, 0, stream>>>((const float*)d_in[27], (const float*)d_in[28],
                                         (const float*)d_in[29], pnorm, ecnt);

    WP wp;
    wp.w[0] = (const float*)d_in[3];  wp.w[1] = (const float*)d_in[5];  wp.w[2] = (const float*)d_in[7];
    wp.w[3] = (const float*)d_in[9];  wp.w[4] = (const float*)d_in[11]; wp.w[5] = (const float*)d_in[13];
    wp.w[6] = (const float*)d_in[15]; wp.w[7] = (const float*)d_in[17]; wp.w[8] = (const float*)d_in[19];
    wsplit_kernel<<<9, 256, 0, stream>>>(wp, wsall);

    auto run_layer = [&](int n, int npg, int k, const float* x, int layer, bool do_count,
                         const int* esrc, const int* edst, const int* ecin,
                         const float* ba, const float* bb, const float* bc,
                         const float* p, const float* pn,
                         int* so, int* ddst, int* ecout) {
        if (do_count) {
            hipMemsetAsync(deg, 0, (size_t)n * 4, stream);
            count_kernel<<<EMAX / 256, 256, 0, stream>>>(edst, ecin, deg);
        }
        scan1_kernel<<<n / 256, 256, 0, stream>>>(deg, rowptr, part, dinvb);
        scan2_kernel<<<1, 256, 0, stream>>>(part, rowptr, n / 256, n);
        scan3_kernel<<<n / 256, 256, 0, stream>>>(rowptr, cursor, part);
        scatter_kernel<<<EMAX / 256, 256, 0, stream>>>(esrc, edst, ecin, cursor, dinvb,
                                                       colidx, wcoef);
        gemm3m_kernel<<<n / 64, 256, 0, stream>>>(x, wsall + (size_t)layer * 3 * 32768,
                                                  ba, bb, bc, hA);
        prop_t<0><<<n / 4, 256, 0, stream>>>(hA, hB, rowptr, colidx, wcoef, dinvb,
                                             nullptr, nullptr, nullptr);
        prop_t<1><<<n / 4, 256, 0, stream>>>(hB, hA, rowptr, colidx, wcoef, dinvb,
                                             p, pn, score);
        pool_kernel<<<BGR, 256, 0, stream>>>(score, npg, k, perm, gate, remap);
        newx_kernel<<<(BGR * k) / 4, 256, 0, stream>>>(hA, perm, gate, hB);
        readout_kernel<<<BGR, 512, 0, stream>>>(hB, rsum, k);
        if (ecout)
            compact_kernel<<<EMAX / 1024, 1024, 0, stream>>>(esrc, edst, ecin, remap, so, ddst,
                                                             ecout, deg);
    };

    run_layer(64000, 1000, 800, x0, 0, true, src0, dst0, ecnt + 0,
              (const float*)d_in[4], (const float*)d_in[6], (const float*)d_in[8],
              (const float*)d_in[27], pnorm + 0, srcA, dstA, ecnt + 1);

    run_layer(51200, 800, 640, hB, 1, false, srcA, dstA, ecnt + 1,
              (const float*)d_in[10], (const float*)d_in[12], (const float*)d_in[14],
              (const float*)d_in[28], pnorm + 1, srcB, dstB, ecnt + 2);

    run_layer(40960, 640, 512, hB, 2, false, srcB, dstB, ecnt + 2,
              (const float*)d_in[16], (const float*)d_in[18], (const float*)d_in[20],
              (const float*)d_in[29], pnorm + 2, nullptr, nullptr, nullptr);

    mlp_kernel<<<64, 128, 0, stream>>>(rsum, (const float*)d_in[21], (const float*)d_in[22],
                                       (const float*)d_in[23], (const float*)d_in[24],
                                       (const float*)d_in[25], (const float*)d_in[26],
                                       (float*)d_out);
}

// Round 7
// 690.537 us; speedup vs baseline: 2.3733x; 1.0509x over previous
//
#include <hip/hip_runtime.h>
#include <hip/hip_bf16.h>
#include <math.h>

#define BGR 64
#define EMAX 1024000

typedef _Float16 f16x8 __attribute__((ext_vector_type(8)));
typedef float f32x4 __attribute__((ext_vector_type(4)));

// ---------------- fused pnorm x3 + ecnt init ----------------
__global__ void pnorm3_kernel(const float* __restrict__ p1, const float* __restrict__ p2,
                              const float* __restrict__ p3, float* __restrict__ out,
                              int* __restrict__ ecnt) {
    __shared__ float buf[128];
    int t = threadIdx.x;
    const float* p = (blockIdx.x == 0) ? p1 : (blockIdx.x == 1) ? p2 : p3;
    float v = p[t];
    buf[t] = v * v;
    __syncthreads();
    for (int off = 64; off; off >>= 1) {
        if (t < off) buf[t] += buf[t + off];
        __syncthreads();
    }
    if (t == 0) out[blockIdx.x] = sqrtf(buf[0]);
    if (blockIdx.x == 0 && t == 0) { ecnt[0] = EMAX; ecnt[1] = 0; ecnt[2] = 0; }
}

// ---------------- weight split: f32 [k][n] -> f16 hi/lo chunk-major ----------------
struct WP { const float* w[9]; };

__global__ void wsplit_kernel(WP wp, _Float16* __restrict__ out) {
    int mat = blockIdx.x;
    const float* __restrict__ w = wp.w[mat];
    _Float16* __restrict__ dst = out + (size_t)mat * 32768;
    for (int e = threadIdx.x; e < 2048; e += 256) {
        int n = e >> 4;
        int kb = (e & 15) * 8;
        f16x8 hi, lo;
#pragma unroll
        for (int j = 0; j < 8; j++) {
            float v = w[(kb + j) * 128 + n];
            _Float16 h = (_Float16)v;
            hi[j] = h;
            lo[j] = (_Float16)((v - (float)h) * 2048.0f);
        }
        int ks = kb >> 5, kg = (kb >> 3) & 3;
        *(f16x8*)(dst + ((((ks * 2 + 0) * 4 + kg) * 128 + n) * 8)) = hi;
        *(f16x8*)(dst + ((((ks * 2 + 1) * 4 + kg) * 128 + n) * 8)) = lo;
    }
}

// ---------------- degree / CSR build ----------------
__global__ void count_kernel(const int* __restrict__ dst, const int* __restrict__ ecnt,
                             int* __restrict__ deg) {
    int e = blockIdx.x * 256 + threadIdx.x;
    if (e >= ecnt[0]) return;
    atomicAdd(&deg[dst[e]], 1);
}

// reads deg, zeroes it for the next layer's fused counting (in compact)
__global__ void scan1_kernel(int* __restrict__ deg, int* __restrict__ rowptr,
                             int* __restrict__ part, float* __restrict__ dinv) {
    __shared__ int buf[256];
    int t = threadIdx.x;
    int i = blockIdx.x * 256 + t;
    int v = deg[i];
    deg[i] = 0;
    dinv[i] = rsqrtf((float)v + 1.0f);
    buf[t] = v;
    __syncthreads();
    for (int off = 1; off < 256; off <<= 1) {
        int tmp = (t >= off) ? buf[t - off] : 0;
        __syncthreads();
        buf[t] += tmp;
        __syncthreads();
    }
    rowptr[i] = buf[t] - v;
    if (t == 255) part[blockIdx.x] = buf[255];
}

__global__ void scan2_kernel(int* __restrict__ part, int* __restrict__ rowptr, int nb, int n) {
    __shared__ int buf[256];
    int t = threadIdx.x;
    int v = (t < nb) ? part[t] : 0;
    buf[t] = v;
    __syncthreads();
    for (int off = 1; off < 256; off <<= 1) {
        int tmp = (t >= off) ? buf[t - off] : 0;
        __syncthreads();
        buf[t] += tmp;
        __syncthreads();
    }
    if (t < nb) part[t] = buf[t] - v;
    if (t == 255) rowptr[n] = buf[255];
}

__global__ void scan3_kernel(int* __restrict__ rowptr, int* __restrict__ cursor,
                             const int* __restrict__ part) {
    int i = blockIdx.x * 256 + threadIdx.x;
    int v = rowptr[i] + part[blockIdx.x];
    rowptr[i] = v;
    cursor[i] = v;
}

__global__ void scatter_kernel(const int* __restrict__ src, const int* __restrict__ dst,
                               const int* __restrict__ ecnt, int* __restrict__ cursor,
                               const float* __restrict__ dinv, int* __restrict__ colidx,
                               float* __restrict__ wcoef) {
    int e = blockIdx.x * 256 + threadIdx.x;
    if (e >= ecnt[0]) return;
    int s = src[e], d = dst[e];
    int pos = atomicAdd(&cursor[d], 1);
    colidx[pos] = s;
    wcoef[pos] = dinv[s] * dinv[d];
}

// ---------------- fused 3-branch MFMA GEMM (f16 split, f32-equivalent accuracy) ----------
__global__ __launch_bounds__(256) void gemm3m_kernel(
    const float* __restrict__ x, const _Float16* __restrict__ wsp,
    const float* __restrict__ b0, const float* __restrict__ b1, const float* __restrict__ b2,
    float* __restrict__ out) {
    __shared__ _Float16 ws[2][8192] __attribute__((aligned(16)));
    const int tid = threadIdx.x;
    const int wave = tid >> 6;
    const int lane = tid & 63;
    const int l15 = lane & 15;
    const int kg = lane >> 4;          // 0..3
    const long base = (long)blockIdx.x * 64;
    const int m = wave * 16 + l15;     // row within block tile

    float4 xrow[8];
    const float4* xg = (const float4*)(x + (base + m) * 128);
#pragma unroll
    for (int q = 0; q < 8; q++) xrow[q] = xg[(q >> 1) * 8 + kg * 2 + (q & 1)];

    auto stage = [&](int c, int buf) {
#pragma unroll
        for (int t = 0; t < 4; t++) {
            int u = tid + t * 256;
            __builtin_amdgcn_global_load_lds(
                (const __attribute__((address_space(1))) unsigned int*)(wsp + (size_t)c * 8192 + u * 8),
                (__attribute__((address_space(3))) unsigned int*)(&ws[buf][u * 8]),
                16, 0, 0);
        }
    };

    float tot[8][4];
#pragma unroll
    for (int nt = 0; nt < 8; nt++)
#pragma unroll
        for (int r = 0; r < 4; r++) tot[nt][r] = 0.f;

    f32x4 acc_h[8], acc_m[8];
    stage(0, 0);

#pragma unroll
    for (int c = 0; c < 12; c++) {
        const int br = c >> 2, ks = c & 3, buf = c & 1;
        if (ks == 0) {
#pragma unroll
            for (int nt = 0; nt < 8; nt++) {
                acc_h[nt] = (f32x4){0.f, 0.f, 0.f, 0.f};
                acc_m[nt] = (f32x4){0.f, 0.f, 0.f, 0.f};
            }
        }
        __syncthreads();
        if (c < 11) stage(c + 1, buf ^ 1);

        float ev[8] = {xrow[ks * 2].x, xrow[ks * 2].y, xrow[ks * 2].z, xrow[ks * 2].w,
                       xrow[ks * 2 + 1].x, xrow[ks * 2 + 1].y, xrow[ks * 2 + 1].z, xrow[ks * 2 + 1].w};
        f16x8 ah, al;
#pragma unroll
        for (int i = 0; i < 8; i++) {
            _Float16 h = (_Float16)ev[i];
            ah[i] = h;
            al[i] = (_Float16)((ev[i] - (float)h) * 2048.0f);
        }

        const _Float16* wb = &ws[buf][0];
        const int nb = kg * 1024 + l15 * 8;
        f16x8 bh[8], bl[8];
#pragma unroll
        for (int nt = 0; nt < 8; nt++) {
            bh[nt] = *(const f16x8*)(wb + nb + nt * 128);
            bl[nt] = *(const f16x8*)(wb + 4096 + nb + nt * 128);
        }
#pragma unroll
        for (int nt = 0; nt < 8; nt++)
            acc_h[nt] = __builtin_amdgcn_mfma_f32_16x16x32_f16(ah, bh[nt], acc_h[nt], 0, 0, 0);
#pragma unroll
        for (int nt = 0; nt < 8; nt++)
            acc_m[nt] = __builtin_amdgcn_mfma_f32_16x16x32_f16(ah, bl[nt], acc_m[nt], 0, 0, 0);
#pragma unroll
        for (int nt = 0; nt < 8; nt++)
            acc_m[nt] = __builtin_amdgcn_mfma_f32_16x16x32_f16(al, bh[nt], acc_m[nt], 0, 0, 0);

        if (ks == 3) {
            const float* bb = (br == 0) ? b0 : (br == 1) ? b1 : b2;
#pragma unroll
            for (int nt = 0; nt < 8; nt++) {
                float bv = bb[nt * 16 + l15];
#pragma unroll
                for (int r = 0; r < 4; r++)
                    tot[nt][r] += fmaxf(acc_h[nt][r] + acc_m[nt][r] * (1.0f / 2048.0f) + bv, 0.f);
            }
        }
    }

    float* op = out + (base + wave * 16 + kg * 4) * 128 + l15;
#pragma unroll
    for (int nt = 0; nt < 8; nt++)
#pragma unroll
        for (int r = 0; r < 4; r++) op[r * 128 + nt * 16] = tot[nt][r];
}

// ---------------- propagation (+optional fused score) ----------------
// 1 node/wave; edge metadata broadcast to SGPRs via readlane so each in-flight
// gather costs only 2 data VGPRs -> genuine 16-deep pipeline.
template <int SC>
__global__ __launch_bounds__(256, 4) void prop_t(
    const float* __restrict__ hin, float* __restrict__ hout,
    const int* __restrict__ rowptr, const int* __restrict__ colidx,
    const float* __restrict__ wcoef, const float* __restrict__ dinv,
    const float* __restrict__ p, const float* __restrict__ pn, float* __restrict__ score) {
    int per = gridDim.x >> 3;
    int b = blockIdx.x;
    int sb = (b & 7) * per + (b >> 3);
    int node = sb * 4 + (threadIdx.x >> 6);
    int lane = threadIdx.x & 63;
    const float2* h2 = (const float2*)hin;

    float di = dinv[node];
    float selfc = 1.0f + di * di;
    float2 hv = h2[(long)node * 64 + lane];
    float ax = hv.x * selfc, ay = hv.y * selfc;
    int e = rowptr[node], e1 = rowptr[node + 1];

    while (e + 16 <= e1) {
        int ci = colidx[e + (lane & 15)];
        int wi = __float_as_int(wcoef[e + (lane & 15)]);
        float2 g[16];
        float w[16];
#pragma unroll
        for (int j = 0; j < 16; j++) {
            int idx = __builtin_amdgcn_readlane(ci, j);          // SGPR row index
            w[j] = __int_as_float(__builtin_amdgcn_readlane(wi, j));
            g[j] = h2[(long)idx * 64 + lane];                    // saddr + lane voffset
        }
        __builtin_amdgcn_sched_barrier(0);                       // pin loads-before-FMAs
#pragma unroll
        for (int j = 0; j < 16; j++) { ax += w[j] * g[j].x; ay += w[j] * g[j].y; }
        e += 16;
    }
    if (e + 8 <= e1) {
        int ci = colidx[e + (lane & 7)];
        int wi = __float_as_int(wcoef[e + (lane & 7)]);
        float2 g[8];
        float w[8];
#pragma unroll
        for (int j = 0; j < 8; j++) {
            int idx = __builtin_amdgcn_readlane(ci, j);
            w[j] = __int_as_float(__builtin_amdgcn_readlane(wi, j));
            g[j] = h2[(long)idx * 64 + lane];
        }
        __builtin_amdgcn_sched_barrier(0);
#pragma unroll
        for (int j = 0; j < 8; j++) { ax += w[j] * g[j].x; ay += w[j] * g[j].y; }
        e += 8;
    }
    if (e + 4 <= e1) {
        int ci = colidx[e + (lane & 3)];
        int wi = __float_as_int(wcoef[e + (lane & 3)]);
        float2 g[4];
        float w[4];
#pragma unroll
        for (int j = 0; j < 4; j++) {
            int idx = __builtin_amdgcn_readlane(ci, j);
            w[j] = __int_as_float(__builtin_amdgcn_readlane(wi, j));
            g[j] = h2[(long)idx * 64 + lane];
        }
        __builtin_amdgcn_sched_barrier(0);
#pragma unroll
        for (int j = 0; j < 4; j++) { ax += w[j] * g[j].x; ay += w[j] * g[j].y; }
        e += 4;
    }
    while (e < e1) {
        int c = colidx[e];
        float w = wcoef[e];
        float2 g = h2[(long)c * 64 + lane];
        ax += w * g.x; ay += w * g.y;
        ++e;
    }

    ((float2*)hout)[(long)node * 64 + lane] = make_float2(ax, ay);

    if (SC) {
        float2 pv = ((const float2*)p)[lane];
        float v = ax * pv.x + ay * pv.y;
        v += __shfl_xor(v, 32);
        v += __shfl_xor(v, 16);
        v += __shfl_xor(v, 8);
        v += __shfl_xor(v, 4);
        v += __shfl_xor(v, 2);
        v += __shfl_xor(v, 1);
        if (lane == 0) score[node] = v / pn[0];
    }
}

// ---------------- top-k pool: bitonic sort 1024 per graph ----------------
__global__ __launch_bounds__(256) void pool_kernel(const float* __restrict__ score, int npg, int k,
                            int* __restrict__ perm, float* __restrict__ gate,
                            int* __restrict__ remap) {
    __shared__ float sval[1024];
    __shared__ int sidx[1024];
    int b = blockIdx.x, t = threadIdx.x;
    for (int i = t; i < 1024; i += 256) {
        sval[i] = (i < npg) ? score[b * npg + i] : -INFINITY;
        sidx[i] = i;
    }
    __syncthreads();
    for (int ksz = 2; ksz <= 1024; ksz <<= 1) {
        for (int j = ksz >> 1; j > 0; j >>= 1) {
            for (int i = t; i < 1024; i += 256) {
                int l = i ^ j;
                if (l > i) {
                    float vi = sval[i], vl = sval[l];
                    bool up = ((i & ksz) == 0);
                    bool sw = up ? (vi < vl) : (vi > vl);   // descending sort
                    if (sw) {
                        sval[i] = vl; sval[l] = vi;
                        int tmp = sidx[i]; sidx[i] = sidx[l]; sidx[l] = tmp;
                    }
                }
            }
            __syncthreads();
        }
    }
    for (int i = t; i < k; i += 256) {
        int oldg = b * npg + sidx[i];
        int newg = b * k + i;
        perm[newg] = oldg;
        gate[newg] = tanhf(sval[i]);
        remap[oldg] = newg;
    }
    for (int i = k + t; i < npg; i += 256)
        remap[b * npg + sidx[i]] = -1;
}

// ---------------- gather new_x = h[perm] * gate ----------------
__global__ void newx_kernel(const float* __restrict__ h, const int* __restrict__ perm,
                            const float* __restrict__ gate, float* __restrict__ xo) {
    int m = blockIdx.x * 4 + (threadIdx.x >> 6);
    int lane = threadIdx.x & 63;
    int old = perm[m];
    float g = gate[m];
    float2 v = ((const float2*)h)[old * 64 + lane];
    ((float2*)xo)[m * 64 + lane] = make_float2(v.x * g, v.y * g);
}

// ---------------- readout: rsum[b] += [max over k ; mean over k] ----------------
__global__ __launch_bounds__(512) void readout_kernel(const float* __restrict__ x,
                                                      float* __restrict__ rsum, int k) {
    __shared__ float smx[4][128], ssm[4][128];
    int b = blockIdx.x, t = threadIdx.x;
    int f = t & 127, c = t >> 7;
    int rows = k >> 2;
    const float* base = x + (size_t)b * k * 128 + (size_t)c * rows * 128 + f;
    float mx = -INFINITY, sm = 0.f;
#pragma unroll 8
    for (int j = 0; j < rows; j++) {
        float v = base[(size_t)j * 128];
        mx = fmaxf(mx, v);
        sm += v;
    }
    smx[c][f] = mx;
    ssm[c][f] = sm;
    __syncthreads();
    if (c == 0) {
        float m2 = fmaxf(fmaxf(smx[0][f], smx[1][f]), fmaxf(smx[2][f], smx[3][f]));
        float s2 = ssm[0][f] + ssm[1][f] + ssm[2][f] + ssm[3][f];
        rsum[b * 256 + f] += m2;
        rsum[b * 256 + 128 + f] += s2 / (float)k;
    }
}

// ---------------- edge remap + compact + fused next-layer degree count ----------------
__global__ __launch_bounds__(1024) void compact_kernel(
    const int* __restrict__ src, const int* __restrict__ dst,
    const int* __restrict__ ecnt, const int* __restrict__ remap,
    int* __restrict__ so, int* __restrict__ dd, int* __restrict__ ecout,
    int* __restrict__ deg) {
    __shared__ int wcnt[16];
    __shared__ int bbase;
    int n = ecnt[0];
    int e = blockIdx.x * 1024 + threadIdx.x;
    int wave = threadIdx.x >> 6;
    int lane = threadIdx.x & 63;
    bool v = false;
    int s = 0, d = 0;
    if (e < n) {
        s = remap[src[e]];
        d = remap[dst[e]];
        v = ((s | d) >= 0);
    }
    unsigned long long m = __ballot(v);
    int before = __popcll(m & ((1ULL << lane) - 1ULL));
    if (lane == 0) wcnt[wave] = __popcll(m);
    __syncthreads();
    if (threadIdx.x == 0) {
        int tot = 0;
#pragma unroll
        for (int i = 0; i < 16; i++) { int c = wcnt[i]; wcnt[i] = tot; tot += c; }
        bbase = atomicAdd(ecout, tot);
    }
    __syncthreads();
    if (v) {
        int pos = bbase + wcnt[wave] + before;
        so[pos] = s;
        dd[pos] = d;
        atomicAdd(&deg[d], 1);
    }
}

// ---------------- fused final MLP + log_softmax ----------------
__global__ void mlp_kernel(const float* __restrict__ rsum,
                           const float* __restrict__ w1, const float* __restrict__ b1,
                           const float* __restrict__ w2, const float* __restrict__ b2,
                           const float* __restrict__ w3, const float* __restrict__ b3,
                           float* __restrict__ out) {
    __shared__ float z0[256], z1l[128], z2l[64], lg[10], ls;
    int b = blockIdx.x, t = threadIdx.x;   // 128 threads
    z0[t] = rsum[b * 256 + t];
    z0[t + 128] = rsum[b * 256 + 128 + t];
    __syncthreads();
    float acc = b1[t];
    for (int k = 0; k < 256; k++) acc += z0[k] * w1[k * 128 + t];
    z1l[t] = fmaxf(acc, 0.f);
    __syncthreads();
    if (t < 64) {
        acc = b2[t];
        for (int k = 0; k < 128; k++) acc += z1l[k] * w2[k * 64 + t];
        z2l[t] = fmaxf(acc, 0.f);
    }
    __syncthreads();
    if (t < 10) {
        acc = b3[t];
        for (int k = 0; k < 64; k++) acc += z2l[k] * w3[k * 10 + t];
        lg[t] = acc;
    }
    __syncthreads();
    if (t == 0) {
        float mx = lg[0];
        for (int c = 1; c < 10; c++) mx = fmaxf(mx, lg[c]);
        float s = 0.f;
        for (int c = 0; c < 10; c++) s += expf(lg[c] - mx);
        ls = mx + logf(s);
    }
    __syncthreads();
    if (t < 10) out[b * 10 + t] = lg[t] - ls;
}

// =====================================================================
extern "C" void kernel_launch(void* const* d_in, const int* in_sizes, int n_in,
                              void* d_out, int out_size, void* d_ws, size_t ws_size,
                              hipStream_t stream) {
    char* ws = (char*)d_ws;
    size_t off = 0;
    auto alloc = [&](size_t bytes) -> void* {
        void* p = ws + off;
        off += (bytes + 255) & ~(size_t)255;
        return p;
    };
    float* hA = (float*)alloc(64000UL * 128 * 4);
    float* hB = (float*)alloc(64000UL * 128 * 4);
    float* score = (float*)alloc(64000UL * 4);
    float* dinvb = (float*)alloc(64000UL * 4);
    int* deg = (int*)alloc(64000UL * 4);
    int* rowptr = (int*)alloc(64001UL * 4);
    int* cursor = (int*)alloc(64000UL * 4);
    int* part = (int*)alloc(1024);
    int* colidx = (int*)alloc((size_t)EMAX * 4);
    float* wcoef = (float*)alloc((size_t)EMAX * 4);
    int* srcA = (int*)alloc((size_t)EMAX * 4);
    int* dstA = (int*)alloc((size_t)EMAX * 4);
    int* srcB = (int*)alloc((size_t)EMAX * 4);
    int* dstB = (int*)alloc((size_t)EMAX * 4);
    int* perm = (int*)alloc(51200UL * 4);
    float* gate = (float*)alloc(51200UL * 4);
    int* remap = (int*)alloc(64000UL * 4);
    float* rsum = (float*)alloc(64UL * 256 * 4);
    _Float16* wsall = (_Float16*)alloc(9UL * 32768 * 2);
    float* pnorm = (float*)alloc(256);
    int* ecnt = (int*)alloc(256);
    (void)ws_size;  // requires ~94 MB

    const float* x0 = (const float*)d_in[0];
    const int* src0 = (const int*)d_in[1];
    const int* dst0 = (const int*)d_in[2];

    hipMemsetAsync(rsum, 0, 64 * 256 * 4, stream);
    pnorm3_kernel<<<3, 128, 0, stream>>>((const float*)d_in[27], (const float*)d_in[28],
                                         (const float*)d_in[29], pnorm, ecnt);

    WP wp;
    wp.w[0] = (const float*)d_in[3];  wp.w[1] = (const float*)d_in[5];  wp.w[2] = (const float*)d_in[7];
    wp.w[3] = (const float*)d_in[9];  wp.w[4] = (const float*)d_in[11]; wp.w[5] = (const float*)d_in[13];
    wp.w[6] = (const float*)d_in[15]; wp.w[7] = (const float*)d_in[17]; wp.w[8] = (const float*)d_in[19];
    wsplit_kernel<<<9, 256, 0, stream>>>(wp, wsall);

    auto run_layer = [&](int n, int npg, int k, const float* x, int layer, bool do_count,
                         const int* esrc, const int* edst, const int* ecin,
                         const float* ba, const float* bb, const float* bc,
                         const float* p, const float* pn,
                         int* so, int* ddst, int* ecout) {
        if (do_count) {
            hipMemsetAsync(deg, 0, (size_t)n * 4, stream);
            count_kernel<<<EMAX / 256, 256, 0, stream>>>(edst, ecin, deg);
        }
        scan1_kernel<<<n / 256, 256, 0, stream>>>(deg, rowptr, part, dinvb);
        scan2_kernel<<<1, 256, 0, stream>>>(part, rowptr, n / 256, n);
        scan3_kernel<<<n / 256, 256, 0, stream>>>(rowptr, cursor, part);
        scatter_kernel<<<EMAX / 256, 256, 0, stream>>>(esrc, edst, ecin, cursor, dinvb,
                                                       colidx, wcoef);
        gemm3m_kernel<<<n / 64, 256, 0, stream>>>(x, wsall + (size_t)layer * 3 * 32768,
                                                  ba, bb, bc, hA);
        prop_t<0><<<n / 4, 256, 0, stream>>>(hA, hB, rowptr, colidx, wcoef, dinvb,
                                             nullptr, nullptr, nullptr);
        prop_t<1><<<n / 4, 256, 0, stream>>>(hB, hA, rowptr, colidx, wcoef, dinvb,
                                             p, pn, score);
        pool_kernel<<<BGR, 256, 0, stream>>>(score, npg, k, perm, gate, remap);
        newx_kernel<<<(BGR * k) / 4, 256, 0, stream>>>(hA, perm, gate, hB);
        readout_kernel<<<BGR, 512, 0, stream>>>(hB, rsum, k);
        if (ecout)
            compact_kernel<<<EMAX / 1024, 1024, 0, stream>>>(esrc, edst, ecin, remap, so, ddst,
                                                             ecout, deg);
    };

    run_layer(64000, 1000, 800, x0, 0, true, src0, dst0, ecnt + 0,
              (const float*)d_in[4], (const float*)d_in[6], (const float*)d_in[8],
              (const float*)d_in[27], pnorm + 0, srcA, dstA, ecnt + 1);

    run_layer(51200, 800, 640, hB, 1, false, srcA, dstA, ecnt + 1,
              (const float*)d_in[10], (const float*)d_in[12], (const float*)d_in[14],
              (const float*)d_in[28], pnorm + 1, srcB, dstB, ecnt + 2);

    run_layer(40960, 640, 512, hB, 2, false, srcB, dstB, ecnt + 2,
              (const float*)d_in[16], (const float*)d_in[18], (const float*)d_in[20],
              (const float*)d_in[29], pnorm + 2, nullptr, nullptr, nullptr);

    mlp_kernel<<<64, 128, 0, stream>>>(rsum, (const float*)d_in[21], (const float*)d_in[22],
                                       (const float*)d_in[23], (const float*)d_in[24],
                                       (const float*)d_in[25], (const float*)d_in[26],
                                       (float*)d_out);
}

// Round 9
// 633.689 us; speedup vs baseline: 2.5862x; 1.0897x over previous
//
#include <hip/hip_runtime.h>
#include <hip/hip_bf16.h>
#include <math.h>

#define BGR 64
#define EMAX 1024000

typedef _Float16 f16x8 __attribute__((ext_vector_type(8)));
typedef float f32x4 __attribute__((ext_vector_type(4)));

// ---------------- fused init: pnorm x3 + ecnt + deg zero ----------------
__global__ __launch_bounds__(256) void pnorm3_kernel(const float* __restrict__ p1,
                              const float* __restrict__ p2,
                              const float* __restrict__ p3, float* __restrict__ out,
                              int* __restrict__ ecnt, int* __restrict__ deg) {
    __shared__ float buf[128];
    int t = threadIdx.x, b = blockIdx.x;
    for (int i = b * 256 + t; i < 64000; i += 1024) deg[i] = 0;
    if (b < 3) {
        const float* p = (b == 0) ? p1 : (b == 1) ? p2 : p3;
        if (t < 128) buf[t] = p[t] * p[t];
        __syncthreads();
        for (int off = 64; off; off >>= 1) {
            if (t < off) buf[t] += buf[t + off];
            __syncthreads();
        }
        if (t == 0) out[b] = sqrtf(buf[0]);
    } else if (t == 0) {
        ecnt[0] = EMAX; ecnt[1] = 0; ecnt[2] = 0;
    }
}

// ---------------- weight split: f32 [k][n] -> f16 hi/lo chunk-major ----------------
struct WP { const float* w[9]; };

__global__ void wsplit_kernel(WP wp, _Float16* __restrict__ out) {
    int mat = blockIdx.x;
    const float* __restrict__ w = wp.w[mat];
    _Float16* __restrict__ dst = out + (size_t)mat * 32768;
    for (int e = threadIdx.x; e < 2048; e += 256) {
        int n = e >> 4;
        int kb = (e & 15) * 8;
        f16x8 hi, lo;
#pragma unroll
        for (int j = 0; j < 8; j++) {
            float v = w[(kb + j) * 128 + n];
            _Float16 h = (_Float16)v;
            hi[j] = h;
            lo[j] = (_Float16)((v - (float)h) * 2048.0f);
        }
        int ks = kb >> 5, kg = (kb >> 3) & 3;
        *(f16x8*)(dst + ((((ks * 2 + 0) * 4 + kg) * 128 + n) * 8)) = hi;
        *(f16x8*)(dst + ((((ks * 2 + 1) * 4 + kg) * 128 + n) * 8)) = lo;
    }
}

// ---------------- degree count (layer 1 only) ----------------
__global__ void count_kernel(const int* __restrict__ dst, const int* __restrict__ ecnt,
                             int* __restrict__ deg) {
    int e = blockIdx.x * 256 + threadIdx.x;
    if (e >= ecnt[0]) return;
    atomicAdd(&deg[dst[e]], 1);
}

// ---------------- CSR scan chain (proven): scan1 reads+zeroes deg, computes dinv ------
__global__ void scan1_kernel(int* __restrict__ deg, int* __restrict__ rowptr,
                             int* __restrict__ part, float* __restrict__ dinv) {
    __shared__ int buf[256];
    int t = threadIdx.x;
    int i = blockIdx.x * 256 + t;
    int v = deg[i];
    deg[i] = 0;
    dinv[i] = rsqrtf((float)v + 1.0f);
    buf[t] = v;
    __syncthreads();
    for (int off = 1; off < 256; off <<= 1) {
        int tmp = (t >= off) ? buf[t - off] : 0;
        __syncthreads();
        buf[t] += tmp;
        __syncthreads();
    }
    rowptr[i] = buf[t] - v;
    if (t == 255) part[blockIdx.x] = buf[255];
}

__global__ void scan2_kernel(int* __restrict__ part, int* __restrict__ rowptr, int nb, int n) {
    __shared__ int buf[256];
    int t = threadIdx.x;
    int v = (t < nb) ? part[t] : 0;
    buf[t] = v;
    __syncthreads();
    for (int off = 1; off < 256; off <<= 1) {
        int tmp = (t >= off) ? buf[t - off] : 0;
        __syncthreads();
        buf[t] += tmp;
        __syncthreads();
    }
    if (t < nb) part[t] = buf[t] - v;
    if (t == 255) rowptr[n] = buf[255];
}

__global__ void scan3_kernel(int* __restrict__ rowptr, int* __restrict__ cursor,
                             const int* __restrict__ part) {
    int i = blockIdx.x * 256 + threadIdx.x;
    int v = rowptr[i] + part[blockIdx.x];
    rowptr[i] = v;
    cursor[i] = v;
}

__global__ void scatter_kernel(const int* __restrict__ src, const int* __restrict__ dst,
                               const int* __restrict__ ecnt, int* __restrict__ cursor,
                               const float* __restrict__ dinv, int* __restrict__ colidx,
                               float* __restrict__ wcoef) {
    int e = blockIdx.x * 256 + threadIdx.x;
    if (e >= ecnt[0]) return;
    int s = src[e], d = dst[e];
    int pos = atomicAdd(&cursor[d], 1);
    colidx[pos] = s;
    wcoef[pos] = dinv[s] * dinv[d];
}

// ---------------- fused 3-branch MFMA GEMM (f16 split, f32-equivalent accuracy) ----------
__global__ __launch_bounds__(256) void gemm3m_kernel(
    const float* __restrict__ x, const _Float16* __restrict__ wsp,
    const float* __restrict__ b0, const float* __restrict__ b1, const float* __restrict__ b2,
    float* __restrict__ out) {
    __shared__ _Float16 ws[2][8192] __attribute__((aligned(16)));
    const int tid = threadIdx.x;
    const int wave = tid >> 6;
    const int lane = tid & 63;
    const int l15 = lane & 15;
    const int kg = lane >> 4;          // 0..3
    const long base = (long)blockIdx.x * 64;
    const int m = wave * 16 + l15;     // row within block tile

    float4 xrow[8];
    const float4* xg = (const float4*)(x + (base + m) * 128);
#pragma unroll
    for (int q = 0; q < 8; q++) xrow[q] = xg[(q >> 1) * 8 + kg * 2 + (q & 1)];

    auto stage = [&](int c, int buf) {
#pragma unroll
        for (int t = 0; t < 4; t++) {
            int u = tid + t * 256;
            __builtin_amdgcn_global_load_lds(
                (const __attribute__((address_space(1))) unsigned int*)(wsp + (size_t)c * 8192 + u * 8),
                (__attribute__((address_space(3))) unsigned int*)(&ws[buf][u * 8]),
                16, 0, 0);
        }
    };

    float tot[8][4];
#pragma unroll
    for (int nt = 0; nt < 8; nt++)
#pragma unroll
        for (int r = 0; r < 4; r++) tot[nt][r] = 0.f;

    f32x4 acc_h[8], acc_m[8];
    stage(0, 0);

#pragma unroll
    for (int c = 0; c < 12; c++) {
        const int br = c >> 2, ks = c & 3, buf = c & 1;
        if (ks == 0) {
#pragma unroll
            for (int nt = 0; nt < 8; nt++) {
                acc_h[nt] = (f32x4){0.f, 0.f, 0.f, 0.f};
                acc_m[nt] = (f32x4){0.f, 0.f, 0.f, 0.f};
            }
        }
        __syncthreads();
        if (c < 11) stage(c + 1, buf ^ 1);

        float ev[8] = {xrow[ks * 2].x, xrow[ks * 2].y, xrow[ks * 2].z, xrow[ks * 2].w,
                       xrow[ks * 2 + 1].x, xrow[ks * 2 + 1].y, xrow[ks * 2 + 1].z, xrow[ks * 2 + 1].w};
        f16x8 ah, al;
#pragma unroll
        for (int i = 0; i < 8; i++) {
            _Float16 h = (_Float16)ev[i];
            ah[i] = h;
            al[i] = (_Float16)((ev[i] - (float)h) * 2048.0f);
        }

        const _Float16* wb = &ws[buf][0];
        const int nb = kg * 1024 + l15 * 8;
        f16x8 bh[8], bl[8];
#pragma unroll
        for (int nt = 0; nt < 8; nt++) {
            bh[nt] = *(const f16x8*)(wb + nb + nt * 128);
            bl[nt] = *(const f16x8*)(wb + 4096 + nb + nt * 128);
        }
#pragma unroll
        for (int nt = 0; nt < 8; nt++)
            acc_h[nt] = __builtin_amdgcn_mfma_f32_16x16x32_f16(ah, bh[nt], acc_h[nt], 0, 0, 0);
#pragma unroll
        for (int nt = 0; nt < 8; nt++)
            acc_m[nt] = __builtin_amdgcn_mfma_f32_16x16x32_f16(ah, bl[nt], acc_m[nt], 0, 0, 0);
#pragma unroll
        for (int nt = 0; nt < 8; nt++)
            acc_m[nt] = __builtin_amdgcn_mfma_f32_16x16x32_f16(al, bh[nt], acc_m[nt], 0, 0, 0);

        if (ks == 3) {
            const float* bb = (br == 0) ? b0 : (br == 1) ? b1 : b2;
#pragma unroll
            for (int nt = 0; nt < 8; nt++) {
                float bv = bb[nt * 16 + l15];
#pragma unroll
                for (int r = 0; r < 4; r++)
                    tot[nt][r] += fmaxf(acc_h[nt][r] + acc_m[nt][r] * (1.0f / 2048.0f) + bv, 0.f);
            }
        }
    }

    float* op = out + (base + wave * 16 + kg * 4) * 128 + l15;
#pragma unroll
    for (int nt = 0; nt < 8; nt++)
#pragma unroll
        for (int r = 0; r < 4; r++) op[r * 128 + nt * 16] = tot[nt][r];
}

// ---------------- propagation (+optional fused score) ----------------
// 2 nodes per wave, HALF-WAVE each (float4/lane): one gather instruction moves
// 1KB covering both rows; 32 edges in flight. Batches of 16 edges/row with
// clamped index + zero weight (no tail code). Metadata broadcast via readlane.
template <int SC>
__global__ __launch_bounds__(256, 4) void prop_t(
    const float* __restrict__ hin, float* __restrict__ hout,
    const int* __restrict__ rowptr, const int* __restrict__ colidx,
    const float* __restrict__ wcoef, const float* __restrict__ dinv,
    const float* __restrict__ p, const float* __restrict__ pn, float* __restrict__ score) {
    int per = gridDim.x >> 3;
    int b = blockIdx.x;
    int sb = (b & 7) * per + (b >> 3);          // XCD swizzle
    int wave = threadIdx.x >> 6;
    int lane = threadIdx.x & 63;
    int half = lane >> 5;                        // 0 = node A, 1 = node B
    int l31 = lane & 31;
    int node = sb * 8 + wave * 2 + half;

    const char* hb = (const char*)hin;
    const unsigned loff = (unsigned)l31 * 16u;

    float4 hv = *(const float4*)(hb + (size_t)node * 512 + loff);
    float di = dinv[node];
    float selfc = 1.0f + di * di;
    float ax = hv.x * selfc, ay = hv.y * selfc, az = hv.z * selfc, aw = hv.w * selfc;

    int e0 = rowptr[node];
    int e1 = rowptr[node + 1];
    int deg = e1 - e0;
    int degA = __builtin_amdgcn_readlane(deg, 0);
    int degB = __builtin_amdgcn_readlane(deg, 32);
    int dmax = degA > degB ? degA : degB;
    int T = (dmax + 15) >> 4;

    for (int t = 0; t < T; ++t) {
        int ee = e0 + t * 16 + (lane & 15);
        int ec = ee < e1 - 1 ? ee : e1 - 1;
        ec = ec > 0 ? ec : 0;
        int ci = colidx[ec];
        float wv = (ee < e1) ? wcoef[ec] : 0.0f;
        int wi = __float_as_int(wv);
        float4 g[16];
        float w[16];
#pragma unroll
        for (int j = 0; j < 16; ++j) {
            int iA = __builtin_amdgcn_readlane(ci, j);
            int iB = __builtin_amdgcn_readlane(ci, j + 32);
            float wA = __int_as_float(__builtin_amdgcn_readlane(wi, j));
            float wB = __int_as_float(__builtin_amdgcn_readlane(wi, j + 32));
            int idx = half ? iB : iA;
            w[j] = half ? wB : wA;
            g[j] = *(const float4*)(hb + (unsigned)idx * 512u + loff);
        }
        __builtin_amdgcn_sched_barrier(0);
#pragma unroll
        for (int j = 0; j < 16; ++j) {
            ax += w[j] * g[j].x;
            ay += w[j] * g[j].y;
            az += w[j] * g[j].z;
            aw += w[j] * g[j].w;
        }
    }

    *(float4*)((char*)hout + (size_t)node * 512 + loff) = make_float4(ax, ay, az, aw);

    if (SC) {
        float4 pv = ((const float4*)p)[l31];
        float v = ax * pv.x + ay * pv.y + az * pv.z + aw * pv.w;
        v += __shfl_xor(v, 16);
        v += __shfl_xor(v, 8);
        v += __shfl_xor(v, 4);
        v += __shfl_xor(v, 2);
        v += __shfl_xor(v, 1);
        if (l31 == 0) score[node] = v / pn[0];
    }
}

// ---------------- top-k pool: bitonic sort 1024 per graph ----------------
__global__ __launch_bounds__(256) void pool_kernel(const float* __restrict__ score, int npg, int k,
                            int* __restrict__ perm, float* __restrict__ gate,
                            int* __restrict__ remap) {
    __shared__ float sval[1024];
    __shared__ int sidx[1024];
    int b = blockIdx.x, t = threadIdx.x;
    for (int i = t; i < 1024; i += 256) {
        sval[i] = (i < npg) ? score[b * npg + i] : -INFINITY;
        sidx[i] = i;
    }
    __syncthreads();
    for (int ksz = 2; ksz <= 1024; ksz <<= 1) {
        for (int j = ksz >> 1; j > 0; j >>= 1) {
            for (int i = t; i < 1024; i += 256) {
                int l = i ^ j;
                if (l > i) {
                    float vi = sval[i], vl = sval[l];
                    bool up = ((i & ksz) == 0);
                    bool sw = up ? (vi < vl) : (vi > vl);   // descending sort
                    if (sw) {
                        sval[i] = vl; sval[l] = vi;
                        int tmp = sidx[i]; sidx[i] = sidx[l]; sidx[l] = tmp;
                    }
                }
            }
            __syncthreads();
        }
    }
    for (int i = t; i < k; i += 256) {
        int oldg = b * npg + sidx[i];
        int newg = b * k + i;
        perm[newg] = oldg;
        gate[newg] = tanhf(sval[i]);
        remap[oldg] = newg;
    }
    for (int i = k + t; i < npg; i += 256)
        remap[b * npg + sidx[i]] = -1;
}

// ---------------- gather new_x = h[perm] * gate ----------------
__global__ void newx_kernel(const float* __restrict__ h, const int* __restrict__ perm,
                            const float* __restrict__ gate, float* __restrict__ xo) {
    int m = blockIdx.x * 4 + (threadIdx.x >> 6);
    int lane = threadIdx.x & 63;
    int old = perm[m];
    float g = gate[m];
    float2 v = ((const float2*)h)[old * 64 + lane];
    ((float2*)xo)[m * 64 + lane] = make_float2(v.x * g, v.y * g);
}

// ---------------- readout: rsum[b] (=|+=) [max over k ; mean over k] ----------------
__global__ __launch_bounds__(512) void readout_kernel(const float* __restrict__ x,
                                                      float* __restrict__ rsum, int k,
                                                      int first) {
    __shared__ float smx[4][128], ssm[4][128];
    int b = blockIdx.x, t = threadIdx.x;
    int f = t & 127, c = t >> 7;
    int rows = k >> 2;
    const float* base = x + (size_t)b * k * 128 + (size_t)c * rows * 128 + f;
    float mx = -INFINITY, sm = 0.f;
#pragma unroll 8
    for (int j = 0; j < rows; j++) {
        float v = base[(size_t)j * 128];
        mx = fmaxf(mx, v);
        sm += v;
    }
    smx[c][f] = mx;
    ssm[c][f] = sm;
    __syncthreads();
    if (c == 0) {
        float m2 = fmaxf(fmaxf(smx[0][f], smx[1][f]), fmaxf(smx[2][f], smx[3][f]));
        float s2 = (ssm[0][f] + ssm[1][f] + ssm[2][f] + ssm[3][f]) / (float)k;
        if (first) {
            rsum[b * 256 + f] = m2;
            rsum[b * 256 + 128 + f] = s2;
        } else {
            rsum[b * 256 + f] += m2;
            rsum[b * 256 + 128 + f] += s2;
        }
    }
}

// ---------------- edge remap + compact + fused next-layer degree count ----------------
__global__ __launch_bounds__(1024) void compact_kernel(
    const int* __restrict__ src, const int* __restrict__ dst,
    const int* __restrict__ ecnt, const int* __restrict__ remap,
    int* __restrict__ so, int* __restrict__ dd, int* __restrict__ ecout,
    int* __restrict__ deg) {
    __shared__ int wcnt[16];
    __shared__ int bbase;
    int n = ecnt[0];
    int e = blockIdx.x * 1024 + threadIdx.x;
    int wave = threadIdx.x >> 6;
    int lane = threadIdx.x & 63;
    bool v = false;
    int s = 0, d = 0;
    if (e < n) {
        s = remap[src[e]];
        d = remap[dst[e]];
        v = ((s | d) >= 0);
    }
    unsigned long long m = __ballot(v);
    int before = __popcll(m & ((1ULL << lane) - 1ULL));
    if (lane == 0) wcnt[wave] = __popcll(m);
    __syncthreads();
    if (threadIdx.x == 0) {
        int tot = 0;
#pragma unroll
        for (int i = 0; i < 16; i++) { int c = wcnt[i]; wcnt[i] = tot; tot += c; }
        bbase = atomicAdd(ecout, tot);
    }
    __syncthreads();
    if (v) {
        int pos = bbase + wcnt[wave] + before;
        so[pos] = s;
        dd[pos] = d;
        atomicAdd(&deg[d], 1);
    }
}

// ---------------- fused final MLP + log_softmax ----------------
__global__ void mlp_kernel(const float* __restrict__ rsum,
                           const float* __restrict__ w1, const float* __restrict__ b1,
                           const float* __restrict__ w2, const float* __restrict__ b2,
                           const float* __restrict__ w3, const float* __restrict__ b3,
                           float* __restrict__ out) {
    __shared__ float z0[256], z1l[128], z2l[64], lg[10], ls;
    int b = blockIdx.x, t = threadIdx.x;   // 128 threads
    z0[t] = rsum[b * 256 + t];
    z0[t + 128] = rsum[b * 256 + 128 + t];
    __syncthreads();
    float acc = b1[t];
    for (int k = 0; k < 256; k++) acc += z0[k] * w1[k * 128 + t];
    z1l[t] = fmaxf(acc, 0.f);
    __syncthreads();
    if (t < 64) {
        acc = b2[t];
        for (int k = 0; k < 128; k++) acc += z1l[k] * w2[k * 64 + t];
        z2l[t] = fmaxf(acc, 0.f);
    }
    __syncthreads();
    if (t < 10) {
        acc = b3[t];
        for (int k = 0; k < 64; k++) acc += z2l[k] * w3[k * 10 + t];
        lg[t] = acc;
    }
    __syncthreads();
    if (t == 0) {
        float mx = lg[0];
        for (int c = 1; c < 10; c++) mx = fmaxf(mx, lg[c]);
        float s = 0.f;
        for (int c = 0; c < 10; c++) s += expf(lg[c] - mx);
        ls = mx + logf(s);
    }
    __syncthreads();
    if (t < 10) out[b * 10 + t] = lg[t] - ls;
}

// =====================================================================
extern "C" void kernel_launch(void* const* d_in, const int* in_sizes, int n_in,
                              void* d_out, int out_size, void* d_ws, size_t ws_size,
                              hipStream_t stream) {
    char* ws = (char*)d_ws;
    size_t off = 0;
    auto alloc = [&](size_t bytes) -> void* {
        void* p = ws + off;
        off += (bytes + 255) & ~(size_t)255;
        return p;
    };
    float* hA = (float*)alloc(64000UL * 128 * 4);
    float* hB = (float*)alloc(64000UL * 128 * 4);
    float* score = (float*)alloc(64000UL * 4);
    float* dinvb = (float*)alloc(64000UL * 4);
    int* deg = (int*)alloc(64000UL * 4);
    int* rowptr = (int*)alloc(64001UL * 4);
    int* cursor = (int*)alloc(64000UL * 4);
    int* part = (int*)alloc(1024);
    int* colidx = (int*)alloc((size_t)EMAX * 4);
    float* wcoef = (float*)alloc((size_t)EMAX * 4);
    int* srcA = (int*)alloc((size_t)EMAX * 4);
    int* dstA = (int*)alloc((size_t)EMAX * 4);
    int* srcB = (int*)alloc((size_t)EMAX * 4);
    int* dstB = (int*)alloc((size_t)EMAX * 4);
    int* perm = (int*)alloc(51200UL * 4);
    float* gate = (float*)alloc(51200UL * 4);
    int* remap = (int*)alloc(64000UL * 4);
    float* rsum = (float*)alloc(64UL * 256 * 4);
    _Float16* wsall = (_Float16*)alloc(9UL * 32768 * 2);
    float* pnorm = (float*)alloc(256);
    int* ecnt = (int*)alloc(256);
    (void)ws_size;  // requires ~94 MB

    const float* x0 = (const float*)d_in[0];
    const int* src0 = (const int*)d_in[1];
    const int* dst0 = (const int*)d_in[2];

    pnorm3_kernel<<<4, 256, 0, stream>>>((const float*)d_in[27], (const float*)d_in[28],
                                         (const float*)d_in[29], pnorm, ecnt, deg);

    WP wp;
    wp.w[0] = (const float*)d_in[3];  wp.w[1] = (const float*)d_in[5];  wp.w[2] = (const float*)d_in[7];
    wp.w[3] = (const float*)d_in[9];  wp.w[4] = (const float*)d_in[11]; wp.w[5] = (const float*)d_in[13];
    wp.w[6] = (const float*)d_in[15]; wp.w[7] = (const float*)d_in[17]; wp.w[8] = (const float*)d_in[19];
    wsplit_kernel<<<9, 256, 0, stream>>>(wp, wsall);

    auto run_layer = [&](int n, int npg, int k, const float* x, int layer, bool do_count,
                         const int* esrc, const int* edst, const int* ecin,
                         const float* ba, const float* bb, const float* bc,
                         const float* p, const float* pn,
                         int* so, int* ddst, int* ecout) {
        if (do_count)
            count_kernel<<<EMAX / 256, 256, 0, stream>>>(edst, ecin, deg);
        scan1_kernel<<<n / 256, 256, 0, stream>>>(deg, rowptr, part, dinvb);
        scan2_kernel<<<1, 256, 0, stream>>>(part, rowptr, n / 256, n);
        scan3_kernel<<<n / 256, 256, 0, stream>>>(rowptr, cursor, part);
        scatter_kernel<<<EMAX / 256, 256, 0, stream>>>(esrc, edst, ecin, cursor, dinvb,
                                                       colidx, wcoef);
        gemm3m_kernel<<<n / 64, 256, 0, stream>>>(x, wsall + (size_t)layer * 3 * 32768,
                                                  ba, bb, bc, hA);
        prop_t<0><<<n / 8, 256, 0, stream>>>(hA, hB, rowptr, colidx, wcoef, dinvb,
                                             nullptr, nullptr, nullptr);
        prop_t<1><<<n / 8, 256, 0, stream>>>(hB, hA, rowptr, colidx, wcoef, dinvb,
                                             p, pn, score);
        pool_kernel<<<BGR, 256, 0, stream>>>(score, npg, k, perm, gate, remap);
        newx_kernel<<<(BGR * k) / 4, 256, 0, stream>>>(hA, perm, gate, hB);
        readout_kernel<<<BGR, 512, 0, stream>>>(hB, rsum, k, layer == 0 ? 1 : 0);
        if (ecout)
            compact_kernel<<<EMAX / 1024, 1024, 0, stream>>>(esrc, edst, ecin, remap, so, ddst,
                                                             ecout, deg);
    };

    run_layer(64000, 1000, 800, x0, 0, true, src0, dst0, ecnt + 0,
              (const float*)d_in[4], (const float*)d_in[6], (const float*)d_in[8],
              (const float*)d_in[27], pnorm + 0, srcA, dstA, ecnt + 1);

    run_layer(51200, 800, 640, hB, 1, false, srcA, dstA, ecnt + 1,
              (const float*)d_in[10], (const float*)d_in[12], (const float*)d_in[14],
              (const float*)d_in[28], pnorm + 1, srcB, dstB, ecnt + 2);

    run_layer(40960, 640, 512, hB, 2, false, srcB, dstB, ecnt + 2,
              (const float*)d_in[16], (const float*)d_in[18], (const float*)d_in[20],
              (const float*)d_in[29], pnorm + 2, nullptr, nullptr, nullptr);

    mlp_kernel<<<64, 128, 0, stream>>>(rsum, (const float*)d_in[21], (const float*)d_in[22],
                                       (const float*)d_in[23], (const float*)d_in[24],
                                       (const float*)d_in[25], (const float*)d_in[26],
                                       (float*)d_out);
}

// Round 11
// 613.080 us; speedup vs baseline: 2.6731x; 1.0336x over previous
//
#include <hip/hip_runtime.h>
#include <hip/hip_bf16.h>
#include <math.h>

#define BGR 64
#define EMAX 1024000

typedef _Float16 f16x8 __attribute__((ext_vector_type(8)));
typedef float f32x4 __attribute__((ext_vector_type(4)));

// ---------------- fused init: pnorm x3 + ecnt + deg zero ----------------
__global__ __launch_bounds__(256) void pnorm3_kernel(const float* __restrict__ p1,
                              const float* __restrict__ p2,
                              const float* __restrict__ p3, float* __restrict__ out,
                              int* __restrict__ ecnt, int* __restrict__ deg) {
    __shared__ float buf[128];
    int t = threadIdx.x, b = blockIdx.x;
    for (int i = b * 256 + t; i < 64000; i += 1024) deg[i] = 0;
    if (b < 3) {
        const float* p = (b == 0) ? p1 : (b == 1) ? p2 : p3;
        if (t < 128) buf[t] = p[t] * p[t];
        __syncthreads();
        for (int off = 64; off; off >>= 1) {
            if (t < off) buf[t] += buf[t + off];
            __syncthreads();
        }
        if (t == 0) out[b] = sqrtf(buf[0]);
    } else if (t == 0) {
        ecnt[0] = EMAX; ecnt[1] = 0; ecnt[2] = 0;
    }
}

// ---------------- weight split: f32 [k][n] -> f16 hi/lo chunk-major ----------------
struct WP { const float* w[9]; };

__global__ void wsplit_kernel(WP wp, _Float16* __restrict__ out) {
    int mat = blockIdx.x;
    const float* __restrict__ w = wp.w[mat];
    _Float16* __restrict__ dst = out + (size_t)mat * 32768;
    for (int e = threadIdx.x; e < 2048; e += 256) {
        int n = e >> 4;
        int kb = (e & 15) * 8;
        f16x8 hi, lo;
#pragma unroll
        for (int j = 0; j < 8; j++) {
            float v = w[(kb + j) * 128 + n];
            _Float16 h = (_Float16)v;
            hi[j] = h;
            lo[j] = (_Float16)((v - (float)h) * 2048.0f);
        }
        int ks = kb >> 5, kg = (kb >> 3) & 3;
        *(f16x8*)(dst + ((((ks * 2 + 0) * 4 + kg) * 128 + n) * 8)) = hi;
        *(f16x8*)(dst + ((((ks * 2 + 1) * 4 + kg) * 128 + n) * 8)) = lo;
    }
}

// ---------------- degree count (layer 1 only), 4 edges/thread ----------------
__global__ void count_kernel(const int* __restrict__ dst, const int* __restrict__ ecnt,
                             int* __restrict__ deg) {
    int i = blockIdx.x * 256 + threadIdx.x;
    if (i * 4 >= ecnt[0]) return;
    int4 d = ((const int4*)dst)[i];
    atomicAdd(&deg[d.x], 1);
    atomicAdd(&deg[d.y], 1);
    atomicAdd(&deg[d.z], 1);
    atomicAdd(&deg[d.w], 1);
}

// ---------------- CSR scan chain: scan1 reads+zeroes deg, computes dinv ------
__global__ void scan1_kernel(int* __restrict__ deg, int* __restrict__ rowptr,
                             int* __restrict__ part, float* __restrict__ dinv) {
    __shared__ int buf[256];
    int t = threadIdx.x;
    int i = blockIdx.x * 256 + t;
    int v = deg[i];
    deg[i] = 0;
    dinv[i] = rsqrtf((float)v + 1.0f);
    buf[t] = v;
    __syncthreads();
    for (int off = 1; off < 256; off <<= 1) {
        int tmp = (t >= off) ? buf[t - off] : 0;
        __syncthreads();
        buf[t] += tmp;
        __syncthreads();
    }
    rowptr[i] = buf[t] - v;
    if (t == 255) part[blockIdx.x] = buf[255];
}

__global__ void scan2_kernel(int* __restrict__ part, int* __restrict__ rowptr, int nb, int n) {
    __shared__ int buf[256];
    int t = threadIdx.x;
    int v = (t < nb) ? part[t] : 0;
    buf[t] = v;
    __syncthreads();
    for (int off = 1; off < 256; off <<= 1) {
        int tmp = (t >= off) ? buf[t - off] : 0;
        __syncthreads();
        buf[t] += tmp;
        __syncthreads();
    }
    if (t < nb) part[t] = buf[t] - v;
    if (t == 255) rowptr[n] = buf[255];
}

__global__ void scan3_kernel(int* __restrict__ rowptr, int* __restrict__ cursor,
                             const int* __restrict__ part) {
    int i = blockIdx.x * 256 + threadIdx.x;
    int v = rowptr[i] + part[blockIdx.x];
    rowptr[i] = v;
    cursor[i] = v;
}

// ---------------- scatter: packed int2 {colidx, wcoef} -> 1 random line/edge ---------
__global__ void scatter_kernel(const int* __restrict__ src, const int* __restrict__ dst,
                               const int* __restrict__ ecnt, int* __restrict__ cursor,
                               const float* __restrict__ dinv, int2* __restrict__ edata) {
    int e = blockIdx.x * 256 + threadIdx.x;
    if (e >= ecnt[0]) return;
    int s = src[e], d = dst[e];
    int pos = atomicAdd(&cursor[d], 1);
    edata[pos] = make_int2(s, __float_as_int(dinv[s] * dinv[d]));
}

// ---------------- fused 3-branch MFMA GEMM (f16 split, f32-equivalent accuracy) ----------
// Half-matrix double buffer: 6 stages x 32KB (16384 f16). Barriers 6 (was 12).
// LDS 64KB -> 2 blocks/CU.
__global__ __launch_bounds__(256) void gemm3m_kernel(
    const float* __restrict__ x, const _Float16* __restrict__ wsp,
    const float* __restrict__ b0, const float* __restrict__ b1, const float* __restrict__ b2,
    float* __restrict__ out) {
    __shared__ _Float16 ws[2][16384] __attribute__((aligned(16)));
    const int tid = threadIdx.x;
    const int wave = tid >> 6;
    const int lane = tid & 63;
    const int l15 = lane & 15;
    const int kg = lane >> 4;          // 0..3
    const long base = (long)blockIdx.x * 64;
    const int m = wave * 16 + l15;     // row within block tile

    float4 xrow[8];
    const float4* xg = (const float4*)(x + (base + m) * 128);
#pragma unroll
    for (int q = 0; q < 8; q++) xrow[q] = xg[(q >> 1) * 8 + kg * 2 + (q & 1)];

    // stage 16384 f16 = 32KB (half matrix: 2 ks chunks)
    auto stageH = [&](int s, int buf) {
#pragma unroll
        for (int t = 0; t < 8; t++) {
            int u = tid + t * 256;     // 0..2047, 16B each
            __builtin_amdgcn_global_load_lds(
                (const __attribute__((address_space(1))) unsigned int*)(wsp + (size_t)s * 16384 + u * 8),
                (__attribute__((address_space(3))) unsigned int*)(&ws[buf][u * 8]),
                16, 0, 0);
        }
    };

    float tot[8][4];
#pragma unroll
    for (int nt = 0; nt < 8; nt++)
#pragma unroll
        for (int r = 0; r < 4; r++) tot[nt][r] = 0.f;

    f32x4 acc_h[8], acc_m[8];
    stageH(0, 0);

    for (int s = 0; s < 6; s++) {
        const int j = s >> 1;          // matrix index
        __syncthreads();               // half s staged; other buffer free
        if (s < 5) stageH(s + 1, (s & 1) ^ 1);

        if ((s & 1) == 0) {
#pragma unroll
            for (int nt = 0; nt < 8; nt++) {
                acc_h[nt] = (f32x4){0.f, 0.f, 0.f, 0.f};
                acc_m[nt] = (f32x4){0.f, 0.f, 0.f, 0.f};
            }
        }

        const _Float16* wbase = &ws[s & 1][0];
#pragma unroll
        for (int ksl = 0; ksl < 2; ksl++) {
            const int ks = (s & 1) * 2 + ksl;
            float ev[8] = {xrow[ks * 2].x, xrow[ks * 2].y, xrow[ks * 2].z, xrow[ks * 2].w,
                           xrow[ks * 2 + 1].x, xrow[ks * 2 + 1].y, xrow[ks * 2 + 1].z, xrow[ks * 2 + 1].w};
            f16x8 ah, al;
#pragma unroll
            for (int i = 0; i < 8; i++) {
                _Float16 h = (_Float16)ev[i];
                ah[i] = h;
                al[i] = (_Float16)((ev[i] - (float)h) * 2048.0f);
            }
            const _Float16* wb = wbase + ksl * 8192;
            const int nb = kg * 1024 + l15 * 8;
            f16x8 bh[8], bl[8];
#pragma unroll
            for (int nt = 0; nt < 8; nt++) {
                bh[nt] = *(const f16x8*)(wb + nb + nt * 128);
                bl[nt] = *(const f16x8*)(wb + 4096 + nb + nt * 128);
            }
#pragma unroll
            for (int nt = 0; nt < 8; nt++)
                acc_h[nt] = __builtin_amdgcn_mfma_f32_16x16x32_f16(ah, bh[nt], acc_h[nt], 0, 0, 0);
#pragma unroll
            for (int nt = 0; nt < 8; nt++)
                acc_m[nt] = __builtin_amdgcn_mfma_f32_16x16x32_f16(ah, bl[nt], acc_m[nt], 0, 0, 0);
#pragma unroll
            for (int nt = 0; nt < 8; nt++)
                acc_m[nt] = __builtin_amdgcn_mfma_f32_16x16x32_f16(al, bh[nt], acc_m[nt], 0, 0, 0);
        }

        if (s & 1) {
            const float* bb = (j == 0) ? b0 : (j == 1) ? b1 : b2;
#pragma unroll
            for (int nt = 0; nt < 8; nt++) {
                float bv = bb[nt * 16 + l15];
#pragma unroll
                for (int r = 0; r < 4; r++)
                    tot[nt][r] += fmaxf(acc_h[nt][r] + acc_m[nt][r] * (1.0f / 2048.0f) + bv, 0.f);
            }
        }
    }

    float* op = out + (base + wave * 16 + kg * 4) * 128 + l15;
#pragma unroll
    for (int nt = 0; nt < 8; nt++)
#pragma unroll
        for (int r = 0; r < 4; r++) op[r * 128 + nt * 16] = tot[nt][r];
}

// ---------------- propagation (+optional fused score) ----------------
// 2 nodes per wave, HALF-WAVE each (float4/lane): 1KB per gather instruction,
// 32 edges in flight. Packed int2 edge meta; readlane broadcast; no tail code.
template <int SC>
__global__ __launch_bounds__(256, 4) void prop_t(
    const float* __restrict__ hin, float* __restrict__ hout,
    const int* __restrict__ rowptr, const int2* __restrict__ edata,
    const float* __restrict__ dinv,
    const float* __restrict__ p, const float* __restrict__ pn, float* __restrict__ score) {
    int per = gridDim.x >> 3;
    int b = blockIdx.x;
    int sb = (b & 7) * per + (b >> 3);          // XCD swizzle
    int wave = threadIdx.x >> 6;
    int lane = threadIdx.x & 63;
    int half = lane >> 5;                        // 0 = node A, 1 = node B
    int l31 = lane & 31;
    int node = sb * 8 + wave * 2 + half;

    const char* hb = (const char*)hin;
    const unsigned loff = (unsigned)l31 * 16u;

    float4 hv = *(const float4*)(hb + (size_t)node * 512 + loff);
    float di = dinv[node];
    float selfc = 1.0f + di * di;
    float ax = hv.x * selfc, ay = hv.y * selfc, az = hv.z * selfc, aw = hv.w * selfc;

    int e0 = rowptr[node];
    int e1 = rowptr[node + 1];
    int deg = e1 - e0;
    int degA = __builtin_amdgcn_readlane(deg, 0);
    int degB = __builtin_amdgcn_readlane(deg, 32);
    int dmax = degA > degB ? degA : degB;
    int T = (dmax + 15) >> 4;

    for (int t = 0; t < T; ++t) {
        int ee = e0 + t * 16 + (lane & 15);
        int ec = ee < e1 - 1 ? ee : e1 - 1;
        ec = ec > 0 ? ec : 0;
        int2 md = edata[ec];
        int ci = md.x;
        int wi = (ee < e1) ? md.y : 0;           // 0 bits == 0.0f
        float4 g[16];
        float w[16];
#pragma unroll
        for (int j = 0; j < 16; ++j) {
            int iA = __builtin_amdgcn_readlane(ci, j);
            int iB = __builtin_amdgcn_readlane(ci, j + 32);
            float wA = __int_as_float(__builtin_amdgcn_readlane(wi, j));
            float wB = __int_as_float(__builtin_amdgcn_readlane(wi, j + 32));
            int idx = half ? iB : iA;
            w[j] = half ? wB : wA;
            g[j] = *(const float4*)(hb + (unsigned)idx * 512u + loff);
        }
        __builtin_amdgcn_sched_barrier(0);
#pragma unroll
        for (int j = 0; j < 16; ++j) {
            ax += w[j] * g[j].x;
            ay += w[j] * g[j].y;
            az += w[j] * g[j].z;
            aw += w[j] * g[j].w;
        }
    }

    *(float4*)((char*)hout + (size_t)node * 512 + loff) = make_float4(ax, ay, az, aw);

    if (SC) {
        float4 pv = ((const float4*)p)[l31];
        float v = ax * pv.x + ay * pv.y + az * pv.z + aw * pv.w;
        v += __shfl_xor(v, 16);
        v += __shfl_xor(v, 8);
        v += __shfl_xor(v, 4);
        v += __shfl_xor(v, 2);
        v += __shfl_xor(v, 1);
        if (l31 == 0) score[node] = v / pn[0];
    }
}

// ---------------- top-k pool: bitonic sort 1024 per graph ----------------
__global__ __launch_bounds__(256) void pool_kernel(const float* __restrict__ score, int npg, int k,
                            int* __restrict__ perm, float* __restrict__ gate,
                            int* __restrict__ remap) {
    __shared__ float sval[1024];
    __shared__ int sidx[1024];
    int b = blockIdx.x, t = threadIdx.x;
    for (int i = t; i < 1024; i += 256) {
        sval[i] = (i < npg) ? score[b * npg + i] : -INFINITY;
        sidx[i] = i;
    }
    __syncthreads();
    for (int ksz = 2; ksz <= 1024; ksz <<= 1) {
        for (int j = ksz >> 1; j > 0; j >>= 1) {
            for (int i = t; i < 1024; i += 256) {
                int l = i ^ j;
                if (l > i) {
                    float vi = sval[i], vl = sval[l];
                    bool up = ((i & ksz) == 0);
                    bool sw = up ? (vi < vl) : (vi > vl);   // descending sort
                    if (sw) {
                        sval[i] = vl; sval[l] = vi;
                        int tmp = sidx[i]; sidx[i] = sidx[l]; sidx[l] = tmp;
                    }
                }
            }
            __syncthreads();
        }
    }
    for (int i = t; i < k; i += 256) {
        int oldg = b * npg + sidx[i];
        int newg = b * k + i;
        perm[newg] = oldg;
        gate[newg] = tanhf(sval[i]);
        remap[oldg] = newg;
    }
    for (int i = k + t; i < npg; i += 256)
        remap[b * npg + sidx[i]] = -1;
}

// ---------------- gather new_x = h[perm] * gate ----------------
__global__ void newx_kernel(const float* __restrict__ h, const int* __restrict__ perm,
                            const float* __restrict__ gate, float* __restrict__ xo) {
    int m = blockIdx.x * 4 + (threadIdx.x >> 6);
    int lane = threadIdx.x & 63;
    int old = perm[m];
    float g = gate[m];
    float2 v = ((const float2*)h)[old * 64 + lane];
    ((float2*)xo)[m * 64 + lane] = make_float2(v.x * g, v.y * g);
}

// ---------------- readout: rsum[b] (=|+=) [max over k ; mean over k] ----------------
__global__ __launch_bounds__(512) void readout_kernel(const float* __restrict__ x,
                                                      float* __restrict__ rsum, int k,
                                                      int first) {
    __shared__ float smx[4][128], ssm[4][128];
    int b = blockIdx.x, t = threadIdx.x;
    int f = t & 127, c = t >> 7;
    int rows = k >> 2;
    const float* base = x + (size_t)b * k * 128 + (size_t)c * rows * 128 + f;
    float mx = -INFINITY, sm = 0.f;
#pragma unroll 8
    for (int j = 0; j < rows; j++) {
        float v = base[(size_t)j * 128];
        mx = fmaxf(mx, v);
        sm += v;
    }
    smx[c][f] = mx;
    ssm[c][f] = sm;
    __syncthreads();
    if (c == 0) {
        float m2 = fmaxf(fmaxf(smx[0][f], smx[1][f]), fmaxf(smx[2][f], smx[3][f]));
        float s2 = (ssm[0][f] + ssm[1][f] + ssm[2][f] + ssm[3][f]) / (float)k;
        if (first) {
            rsum[b * 256 + f] = m2;
            rsum[b * 256 + 128 + f] = s2;
        } else {
            rsum[b * 256 + f] += m2;
            rsum[b * 256 + 128 + f] += s2;
        }
    }
}

// ---------------- edge remap + compact + fused next-layer degree count ----------------
__global__ __launch_bounds__(1024) void compact_kernel(
    const int* __restrict__ src, const int* __restrict__ dst,
    const int* __restrict__ ecnt, const int* __restrict__ remap,
    int* __restrict__ so, int* __restrict__ dd, int* __restrict__ ecout,
    int* __restrict__ deg) {
    __shared__ int wcnt[16];
    __shared__ int bbase;
    int n = ecnt[0];
    int e = blockIdx.x * 1024 + threadIdx.x;
    int wave = threadIdx.x >> 6;
    int lane = threadIdx.x & 63;
    bool v = false;
    int s = 0, d = 0;
    if (e < n) {
        s = remap[src[e]];
        d = remap[dst[e]];
        v = ((s | d) >= 0);
    }
    unsigned long long m = __ballot(v);
    int before = __popcll(m & ((1ULL << lane) - 1ULL));
    if (lane == 0) wcnt[wave] = __popcll(m);
    __syncthreads();
    if (threadIdx.x == 0) {
        int tot = 0;
#pragma unroll
        for (int i = 0; i < 16; i++) { int c = wcnt[i]; wcnt[i] = tot; tot += c; }
        bbase = atomicAdd(ecout, tot);
    }
    __syncthreads();
    if (v) {
        int pos = bbase + wcnt[wave] + before;
        so[pos] = s;
        dd[pos] = d;
        atomicAdd(&deg[d], 1);
    }
}

// ---------------- fused final MLP + log_softmax ----------------
__global__ void mlp_kernel(const float* __restrict__ rsum,
                           const float* __restrict__ w1, const float* __restrict__ b1,
                           const float* __restrict__ w2, const float* __restrict__ b2,
                           const float* __restrict__ w3, const float* __restrict__ b3,
                           float* __restrict__ out) {
    __shared__ float z0[256], z1l[128], z2l[64], lg[10], ls;
    int b = blockIdx.x, t = threadIdx.x;   // 128 threads
    z0[t] = rsum[b * 256 + t];
    z0[t + 128] = rsum[b * 256 + 128 + t];
    __syncthreads();
    float acc = b1[t];
    for (int k = 0; k < 256; k++) acc += z0[k] * w1[k * 128 + t];
    z1l[t] = fmaxf(acc, 0.f);
    __syncthreads();
    if (t < 64) {
        acc = b2[t];
        for (int k = 0; k < 128; k++) acc += z1l[k] * w2[k * 64 + t];
        z2l[t] = fmaxf(acc, 0.f);
    }
    __syncthreads();
    if (t < 10) {
        acc = b3[t];
        for (int k = 0; k < 64; k++) acc += z2l[k] * w3[k * 10 + t];
        lg[t] = acc;
    }
    __syncthreads();
    if (t == 0) {
        float mx = lg[0];
        for (int c = 1; c < 10; c++) mx = fmaxf(mx, lg[c]);
        float s = 0.f;
        for (int c = 0; c < 10; c++) s += expf(lg[c] - mx);
        ls = mx + logf(s);
    }
    __syncthreads();
    if (t < 10) out[b * 10 + t] = lg[t] - ls;
}

// =====================================================================
extern "C" void kernel_launch(void* const* d_in, const int* in_sizes, int n_in,
                              void* d_out, int out_size, void* d_ws, size_t ws_size,
                              hipStream_t stream) {
    char* ws = (char*)d_ws;
    size_t off = 0;
    auto alloc = [&](size_t bytes) -> void* {
        void* p = ws + off;
        off += (bytes + 255) & ~(size_t)255;
        return p;
    };
    float* hA = (float*)alloc(64000UL * 128 * 4);
    float* hB = (float*)alloc(64000UL * 128 * 4);
    float* score = (float*)alloc(64000UL * 4);
    float* dinvb = (float*)alloc(64000UL * 4);
    int* deg = (int*)alloc(64000UL * 4);
    int* rowptr = (int*)alloc(64001UL * 4);
    int* cursor = (int*)alloc(64000UL * 4);
    int* part = (int*)alloc(1024);
    int2* edata = (int2*)alloc((size_t)EMAX * 8);
    int* srcA = (int*)alloc((size_t)EMAX * 4);
    int* dstA = (int*)alloc((size_t)EMAX * 4);
    int* srcB = (int*)alloc((size_t)EMAX * 4);
    int* dstB = (int*)alloc((size_t)EMAX * 4);
    int* perm = (int*)alloc(51200UL * 4);
    float* gate = (float*)alloc(51200UL * 4);
    int* remap = (int*)alloc(64000UL * 4);
    float* rsum = (float*)alloc(64UL * 256 * 4);
    _Float16* wsall = (_Float16*)alloc(9UL * 32768 * 2);
    float* pnorm = (float*)alloc(256);
    int* ecnt = (int*)alloc(256);
    (void)ws_size;  // requires ~94 MB

    const float* x0 = (const float*)d_in[0];
    const int* src0 = (const int*)d_in[1];
    const int* dst0 = (const int*)d_in[2];

    pnorm3_kernel<<<4, 256, 0, stream>>>((const float*)d_in[27], (const float*)d_in[28],
                                         (const float*)d_in[29], pnorm, ecnt, deg);

    WP wp;
    wp.w[0] = (const float*)d_in[3];  wp.w[1] = (const float*)d_in[5];  wp.w[2] = (const float*)d_in[7];
    wp.w[3] = (const float*)d_in[9];  wp.w[4] = (const float*)d_in[11]; wp.w[5] = (const float*)d_in[13];
    wp.w[6] = (const float*)d_in[15]; wp.w[7] = (const float*)d_in[17]; wp.w[8] = (const float*)d_in[19];
    wsplit_kernel<<<9, 256, 0, stream>>>(wp, wsall);

    auto run_layer = [&](int n, int npg, int k, const float* x, int layer, bool do_count,
                         const int* esrc, const int* edst, const int* ecin,
                         const float* ba, const float* bb, const float* bc,
                         const float* p, const float* pn,
                         int* so, int* ddst, int* ecout) {
        if (do_count)
            count_kernel<<<EMAX / 1024, 256, 0, stream>>>(edst, ecin, deg);
        scan1_kernel<<<n / 256, 256, 0, stream>>>(deg, rowptr, part, dinvb);
        scan2_kernel<<<1, 256, 0, stream>>>(part, rowptr, n / 256, n);
        scan3_kernel<<<n / 256, 256, 0, stream>>>(rowptr, cursor, part);
        scatter_kernel<<<EMAX / 256, 256, 0, stream>>>(esrc, edst, ecin, cursor, dinvb, edata);
        gemm3m_kernel<<<n / 64, 256, 0, stream>>>(x, wsall + (size_t)layer * 3 * 32768,
                                                  ba, bb, bc, hA);
        prop_t<0><<<n / 8, 256, 0, stream>>>(hA, hB, rowptr, edata, dinvb,
                                             nullptr, nullptr, nullptr);
        prop_t<1><<<n / 8, 256, 0, stream>>>(hB, hA, rowptr, edata, dinvb,
                                             p, pn, score);
        pool_kernel<<<BGR, 256, 0, stream>>>(score, npg, k, perm, gate, remap);
        newx_kernel<<<(BGR * k) / 4, 256, 0, stream>>>(hA, perm, gate, hB);
        readout_kernel<<<BGR, 512, 0, stream>>>(hB, rsum, k, layer == 0 ? 1 : 0);
        if (ecout)
            compact_kernel<<<EMAX / 1024, 1024, 0, stream>>>(esrc, edst, ecin, remap, so, ddst,
                                                             ecout, deg);
    };

    run_layer(64000, 1000, 800, x0, 0, true, src0, dst0, ecnt + 0,
              (const float*)d_in[4], (const float*)d_in[6], (const float*)d_in[8],
              (const float*)d_in[27], pnorm + 0, srcA, dstA, ecnt + 1);

    run_layer(51200, 800, 640, hB, 1, false, srcA, dstA, ecnt + 1,
              (const float*)d_in[10], (const float*)d_in[12], (const float*)d_in[14],
              (const float*)d_in[28], pnorm + 1, srcB, dstB, ecnt + 2);

    run_layer(40960, 640, 512, hB, 2, false, srcB, dstB, ecnt + 2,
              (const float*)d_in[16], (const float*)d_in[18], (const float*)d_in[20],
              (const float*)d_in[29], pnorm + 2, nullptr, nullptr, nullptr);

    mlp_kernel<<<64, 128, 0, stream>>>(rsum, (const float*)d_in[21], (const float*)d_in[22],
                                       (const float*)d_in[23], (const float*)d_in[24],
                                       (const float*)d_in[25], (const float*)d_in[26],
                                       (float*)d_out);
}

// Round 12
// 522.083 us; speedup vs baseline: 3.1390x; 1.1743x over previous
//
#include <hip/hip_runtime.h>
#include <hip/hip_bf16.h>
#include <math.h>

#define BGR 64
#define ECAP 16000
#define EMAX 1024000

typedef _Float16 f16x8 __attribute__((ext_vector_type(8)));
typedef float f32x4 __attribute__((ext_vector_type(4)));

// ---------------- pnorm x3 ----------------
__global__ __launch_bounds__(128) void pnorm3_kernel(const float* __restrict__ p1,
                              const float* __restrict__ p2,
                              const float* __restrict__ p3, float* __restrict__ out) {
    __shared__ float buf[128];
    int t = threadIdx.x, b = blockIdx.x;
    const float* p = (b == 0) ? p1 : (b == 1) ? p2 : p3;
    buf[t] = p[t] * p[t];
    __syncthreads();
    for (int off = 64; off; off >>= 1) {
        if (t < off) buf[t] += buf[t + off];
        __syncthreads();
    }
    if (t == 0) out[b] = sqrtf(buf[0]);
}

// ---------------- weight split: f32 [k][n] -> f16 hi/lo chunk-major ----------------
struct WP { const float* w[9]; };

__global__ void wsplit_kernel(WP wp, _Float16* __restrict__ out) {
    int mat = blockIdx.x;
    const float* __restrict__ w = wp.w[mat];
    _Float16* __restrict__ dst = out + (size_t)mat * 32768;
    for (int e = threadIdx.x; e < 2048; e += 256) {
        int n = e >> 4;
        int kb = (e & 15) * 8;
        f16x8 hi, lo;
#pragma unroll
        for (int j = 0; j < 8; j++) {
            float v = w[(kb + j) * 128 + n];
            _Float16 h = (_Float16)v;
            hi[j] = h;
            lo[j] = (_Float16)((v - (float)h) * 2048.0f);
        }
        int ks = kb >> 5, kg = (kb >> 3) & 3;
        *(f16x8*)(dst + ((((ks * 2 + 0) * 4 + kg) * 128 + n) * 8)) = hi;
        *(f16x8*)(dst + ((((ks * 2 + 1) * 4 + kg) * 128 + n) * 8)) = lo;
    }
}

// ---------------- per-graph CSR build: count + LDS scan + LDS-cursor scatter ----------
// One block per graph. Edges live in per-graph segments of stride ECAP.
__global__ __launch_bounds__(1024) void build_kernel(
    const int* __restrict__ src, const int* __restrict__ dst,
    const int* __restrict__ gcnt, int fixedcnt, int npg,
    int2* __restrict__ rowdeg, float* __restrict__ dinv, int2* __restrict__ edata) {
    __shared__ int cnt[1024];
    __shared__ int scn[1024];
    __shared__ float sdinv[1024];
    int g = blockIdx.x, t = threadIdx.x;
    int E = gcnt ? gcnt[g] : fixedcnt;
    int ebase = g * ECAP;
    int gnb = g * npg;
    cnt[t] = 0;
    __syncthreads();
    for (int i = t; i < E; i += 1024)
        atomicAdd(&cnt[dst[ebase + i] - gnb], 1);
    __syncthreads();
    int myc = (t < npg) ? cnt[t] : 0;
    scn[t] = myc;
    __syncthreads();
    for (int off = 1; off < 1024; off <<= 1) {
        int v = (t >= off) ? scn[t - off] : 0;
        __syncthreads();
        scn[t] += v;
        __syncthreads();
    }
    int excl = scn[t] - myc;
    if (t < npg) {
        float dv = rsqrtf((float)myc + 1.0f);
        rowdeg[gnb + t] = make_int2(ebase + excl, myc);
        dinv[gnb + t] = dv;
        sdinv[t] = dv;
        scn[t] = excl;                    // becomes LDS cursor
    }
    __syncthreads();
    for (int i = t; i < E; i += 1024) {
        int s = src[ebase + i];
        int d = dst[ebase + i];
        int sl = s - gnb, dl = d - gnb;
        int pos = atomicAdd(&scn[dl], 1);
        edata[ebase + pos] = make_int2(s, __float_as_int(sdinv[sl] * sdinv[dl]));
    }
}

// ---------------- fused 3-branch MFMA GEMM (f16 split, f32-equivalent accuracy) ----------
__global__ __launch_bounds__(256) void gemm3m_kernel(
    const float* __restrict__ x, const _Float16* __restrict__ wsp,
    const float* __restrict__ b0, const float* __restrict__ b1, const float* __restrict__ b2,
    float* __restrict__ out) {
    __shared__ _Float16 ws[2][16384] __attribute__((aligned(16)));
    const int tid = threadIdx.x;
    const int wave = tid >> 6;
    const int lane = tid & 63;
    const int l15 = lane & 15;
    const int kg = lane >> 4;          // 0..3
    const long base = (long)blockIdx.x * 64;
    const int m = wave * 16 + l15;     // row within block tile

    float4 xrow[8];
    const float4* xg = (const float4*)(x + (base + m) * 128);
#pragma unroll
    for (int q = 0; q < 8; q++) xrow[q] = xg[(q >> 1) * 8 + kg * 2 + (q & 1)];

    auto stageH = [&](int s, int buf) {
#pragma unroll
        for (int t = 0; t < 8; t++) {
            int u = tid + t * 256;
            __builtin_amdgcn_global_load_lds(
                (const __attribute__((address_space(1))) unsigned int*)(wsp + (size_t)s * 16384 + u * 8),
                (__attribute__((address_space(3))) unsigned int*)(&ws[buf][u * 8]),
                16, 0, 0);
        }
    };

    float tot[8][4];
#pragma unroll
    for (int nt = 0; nt < 8; nt++)
#pragma unroll
        for (int r = 0; r < 4; r++) tot[nt][r] = 0.f;

    f32x4 acc_h[8], acc_m[8];
    stageH(0, 0);

    for (int s = 0; s < 6; s++) {
        const int j = s >> 1;
        __syncthreads();
        if (s < 5) stageH(s + 1, (s & 1) ^ 1);

        if ((s & 1) == 0) {
#pragma unroll
            for (int nt = 0; nt < 8; nt++) {
                acc_h[nt] = (f32x4){0.f, 0.f, 0.f, 0.f};
                acc_m[nt] = (f32x4){0.f, 0.f, 0.f, 0.f};
            }
        }

        const _Float16* wbase = &ws[s & 1][0];
#pragma unroll
        for (int ksl = 0; ksl < 2; ksl++) {
            const int ks = (s & 1) * 2 + ksl;
            float ev[8] = {xrow[ks * 2].x, xrow[ks * 2].y, xrow[ks * 2].z, xrow[ks * 2].w,
                           xrow[ks * 2 + 1].x, xrow[ks * 2 + 1].y, xrow[ks * 2 + 1].z, xrow[ks * 2 + 1].w};
            f16x8 ah, al;
#pragma unroll
            for (int i = 0; i < 8; i++) {
                _Float16 h = (_Float16)ev[i];
                ah[i] = h;
                al[i] = (_Float16)((ev[i] - (float)h) * 2048.0f);
            }
            const _Float16* wb = wbase + ksl * 8192;
            const int nb = kg * 1024 + l15 * 8;
            f16x8 bh[8], bl[8];
#pragma unroll
            for (int nt = 0; nt < 8; nt++) {
                bh[nt] = *(const f16x8*)(wb + nb + nt * 128);
                bl[nt] = *(const f16x8*)(wb + 4096 + nb + nt * 128);
            }
#pragma unroll
            for (int nt = 0; nt < 8; nt++)
                acc_h[nt] = __builtin_amdgcn_mfma_f32_16x16x32_f16(ah, bh[nt], acc_h[nt], 0, 0, 0);
#pragma unroll
            for (int nt = 0; nt < 8; nt++)
                acc_m[nt] = __builtin_amdgcn_mfma_f32_16x16x32_f16(ah, bl[nt], acc_m[nt], 0, 0, 0);
#pragma unroll
            for (int nt = 0; nt < 8; nt++)
                acc_m[nt] = __builtin_amdgcn_mfma_f32_16x16x32_f16(al, bh[nt], acc_m[nt], 0, 0, 0);
        }

        if (s & 1) {
            const float* bb = (j == 0) ? b0 : (j == 1) ? b1 : b2;
#pragma unroll
            for (int nt = 0; nt < 8; nt++) {
                float bv = bb[nt * 16 + l15];
#pragma unroll
                for (int r = 0; r < 4; r++)
                    tot[nt][r] += fmaxf(acc_h[nt][r] + acc_m[nt][r] * (1.0f / 2048.0f) + bv, 0.f);
            }
        }
    }

    float* op = out + (base + wave * 16 + kg * 4) * 128 + l15;
#pragma unroll
    for (int nt = 0; nt < 8; nt++)
#pragma unroll
        for (int r = 0; r < 4; r++) op[r * 128 + nt * 16] = tot[nt][r];
}

// ---------------- propagation (+optional fused score) ----------------
// 2 nodes per wave, half-wave each (float4/lane). rowdeg = {start, deg} (segmented CSR).
// Padding lanes gated to ci=0,w=0 so uninitialized segment slack can't form wild addresses.
template <int SC>
__global__ __launch_bounds__(256, 4) void prop_t(
    const float* __restrict__ hin, float* __restrict__ hout,
    const int2* __restrict__ rowdeg, const int2* __restrict__ edata,
    const float* __restrict__ dinv,
    const float* __restrict__ p, const float* __restrict__ pn, float* __restrict__ score) {
    int per = gridDim.x >> 3;
    int b = blockIdx.x;
    int sb = (b & 7) * per + (b >> 3);          // XCD swizzle
    int wave = threadIdx.x >> 6;
    int lane = threadIdx.x & 63;
    int half = lane >> 5;
    int l31 = lane & 31;
    int node = sb * 8 + wave * 2 + half;

    const char* hb = (const char*)hin;
    const unsigned loff = (unsigned)l31 * 16u;

    float4 hv = *(const float4*)(hb + (size_t)node * 512 + loff);
    float di = dinv[node];
    float selfc = 1.0f + di * di;
    float ax = hv.x * selfc, ay = hv.y * selfc, az = hv.z * selfc, aw = hv.w * selfc;

    int2 rd = rowdeg[node];
    int e0 = rd.x;
    int dg = rd.y;
    int e1 = e0 + dg;
    int degA = __builtin_amdgcn_readlane(dg, 0);
    int degB = __builtin_amdgcn_readlane(dg, 32);
    int dmax = degA > degB ? degA : degB;
    int T = (dmax + 15) >> 4;

    for (int t = 0; t < T; ++t) {
        int ee = e0 + t * 16 + (lane & 15);
        int ec = ee < e1 - 1 ? ee : e1 - 1;
        ec = ec < e0 ? e0 : ec;
        int2 md = edata[ec];
        bool val = ee < e1;
        int ci = val ? md.x : 0;
        int wi = val ? md.y : 0;
        float4 g[16];
        float w[16];
#pragma unroll
        for (int j = 0; j < 16; ++j) {
            int iA = __builtin_amdgcn_readlane(ci, j);
            int iB = __builtin_amdgcn_readlane(ci, j + 32);
            float wA = __int_as_float(__builtin_amdgcn_readlane(wi, j));
            float wB = __int_as_float(__builtin_amdgcn_readlane(wi, j + 32));
            int idx = half ? iB : iA;
            w[j] = half ? wB : wA;
            g[j] = *(const float4*)(hb + (unsigned)idx * 512u + loff);
        }
        __builtin_amdgcn_sched_barrier(0);
#pragma unroll
        for (int j = 0; j < 16; ++j) {
            ax += w[j] * g[j].x;
            ay += w[j] * g[j].y;
            az += w[j] * g[j].z;
            aw += w[j] * g[j].w;
        }
    }

    *(float4*)((char*)hout + (size_t)node * 512 + loff) = make_float4(ax, ay, az, aw);

    if (SC) {
        float4 pv = ((const float4*)p)[l31];
        float v = ax * pv.x + ay * pv.y + az * pv.z + aw * pv.w;
        v += __shfl_xor(v, 16);
        v += __shfl_xor(v, 8);
        v += __shfl_xor(v, 4);
        v += __shfl_xor(v, 2);
        v += __shfl_xor(v, 1);
        if (l31 == 0) score[node] = v / pn[0];
    }
}

// ---------------- top-k pool: bitonic sort 1024 per graph ----------------
__global__ __launch_bounds__(256) void pool_kernel(const float* __restrict__ score, int npg, int k,
                            int* __restrict__ perm, float* __restrict__ gate,
                            int* __restrict__ remap) {
    __shared__ float sval[1024];
    __shared__ int sidx[1024];
    int b = blockIdx.x, t = threadIdx.x;
    for (int i = t; i < 1024; i += 256) {
        sval[i] = (i < npg) ? score[b * npg + i] : -INFINITY;
        sidx[i] = i;
    }
    __syncthreads();
    for (int ksz = 2; ksz <= 1024; ksz <<= 1) {
        for (int j = ksz >> 1; j > 0; j >>= 1) {
            for (int i = t; i < 1024; i += 256) {
                int l = i ^ j;
                if (l > i) {
                    float vi = sval[i], vl = sval[l];
                    bool up = ((i & ksz) == 0);
                    bool sw = up ? (vi < vl) : (vi > vl);   // descending sort
                    if (sw) {
                        sval[i] = vl; sval[l] = vi;
                        int tmp = sidx[i]; sidx[i] = sidx[l]; sidx[l] = tmp;
                    }
                }
            }
            __syncthreads();
        }
    }
    for (int i = t; i < k; i += 256) {
        int oldg = b * npg + sidx[i];
        int newg = b * k + i;
        perm[newg] = oldg;
        gate[newg] = tanhf(sval[i]);
        remap[oldg] = newg;
    }
    for (int i = k + t; i < npg; i += 256)
        remap[b * npg + sidx[i]] = -1;
}

// ---------------- gather new_x = h[perm] * gate ----------------
__global__ void newx_kernel(const float* __restrict__ h, const int* __restrict__ perm,
                            const float* __restrict__ gate, float* __restrict__ xo) {
    int m = blockIdx.x * 4 + (threadIdx.x >> 6);
    int lane = threadIdx.x & 63;
    int old = perm[m];
    float g = gate[m];
    float2 v = ((const float2*)h)[old * 64 + lane];
    ((float2*)xo)[m * 64 + lane] = make_float2(v.x * g, v.y * g);
}

// ---------------- readout: rsum[b] (=|+=) [max over k ; mean over k] ----------------
__global__ __launch_bounds__(512) void readout_kernel(const float* __restrict__ x,
                                                      float* __restrict__ rsum, int k,
                                                      int first) {
    __shared__ float smx[4][128], ssm[4][128];
    int b = blockIdx.x, t = threadIdx.x;
    int f = t & 127, c = t >> 7;
    int rows = k >> 2;
    const float* base = x + (size_t)b * k * 128 + (size_t)c * rows * 128 + f;
    float mx = -INFINITY, sm = 0.f;
#pragma unroll 8
    for (int j = 0; j < rows; j++) {
        float v = base[(size_t)j * 128];
        mx = fmaxf(mx, v);
        sm += v;
    }
    smx[c][f] = mx;
    ssm[c][f] = sm;
    __syncthreads();
    if (c == 0) {
        float m2 = fmaxf(fmaxf(smx[0][f], smx[1][f]), fmaxf(smx[2][f], smx[3][f]));
        float s2 = (ssm[0][f] + ssm[1][f] + ssm[2][f] + ssm[3][f]) / (float)k;
        if (first) {
            rsum[b * 256 + f] = m2;
            rsum[b * 256 + 128 + f] = s2;
        } else {
            rsum[b * 256 + f] += m2;
            rsum[b * 256 + 128 + f] += s2;
        }
    }
}

// ---------------- per-graph edge compact (keeps per-graph segments) ----------------
__global__ __launch_bounds__(1024) void compact_kernel(
    const int* __restrict__ src, const int* __restrict__ dst,
    const int* __restrict__ gcntIn, int fixedIn, const int* __restrict__ remap,
    int* __restrict__ so, int* __restrict__ dd, int* __restrict__ gcntOut) {
    __shared__ int wsum[16];
    __shared__ int runbase;
    int g = blockIdx.x, t = threadIdx.x;
    int wave = t >> 6, lane = t & 63;
    int E = gcntIn ? gcntIn[g] : fixedIn;
    int ebase = g * ECAP;
    if (t == 0) runbase = 0;
    __syncthreads();
    for (int i0 = 0; i0 < E; i0 += 1024) {
        int i = i0 + t;
        bool v = false;
        int s = 0, d = 0;
        if (i < E) {
            s = remap[src[ebase + i]];
            d = remap[dst[ebase + i]];
            v = ((s | d) >= 0);
        }
        unsigned long long m = __ballot(v);
        int before = __popcll(m & ((1ULL << lane) - 1ULL));
        if (lane == 0) wsum[wave] = __popcll(m);
        __syncthreads();
        if (t == 0) {
            int tot = 0;
#pragma unroll
            for (int w2 = 0; w2 < 16; w2++) { int c = wsum[w2]; wsum[w2] = runbase + tot; tot += c; }
            runbase += tot;
        }
        __syncthreads();
        if (v) {
            int pos = ebase + wsum[wave] + before;
            so[pos] = s;
            dd[pos] = d;
        }
        __syncthreads();
    }
    if (t == 0) gcntOut[g] = runbase;
}

// ---------------- fused final MLP + log_softmax ----------------
__global__ void mlp_kernel(const float* __restrict__ rsum,
                           const float* __restrict__ w1, const float* __restrict__ b1,
                           const float* __restrict__ w2, const float* __restrict__ b2,
                           const float* __restrict__ w3, const float* __restrict__ b3,
                           float* __restrict__ out) {
    __shared__ float z0[256], z1l[128], z2l[64], lg[10], ls;
    int b = blockIdx.x, t = threadIdx.x;   // 128 threads
    z0[t] = rsum[b * 256 + t];
    z0[t + 128] = rsum[b * 256 + 128 + t];
    __syncthreads();
    float acc = b1[t];
    for (int k = 0; k < 256; k++) acc += z0[k] * w1[k * 128 + t];
    z1l[t] = fmaxf(acc, 0.f);
    __syncthreads();
    if (t < 64) {
        acc = b2[t];
        for (int k = 0; k < 128; k++) acc += z1l[k] * w2[k * 64 + t];
        z2l[t] = fmaxf(acc, 0.f);
    }
    __syncthreads();
    if (t < 10) {
        acc = b3[t];
        for (int k = 0; k < 64; k++) acc += z2l[k] * w3[k * 10 + t];
        lg[t] = acc;
    }
    __syncthreads();
    if (t == 0) {
        float mx = lg[0];
        for (int c = 1; c < 10; c++) mx = fmaxf(mx, lg[c]);
        float s = 0.f;
        for (int c = 0; c < 10; c++) s += expf(lg[c] - mx);
        ls = mx + logf(s);
    }
    __syncthreads();
    if (t < 10) out[b * 10 + t] = lg[t] - ls;
}

// =====================================================================
extern "C" void kernel_launch(void* const* d_in, const int* in_sizes, int n_in,
                              void* d_out, int out_size, void* d_ws, size_t ws_size,
                              hipStream_t stream) {
    char* ws = (char*)d_ws;
    size_t off = 0;
    auto alloc = [&](size_t bytes) -> void* {
        void* p = ws + off;
        off += (bytes + 255) & ~(size_t)255;
        return p;
    };
    float* hA = (float*)alloc(64000UL * 128 * 4);
    float* hB = (float*)alloc(64000UL * 128 * 4);
    float* score = (float*)alloc(64000UL * 4);
    float* dinvb = (float*)alloc(64000UL * 4);
    int2* rowdeg = (int2*)alloc(64000UL * 8);
    int2* edata = (int2*)alloc((size_t)EMAX * 8);
    int* srcA = (int*)alloc((size_t)EMAX * 4);
    int* dstA = (int*)alloc((size_t)EMAX * 4);
    int* srcB = (int*)alloc((size_t)EMAX * 4);
    int* dstB = (int*)alloc((size_t)EMAX * 4);
    int* perm = (int*)alloc(51200UL * 4);
    float* gate = (float*)alloc(51200UL * 4);
    int* remap = (int*)alloc(64000UL * 4);
    float* rsum = (float*)alloc(64UL * 256 * 4);
    _Float16* wsall = (_Float16*)alloc(9UL * 32768 * 2);
    float* pnorm = (float*)alloc(256);
    int* gA = (int*)alloc(256);
    int* gB = (int*)alloc(256);
    (void)ws_size;  // requires ~94 MB

    const float* x0 = (const float*)d_in[0];
    const int* src0 = (const int*)d_in[1];
    const int* dst0 = (const int*)d_in[2];

    pnorm3_kernel<<<3, 128, 0, stream>>>((const float*)d_in[27], (const float*)d_in[28],
                                         (const float*)d_in[29], pnorm);

    WP wp;
    wp.w[0] = (const float*)d_in[3];  wp.w[1] = (const float*)d_in[5];  wp.w[2] = (const float*)d_in[7];
    wp.w[3] = (const float*)d_in[9];  wp.w[4] = (const float*)d_in[11]; wp.w[5] = (const float*)d_in[13];
    wp.w[6] = (const float*)d_in[15]; wp.w[7] = (const float*)d_in[17]; wp.w[8] = (const float*)d_in[19];
    wsplit_kernel<<<9, 256, 0, stream>>>(wp, wsall);

    auto run_layer = [&](int n, int npg, int k, const float* x, int layer,
                         const int* esrc, const int* edst, const int* gcnt,
                         const float* ba, const float* bb, const float* bc,
                         const float* p, const float* pn,
                         int* so, int* ddst, int* gout) {
        build_kernel<<<BGR, 1024, 0, stream>>>(esrc, edst, gcnt, ECAP, npg,
                                               rowdeg, dinvb, edata);
        gemm3m_kernel<<<n / 64, 256, 0, stream>>>(x, wsall + (size_t)layer * 3 * 32768,
                                                  ba, bb, bc, hA);
        prop_t<0><<<n / 8, 256, 0, stream>>>(hA, hB, rowdeg, edata, dinvb,
                                             nullptr, nullptr, nullptr);
        prop_t<1><<<n / 8, 256, 0, stream>>>(hB, hA, rowdeg, edata, dinvb,
                                             p, pn, score);
        pool_kernel<<<BGR, 256, 0, stream>>>(score, npg, k, perm, gate, remap);
        newx_kernel<<<(BGR * k) / 4, 256, 0, stream>>>(hA, perm, gate, hB);
        readout_kernel<<<BGR, 512, 0, stream>>>(hB, rsum, k, layer == 0 ? 1 : 0);
        if (gout)
            compact_kernel<<<BGR, 1024, 0, stream>>>(esrc, edst, gcnt, ECAP, remap,
                                                     so, ddst, gout);
    };

    run_layer(64000, 1000, 800, x0, 0, src0, dst0, nullptr,
              (const float*)d_in[4], (const float*)d_in[6], (const float*)d_in[8],
              (const float*)d_in[27], pnorm + 0, srcA, dstA, gA);

    run_layer(51200, 800, 640, hB, 1, srcA, dstA, gA,
              (const float*)d_in[10], (const float*)d_in[12], (const float*)d_in[14],
              (const float*)d_in[28], pnorm + 1, srcB, dstB, gB);

    run_layer(40960, 640, 512, hB, 2, srcB, dstB, gB,
              (const float*)d_in[16], (const float*)d_in[18], (const float*)d_in[20],
              (const float*)d_in[29], pnorm + 2, nullptr, nullptr, nullptr);

    mlp_kernel<<<64, 128, 0, stream>>>(rsum, (const float*)d_in[21], (const float*)d_in[22],
                                       (const float*)d_in[23], (const float*)d_in[24],
                                       (const float*)d_in[25], (const float*)d_in[26],
                                       (float*)d_out);
}

// Round 13
// 448.388 us; speedup vs baseline: 3.6550x; 1.1644x over previous
//
#include <hip/hip_runtime.h>
#include <hip/hip_bf16.h>
#include <math.h>

#define BGR 64
#define ECAP 16000
#define EMAX 1024000

typedef _Float16 f16x8 __attribute__((ext_vector_type(8)));
typedef float f32x4 __attribute__((ext_vector_type(4)));

// ---------------- pnorm x3 ----------------
__global__ __launch_bounds__(128) void pnorm3_kernel(const float* __restrict__ p1,
                              const float* __restrict__ p2,
                              const float* __restrict__ p3, float* __restrict__ out) {
    __shared__ float buf[128];
    int t = threadIdx.x, b = blockIdx.x;
    const float* p = (b == 0) ? p1 : (b == 1) ? p2 : p3;
    buf[t] = p[t] * p[t];
    __syncthreads();
    for (int off = 64; off; off >>= 1) {
        if (t < off) buf[t] += buf[t + off];
        __syncthreads();
    }
    if (t == 0) out[b] = sqrtf(buf[0]);
}

// ---------------- weight split: f32 [k][n] -> f16 hi/lo chunk-major ----------------
struct WP { const float* w[9]; };

__global__ void wsplit_kernel(WP wp, _Float16* __restrict__ out) {
    int mat = blockIdx.x;
    const float* __restrict__ w = wp.w[mat];
    _Float16* __restrict__ dst = out + (size_t)mat * 32768;
    for (int e = threadIdx.x; e < 2048; e += 256) {
        int n = e >> 4;
        int kb = (e & 15) * 8;
        f16x8 hi, lo;
#pragma unroll
        for (int j = 0; j < 8; j++) {
            float v = w[(kb + j) * 128 + n];
            _Float16 h = (_Float16)v;
            hi[j] = h;
            lo[j] = (_Float16)((v - (float)h) * 2048.0f);
        }
        int ks = kb >> 5, kg = (kb >> 3) & 3;
        *(f16x8*)(dst + ((((ks * 2 + 0) * 4 + kg) * 128 + n) * 8)) = hi;
        *(f16x8*)(dst + ((((ks * 2 + 1) * 4 + kg) * 128 + n) * 8)) = lo;
    }
}

// ---------------- per-graph CSR build: count + LDS scan + LDS-cursor scatter ----------
__global__ __launch_bounds__(1024) void build_kernel(
    const int* __restrict__ src, const int* __restrict__ dst,
    const int* __restrict__ gcnt, int fixedcnt, int npg,
    int2* __restrict__ rowdeg, float* __restrict__ dinv, int2* __restrict__ edata) {
    __shared__ int cnt[1024];
    __shared__ int scn[1024];
    __shared__ float sdinv[1024];
    int g = blockIdx.x, t = threadIdx.x;
    int E = gcnt ? gcnt[g] : fixedcnt;
    int ebase = g * ECAP;
    int gnb = g * npg;
    cnt[t] = 0;
    __syncthreads();
    for (int i = t; i < E; i += 1024)
        atomicAdd(&cnt[dst[ebase + i] - gnb], 1);
    __syncthreads();
    int myc = (t < npg) ? cnt[t] : 0;
    scn[t] = myc;
    __syncthreads();
    for (int off = 1; off < 1024; off <<= 1) {
        int v = (t >= off) ? scn[t - off] : 0;
        __syncthreads();
        scn[t] += v;
        __syncthreads();
    }
    int excl = scn[t] - myc;
    if (t < npg) {
        float dv = rsqrtf((float)myc + 1.0f);
        rowdeg[gnb + t] = make_int2(ebase + excl, myc);
        dinv[gnb + t] = dv;
        sdinv[t] = dv;
        scn[t] = excl;                    // becomes LDS cursor
    }
    __syncthreads();
    for (int i = t; i < E; i += 1024) {
        int s = src[ebase + i];
        int d = dst[ebase + i];
        int sl = s - gnb, dl = d - gnb;
        int pos = atomicAdd(&scn[dl], 1);
        edata[ebase + pos] = make_int2(s, __float_as_int(sdinv[sl] * sdinv[dl]));
    }
}

// ---------------- fused 3-branch MFMA GEMM (f16 split, f32-equivalent accuracy) ----------
__global__ __launch_bounds__(256) void gemm3m_kernel(
    const float* __restrict__ x, const _Float16* __restrict__ wsp,
    const float* __restrict__ b0, const float* __restrict__ b1, const float* __restrict__ b2,
    float* __restrict__ out) {
    __shared__ _Float16 ws[2][16384] __attribute__((aligned(16)));
    const int tid = threadIdx.x;
    const int wave = tid >> 6;
    const int lane = tid & 63;
    const int l15 = lane & 15;
    const int kg = lane >> 4;          // 0..3
    const long base = (long)blockIdx.x * 64;
    const int m = wave * 16 + l15;     // row within block tile

    float4 xrow[8];
    const float4* xg = (const float4*)(x + (base + m) * 128);
#pragma unroll
    for (int q = 0; q < 8; q++) xrow[q] = xg[(q >> 1) * 8 + kg * 2 + (q & 1)];

    auto stageH = [&](int s, int buf) {
#pragma unroll
        for (int t = 0; t < 8; t++) {
            int u = tid + t * 256;
            __builtin_amdgcn_global_load_lds(
                (const __attribute__((address_space(1))) unsigned int*)(wsp + (size_t)s * 16384 + u * 8),
                (__attribute__((address_space(3))) unsigned int*)(&ws[buf][u * 8]),
                16, 0, 0);
        }
    };

    float tot[8][4];
#pragma unroll
    for (int nt = 0; nt < 8; nt++)
#pragma unroll
        for (int r = 0; r < 4; r++) tot[nt][r] = 0.f;

    f32x4 acc_h[8], acc_m[8];
    stageH(0, 0);

    for (int s = 0; s < 6; s++) {
        const int j = s >> 1;
        __syncthreads();
        if (s < 5) stageH(s + 1, (s & 1) ^ 1);

        if ((s & 1) == 0) {
#pragma unroll
            for (int nt = 0; nt < 8; nt++) {
                acc_h[nt] = (f32x4){0.f, 0.f, 0.f, 0.f};
                acc_m[nt] = (f32x4){0.f, 0.f, 0.f, 0.f};
            }
        }

        const _Float16* wbase = &ws[s & 1][0];
#pragma unroll
        for (int ksl = 0; ksl < 2; ksl++) {
            const int ks = (s & 1) * 2 + ksl;
            float ev[8] = {xrow[ks * 2].x, xrow[ks * 2].y, xrow[ks * 2].z, xrow[ks * 2].w,
                           xrow[ks * 2 + 1].x, xrow[ks * 2 + 1].y, xrow[ks * 2 + 1].z, xrow[ks * 2 + 1].w};
            f16x8 ah, al;
#pragma unroll
            for (int i = 0; i < 8; i++) {
                _Float16 h = (_Float16)ev[i];
                ah[i] = h;
                al[i] = (_Float16)((ev[i] - (float)h) * 2048.0f);
            }
            const _Float16* wb = wbase + ksl * 8192;
            const int nb = kg * 1024 + l15 * 8;
            f16x8 bh[8], bl[8];
#pragma unroll
            for (int nt = 0; nt < 8; nt++) {
                bh[nt] = *(const f16x8*)(wb + nb + nt * 128);
                bl[nt] = *(const f16x8*)(wb + 4096 + nb + nt * 128);
            }
#pragma unroll
            for (int nt = 0; nt < 8; nt++)
                acc_h[nt] = __builtin_amdgcn_mfma_f32_16x16x32_f16(ah, bh[nt], acc_h[nt], 0, 0, 0);
#pragma unroll
            for (int nt = 0; nt < 8; nt++)
                acc_m[nt] = __builtin_amdgcn_mfma_f32_16x16x32_f16(ah, bl[nt], acc_m[nt], 0, 0, 0);
#pragma unroll
            for (int nt = 0; nt < 8; nt++)
                acc_m[nt] = __builtin_amdgcn_mfma_f32_16x16x32_f16(al, bh[nt], acc_m[nt], 0, 0, 0);
        }

        if (s & 1) {
            const float* bb = (j == 0) ? b0 : (j == 1) ? b1 : b2;
#pragma unroll
            for (int nt = 0; nt < 8; nt++) {
                float bv = bb[nt * 16 + l15];
#pragma unroll
                for (int r = 0; r < 4; r++)
                    tot[nt][r] += fmaxf(acc_h[nt][r] + acc_m[nt][r] * (1.0f / 2048.0f) + bv, 0.f);
            }
        }
    }

    float* op = out + (base + wave * 16 + kg * 4) * 128 + l15;
#pragma unroll
    for (int nt = 0; nt < 8; nt++)
#pragma unroll
        for (int r = 0; r < 4; r++) op[r * 128 + nt * 16] = tot[nt][r];
}

// ---------------- propagation (+optional fused score) ----------------
template <int SC>
__global__ __launch_bounds__(256, 4) void prop_t(
    const float* __restrict__ hin, float* __restrict__ hout,
    const int2* __restrict__ rowdeg, const int2* __restrict__ edata,
    const float* __restrict__ dinv,
    const float* __restrict__ p, const float* __restrict__ pn, float* __restrict__ score) {
    int per = gridDim.x >> 3;
    int b = blockIdx.x;
    int sb = (b & 7) * per + (b >> 3);          // XCD swizzle
    int wave = threadIdx.x >> 6;
    int lane = threadIdx.x & 63;
    int half = lane >> 5;
    int l31 = lane & 31;
    int node = sb * 8 + wave * 2 + half;

    const char* hb = (const char*)hin;
    const unsigned loff = (unsigned)l31 * 16u;

    float4 hv = *(const float4*)(hb + (size_t)node * 512 + loff);
    float di = dinv[node];
    float selfc = 1.0f + di * di;
    float ax = hv.x * selfc, ay = hv.y * selfc, az = hv.z * selfc, aw = hv.w * selfc;

    int2 rd = rowdeg[node];
    int e0 = rd.x;
    int dg = rd.y;
    int e1 = e0 + dg;
    int degA = __builtin_amdgcn_readlane(dg, 0);
    int degB = __builtin_amdgcn_readlane(dg, 32);
    int dmax = degA > degB ? degA : degB;
    int T = (dmax + 15) >> 4;

    for (int t = 0; t < T; ++t) {
        int ee = e0 + t * 16 + (lane & 15);
        int ec = ee < e1 - 1 ? ee : e1 - 1;
        ec = ec < e0 ? e0 : ec;
        int2 md = edata[ec];
        bool val = ee < e1;
        int ci = val ? md.x : 0;
        int wi = val ? md.y : 0;
        float4 g[16];
        float w[16];
#pragma unroll
        for (int j = 0; j < 16; ++j) {
            int iA = __builtin_amdgcn_readlane(ci, j);
            int iB = __builtin_amdgcn_readlane(ci, j + 32);
            float wA = __int_as_float(__builtin_amdgcn_readlane(wi, j));
            float wB = __int_as_float(__builtin_amdgcn_readlane(wi, j + 32));
            int idx = half ? iB : iA;
            w[j] = half ? wB : wA;
            g[j] = *(const float4*)(hb + (unsigned)idx * 512u + loff);
        }
        __builtin_amdgcn_sched_barrier(0);
#pragma unroll
        for (int j = 0; j < 16; ++j) {
            ax += w[j] * g[j].x;
            ay += w[j] * g[j].y;
            az += w[j] * g[j].z;
            aw += w[j] * g[j].w;
        }
    }

    *(float4*)((char*)hout + (size_t)node * 512 + loff) = make_float4(ax, ay, az, aw);

    if (SC) {
        float4 pv = ((const float4*)p)[l31];
        float v = ax * pv.x + ay * pv.y + az * pv.z + aw * pv.w;
        v += __shfl_xor(v, 16);
        v += __shfl_xor(v, 8);
        v += __shfl_xor(v, 4);
        v += __shfl_xor(v, 2);
        v += __shfl_xor(v, 1);
        if (l31 == 0) score[node] = v / pn[0];
    }
}

// ---------------- top-k pool: 1024-thread key-packed bitonic sort ----------------
// key = (order-flipped score bits << 32) | idx  -> ascending u64 sort == descending
// score with ties to lower index (matches jax.lax.top_k). Pads (-INF) sort to tail.
__global__ __launch_bounds__(1024) void pool_kernel(const float* __restrict__ score, int npg, int k,
                            int* __restrict__ perm, float* __restrict__ gate,
                            int* __restrict__ remap) {
    __shared__ unsigned long long skey[1024];
    int b = blockIdx.x, t = threadIdx.x;
    float v = (t < npg) ? score[b * npg + t] : -INFINITY;
    unsigned ub = __float_as_uint(v);
    unsigned asc = ub ^ ((ub >> 31) ? 0xFFFFFFFFu : 0x80000000u);  // ascending uint map
    unsigned desc = ~asc;                                          // descending
    skey[t] = ((unsigned long long)desc << 32) | (unsigned)t;
    __syncthreads();
    for (int ksz = 2; ksz <= 1024; ksz <<= 1) {
        for (int j = ksz >> 1; j > 0; j >>= 1) {
            int l = t ^ j;
            if (l > t) {
                unsigned long long a = skey[t], c = skey[l];
                bool up = ((t & ksz) == 0);
                if (up ? (a > c) : (a < c)) { skey[t] = c; skey[l] = a; }
            }
            __syncthreads();
        }
    }
    if (t < k) {
        int idx = (int)(skey[t] & 0xFFFFFFFFu);
        int oldg = b * npg + idx;
        int newg = b * k + t;
        perm[newg] = oldg;
        gate[newg] = tanhf(score[oldg]);
        remap[oldg] = newg;
    } else if (t < npg) {
        int idx = (int)(skey[t] & 0xFFFFFFFFu);
        remap[b * npg + idx] = -1;
    }
}

// ---------------- gather new_x = h[perm] * gate ----------------
__global__ void newx_kernel(const float* __restrict__ h, const int* __restrict__ perm,
                            const float* __restrict__ gate, float* __restrict__ xo) {
    int m = blockIdx.x * 4 + (threadIdx.x >> 6);
    int lane = threadIdx.x & 63;
    int old = perm[m];
    float g = gate[m];
    float2 v = ((const float2*)h)[old * 64 + lane];
    ((float2*)xo)[m * 64 + lane] = make_float2(v.x * g, v.y * g);
}

// ---------------- readout: rsum[b] (=|+=) [max over k ; mean over k] ----------------
__global__ __launch_bounds__(512) void readout_kernel(const float* __restrict__ x,
                                                      float* __restrict__ rsum, int k,
                                                      int first) {
    __shared__ float smx[4][128], ssm[4][128];
    int b = blockIdx.x, t = threadIdx.x;
    int f = t & 127, c = t >> 7;
    int rows = k >> 2;
    const float* base = x + (size_t)b * k * 128 + (size_t)c * rows * 128 + f;
    float mx = -INFINITY, sm = 0.f;
#pragma unroll 8
    for (int j = 0; j < rows; j++) {
        float v = base[(size_t)j * 128];
        mx = fmaxf(mx, v);
        sm += v;
    }
    smx[c][f] = mx;
    ssm[c][f] = sm;
    __syncthreads();
    if (c == 0) {
        float m2 = fmaxf(fmaxf(smx[0][f], smx[1][f]), fmaxf(smx[2][f], smx[3][f]));
        float s2 = (ssm[0][f] + ssm[1][f] + ssm[2][f] + ssm[3][f]) / (float)k;
        if (first) {
            rsum[b * 256 + f] = m2;
            rsum[b * 256 + 128 + f] = s2;
        } else {
            rsum[b * 256 + f] += m2;
            rsum[b * 256 + 128 + f] += s2;
        }
    }
}

// ---------------- per-graph edge compact (keeps per-graph segments) ----------------
__global__ __launch_bounds__(1024) void compact_kernel(
    const int* __restrict__ src, const int* __restrict__ dst,
    const int* __restrict__ gcntIn, int fixedIn, const int* __restrict__ remap,
    int* __restrict__ so, int* __restrict__ dd, int* __restrict__ gcntOut) {
    __shared__ int wsum[16];
    __shared__ int runbase;
    int g = blockIdx.x, t = threadIdx.x;
    int wave = t >> 6, lane = t & 63;
    int E = gcntIn ? gcntIn[g] : fixedIn;
    int ebase = g * ECAP;
    if (t == 0) runbase = 0;
    __syncthreads();
    for (int i0 = 0; i0 < E; i0 += 1024) {
        int i = i0 + t;
        bool v = false;
        int s = 0, d = 0;
        if (i < E) {
            s = remap[src[ebase + i]];
            d = remap[dst[ebase + i]];
            v = ((s | d) >= 0);
        }
        unsigned long long m = __ballot(v);
        int before = __popcll(m & ((1ULL << lane) - 1ULL));
        if (lane == 0) wsum[wave] = __popcll(m);
        __syncthreads();
        if (t == 0) {
            int tot = 0;
#pragma unroll
            for (int w2 = 0; w2 < 16; w2++) { int c = wsum[w2]; wsum[w2] = runbase + tot; tot += c; }
            runbase += tot;
        }
        __syncthreads();
        if (v) {
            int pos = ebase + wsum[wave] + before;
            so[pos] = s;
            dd[pos] = d;
        }
        __syncthreads();
    }
    if (t == 0) gcntOut[g] = runbase;
}

// ---------------- fused final MLP + log_softmax ----------------
__global__ void mlp_kernel(const float* __restrict__ rsum,
                           const float* __restrict__ w1, const float* __restrict__ b1,
                           const float* __restrict__ w2, const float* __restrict__ b2,
                           const float* __restrict__ w3, const float* __restrict__ b3,
                           float* __restrict__ out) {
    __shared__ float z0[256], z1l[128], z2l[64], lg[10], ls;
    int b = blockIdx.x, t = threadIdx.x;   // 128 threads
    z0[t] = rsum[b * 256 + t];
    z0[t + 128] = rsum[b * 256 + 128 + t];
    __syncthreads();
    float acc = b1[t];
    for (int k = 0; k < 256; k++) acc += z0[k] * w1[k * 128 + t];
    z1l[t] = fmaxf(acc, 0.f);
    __syncthreads();
    if (t < 64) {
        acc = b2[t];
        for (int k = 0; k < 128; k++) acc += z1l[k] * w2[k * 64 + t];
        z2l[t] = fmaxf(acc, 0.f);
    }
    __syncthreads();
    if (t < 10) {
        acc = b3[t];
        for (int k = 0; k < 64; k++) acc += z2l[k] * w3[k * 10 + t];
        lg[t] = acc;
    }
    __syncthreads();
    if (t == 0) {
        float mx = lg[0];
        for (int c = 1; c < 10; c++) mx = fmaxf(mx, lg[c]);
        float s = 0.f;
        for (int c = 0; c < 10; c++) s += expf(lg[c] - mx);
        ls = mx + logf(s);
    }
    __syncthreads();
    if (t < 10) out[b * 10 + t] = lg[t] - ls;
}

// =====================================================================
extern "C" void kernel_launch(void* const* d_in, const int* in_sizes, int n_in,
                              void* d_out, int out_size, void* d_ws, size_t ws_size,
                              hipStream_t stream) {
    char* ws = (char*)d_ws;
    size_t off = 0;
    auto alloc = [&](size_t bytes) -> void* {
        void* p = ws + off;
        off += (bytes + 255) & ~(size_t)255;
        return p;
    };
    float* hA = (float*)alloc(64000UL * 128 * 4);
    float* hB = (float*)alloc(64000UL * 128 * 4);
    float* score = (float*)alloc(64000UL * 4);
    float* dinvb = (float*)alloc(64000UL * 4);
    int2* rowdeg = (int2*)alloc(64000UL * 8);
    int2* edata = (int2*)alloc((size_t)EMAX * 8);
    int* srcA = (int*)alloc((size_t)EMAX * 4);
    int* dstA = (int*)alloc((size_t)EMAX * 4);
    int* srcB = (int*)alloc((size_t)EMAX * 4);
    int* dstB = (int*)alloc((size_t)EMAX * 4);
    int* perm = (int*)alloc(51200UL * 4);
    float* gate = (float*)alloc(51200UL * 4);
    int* remap = (int*)alloc(64000UL * 4);
    float* rsum = (float*)alloc(64UL * 256 * 4);
    _Float16* wsall = (_Float16*)alloc(9UL * 32768 * 2);
    float* pnorm = (float*)alloc(256);
    int* gA = (int*)alloc(256);
    int* gB = (int*)alloc(256);
    (void)ws_size;  // requires ~94 MB

    const float* x0 = (const float*)d_in[0];
    const int* src0 = (const int*)d_in[1];
    const int* dst0 = (const int*)d_in[2];

    pnorm3_kernel<<<3, 128, 0, stream>>>((const float*)d_in[27], (const float*)d_in[28],
                                         (const float*)d_in[29], pnorm);

    WP wp;
    wp.w[0] = (const float*)d_in[3];  wp.w[1] = (const float*)d_in[5];  wp.w[2] = (const float*)d_in[7];
    wp.w[3] = (const float*)d_in[9];  wp.w[4] = (const float*)d_in[11]; wp.w[5] = (const float*)d_in[13];
    wp.w[6] = (const float*)d_in[15]; wp.w[7] = (const float*)d_in[17]; wp.w[8] = (const float*)d_in[19];
    wsplit_kernel<<<9, 256, 0, stream>>>(wp, wsall);

    auto run_layer = [&](int n, int npg, int k, const float* x, int layer,
                         const int* esrc, const int* edst, const int* gcnt,
                         const float* ba, const float* bb, const float* bc,
                         const float* p, const float* pn,
                         int* so, int* ddst, int* gout) {
        build_kernel<<<BGR, 1024, 0, stream>>>(esrc, edst, gcnt, ECAP, npg,
                                               rowdeg, dinvb, edata);
        gemm3m_kernel<<<n / 64, 256, 0, stream>>>(x, wsall + (size_t)layer * 3 * 32768,
                                                  ba, bb, bc, hA);
        prop_t<0><<<n / 8, 256, 0, stream>>>(hA, hB, rowdeg, edata, dinvb,
                                             nullptr, nullptr, nullptr);
        prop_t<1><<<n / 8, 256, 0, stream>>>(hB, hA, rowdeg, edata, dinvb,
                                             p, pn, score);
        pool_kernel<<<BGR, 1024, 0, stream>>>(score, npg, k, perm, gate, remap);
        newx_kernel<<<(BGR * k) / 4, 256, 0, stream>>>(hA, perm, gate, hB);
        readout_kernel<<<BGR, 512, 0, stream>>>(hB, rsum, k, layer == 0 ? 1 : 0);
        if (gout)
            compact_kernel<<<BGR, 1024, 0, stream>>>(esrc, edst, gcnt, ECAP, remap,
                                                     so, ddst, gout);
    };

    run_layer(64000, 1000, 800, x0, 0, src0, dst0, nullptr,
              (const float*)d_in[4], (const float*)d_in[6], (const float*)d_in[8],
              (const float*)d_in[27], pnorm + 0, srcA, dstA, gA);

    run_layer(51200, 800, 640, hB, 1, srcA, dstA, gA,
              (const float*)d_in[10], (const float*)d_in[12], (const float*)d_in[14],
              (const float*)d_in[28], pnorm + 1, srcB, dstB, gB);

    run_layer(40960, 640, 512, hB, 2, srcB, dstB, gB,
              (const float*)d_in[16], (const float*)d_in[18], (const float*)d_in[20],
              (const float*)d_in[29], pnorm + 2, nullptr, nullptr, nullptr);

    mlp_kernel<<<64, 128, 0, stream>>>(rsum, (const float*)d_in[21], (const float*)d_in[22],
                                       (const float*)d_in[23], (const float*)d_in[24],
                                       (const float*)d_in[25], (const float*)d_in[26],
                                       (float*)d_out);
}